// Round 6
// baseline (873.729 us; speedup 1.0000x reference)
//
#include <hip/hip_runtime.h>

#define HDIM 128
#define SCAN_CHUNK 1024

// ---------- degree histogram ----------
__global__ void deg_kernel(const int* __restrict__ src, const int* __restrict__ dst,
                           int* __restrict__ deg_out, int* __restrict__ deg_in, int E) {
    int e = blockIdx.x * blockDim.x + threadIdx.x;
    if (e < E) {
        atomicAdd(&deg_out[src[e]], 1);
        atomicAdd(&deg_in[dst[e]], 1);
    }
}

// ---------- inverse-sqrt degree ----------
__global__ void inv_kernel(const int* __restrict__ deg_out, const int* __restrict__ deg_in,
                           float* __restrict__ inv_out, float* __restrict__ inv_in, int N) {
    int n = blockIdx.x * blockDim.x + threadIdx.x;
    if (n < N) {
        float dO = (float)(deg_out[n] > 1 ? deg_out[n] : 1);
        float dI = (float)(deg_in[n]  > 1 ? deg_in[n]  : 1);
        inv_out[n] = 1.0f / sqrtf(dO);
        inv_in[n]  = 1.0f / sqrtf(dI);
    }
}

// ---------- hierarchical scan pass 1: per-block sums ----------
__global__ __launch_bounds__(1024) void scan_blk_sum(const int* __restrict__ deg,
                                                     int* __restrict__ blk_sum, int n) {
    __shared__ int red[1024];
    int tid = threadIdx.x;
    int i = blockIdx.x * SCAN_CHUNK + tid;
    red[tid] = (i < n) ? deg[i] : 0;
    __syncthreads();
    for (int s = 512; s > 0; s >>= 1) {
        if (tid < s) red[tid] += red[tid + s];
        __syncthreads();
    }
    if (tid == 0) blk_sum[blockIdx.x] = red[0];
}

// ---------- hierarchical scan pass 2: exclusive scan of block sums (nblk <= 128) ----------
__global__ __launch_bounds__(128) void scan_blk_off(const int* __restrict__ blk_sum,
                                                    int* __restrict__ blk_off, int nblk) {
    __shared__ int buf[128];
    int tid = threadIdx.x;
    int v = (tid < nblk) ? blk_sum[tid] : 0;
    buf[tid] = v;
    __syncthreads();
    for (int offset = 1; offset < 128; offset <<= 1) {
        int t = (tid >= offset) ? buf[tid - offset] : 0;
        __syncthreads();
        buf[tid] += t;
        __syncthreads();
    }
    if (tid < nblk) blk_off[tid] = buf[tid] - v;   // exclusive
}

// ---------- hierarchical scan pass 3: per-block inclusive scan + offset ----------
__global__ __launch_bounds__(1024) void scan_apply(const int* __restrict__ deg,
                                                   const int* __restrict__ blk_off,
                                                   int* __restrict__ row_ptr,
                                                   int* __restrict__ pos, int n) {
    __shared__ int buf[1024];
    int tid = threadIdx.x;
    int i = blockIdx.x * SCAN_CHUNK + tid;
    int v = (i < n) ? deg[i] : 0;
    buf[tid] = v;
    __syncthreads();
    for (int offset = 1; offset < 1024; offset <<= 1) {
        int t = (tid >= offset) ? buf[tid - offset] : 0;
        __syncthreads();
        buf[tid] += t;
        __syncthreads();
    }
    int base = blk_off[blockIdx.x];
    if (i < n) {
        int incl = base + buf[tid];
        row_ptr[i + 1] = incl;
        pos[i] = incl - v;
    }
    if (i == 0) row_ptr[0] = 0;
}

// ---------- scatter edges into CSR (grouped by dst) ----------
__global__ void fill_kernel(const int* __restrict__ src, const int* __restrict__ dst,
                            int* __restrict__ pos, int* __restrict__ csr_src, int E) {
    int e = blockIdx.x * blockDim.x + threadIdx.x;
    if (e < E) {
        int d = dst[e];
        int idx = atomicAdd(&pos[d], 1);
        csr_src[idx] = src[e];
    }
}

// ---------- embedding gather, pre-scaled: x[n] = z_table[z[n]] * inv_out[n] ----------
__global__ void embed_kernel(const int* __restrict__ z, const float* __restrict__ z_table,
                             const float* __restrict__ inv_out,
                             float* __restrict__ x, int N) {
    int t = blockIdx.x * blockDim.x + threadIdx.x;
    int n = t >> 5;          // 32 float4 per row (H=128)
    int c = t & 31;
    if (n < N) {
        int zz = z[n];
        float w = inv_out[n];
        float4 v = reinterpret_cast<const float4*>(z_table)[(size_t)zz * 32 + c];
        v.x *= w; v.y *= w; v.z *= w; v.w *= w;
        reinterpret_cast<float4*>(x)[(size_t)n * 32 + c] = v;
    }
}

// ---------- H-sliced pull-based GraphConv ----------
// Slice s = blockIdx & 7 handles columns [s*16, s*16+16) for all nodes.
// Round-robin block->XCD dispatch pins each 6.4 MB column slice of xs to one
// XCD's L2 (perf heuristic only; correctness independent of mapping).
// Block = 256 thr = 4 waves; wave = 4 nodes x 16 lanes; per-edge read = 64 B
// = one cache line. xs is PRE-SCALED by inv_out.
// mode 0: out = relu(acc*inv_in+b)*inv_out   mode 1: out = acc*inv_in+b
__global__ __launch_bounds__(256) void conv_sliced_kernel(
        const float* __restrict__ xs, float* __restrict__ out,
        const int* __restrict__ row_ptr, const int* __restrict__ csr_src,
        const float* __restrict__ inv_out, const float* __restrict__ inv_in,
        const float* __restrict__ bias, int N, int mode) {
    int slice = blockIdx.x & 7;
    int group = blockIdx.x >> 3;
    int sub   = threadIdx.x >> 4;          // 0..15: node index within block
    int c     = threadIdx.x & 15;          // column within slice
    int n = group * 16 + sub;
    if (n >= N) return;
    int col = slice * 16 + c;

    int start = row_ptr[n];
    int end   = row_ptr[n + 1];

    float a0 = 0.f, a1 = 0.f, a2 = 0.f, a3 = 0.f;
    int e = start;
    for (; e + 4 <= end; e += 4) {
        int s0 = csr_src[e + 0], s1 = csr_src[e + 1];
        int s2 = csr_src[e + 2], s3 = csr_src[e + 3];
        a0 += xs[(size_t)s0 * HDIM + col];
        a1 += xs[(size_t)s1 * HDIM + col];
        a2 += xs[(size_t)s2 * HDIM + col];
        a3 += xs[(size_t)s3 * HDIM + col];
    }
    for (; e < end; ++e) {
        a0 += xs[(size_t)csr_src[e] * HDIM + col];
    }
    float acc = (a0 + a1) + (a2 + a3);

    float o = acc * inv_in[n] + bias[col];
    if (mode == 0) o = fmaxf(o, 0.0f) * inv_out[n];
    out[(size_t)n * HDIM + col] = o;
}

// ---------- center pooling + 2-layer MLP: one block (128 thr) per pair ----------
__global__ __launch_bounds__(128) void mlp_kernel(
        const float* __restrict__ x, const int* __restrict__ pairs,
        const float* __restrict__ W1, const float* __restrict__ b1,
        const float* __restrict__ W2, const float* __restrict__ b2,
        float* __restrict__ out, int B) {
    __shared__ float xp[HDIM];
    __shared__ float red[HDIM];
    int p = blockIdx.x;
    int t = threadIdx.x;
    int a = pairs[p];
    int bnode = pairs[B + p];
    xp[t] = x[(size_t)a * HDIM + t] * x[(size_t)bnode * HDIM + t];
    __syncthreads();
    float h = b1[t];
    #pragma unroll 8
    for (int k = 0; k < HDIM; ++k) h += xp[k] * W1[k * HDIM + t];
    h = fmaxf(h, 0.0f);
    red[t] = h * W2[t];
    __syncthreads();
    for (int s = 64; s > 0; s >>= 1) {
        if (t < s) red[t] += red[t + s];
        __syncthreads();
    }
    if (t == 0) out[p] = red[0] + b2[0];
}

extern "C" void kernel_launch(void* const* d_in, const int* in_sizes, int n_in,
                              void* d_out, int out_size, void* d_ws, size_t ws_size,
                              hipStream_t stream) {
    const int*   z       = (const int*)d_in[0];
    const int*   src     = (const int*)d_in[1];
    const int*   dst     = (const int*)d_in[2];
    const int*   pairs   = (const int*)d_in[3];
    const float* z_table = (const float*)d_in[4];
    const float* bias[3] = {(const float*)d_in[5], (const float*)d_in[6], (const float*)d_in[7]};
    const float* W1      = (const float*)d_in[8];
    const float* b1      = (const float*)d_in[9];
    const float* W2      = (const float*)d_in[10];
    const float* b2      = (const float*)d_in[11];

    const int N = in_sizes[0];
    const int E = in_sizes[1];
    const int B = in_sizes[3] / 2;
    const int nblk = (N + SCAN_CHUNK - 1) / SCAN_CHUNK;

    char* ws = (char*)d_ws;
    size_t off = 0;
    auto carve = [&](size_t bytes) -> void* {
        void* p = ws + off;
        off = (off + bytes + 255) & ~(size_t)255;
        return p;
    };
    int*   deg_out = (int*)carve((size_t)N * 4);
    int*   deg_in  = (int*)carve((size_t)N * 4);
    float* inv_out = (float*)carve((size_t)N * 4);
    float* inv_in  = (float*)carve((size_t)N * 4);
    int*   row_ptr = (int*)carve((size_t)(N + 1) * 4);
    int*   pos     = (int*)carve((size_t)N * 4);
    int*   blk_sum = (int*)carve((size_t)nblk * 4);
    int*   blk_off = (int*)carve((size_t)nblk * 4);
    int*   csr_src = (int*)carve((size_t)E * 4);
    float* xb      = (float*)carve((size_t)N * HDIM * 4);
    float* mb      = (float*)carve((size_t)N * HDIM * 4);

    hipMemsetAsync(deg_out, 0, (size_t)N * 4, stream);
    hipMemsetAsync(deg_in,  0, (size_t)N * 4, stream);

    deg_kernel<<<(E + 255) / 256, 256, 0, stream>>>(src, dst, deg_out, deg_in, E);
    inv_kernel<<<(N + 255) / 256, 256, 0, stream>>>(deg_out, deg_in, inv_out, inv_in, N);

    scan_blk_sum<<<nblk, 1024, 0, stream>>>(deg_in, blk_sum, N);
    scan_blk_off<<<1, 128, 0, stream>>>(blk_sum, blk_off, nblk);
    scan_apply<<<nblk, 1024, 0, stream>>>(deg_in, blk_off, row_ptr, pos, N);

    fill_kernel<<<(E + 255) / 256, 256, 0, stream>>>(src, dst, pos, csr_src, E);
    embed_kernel<<<((size_t)N * 32 + 255) / 256, 256, 0, stream>>>(z, z_table, inv_out, xb, N);

    float* cur = xb;
    float* nxt = mb;
    const int ngroups = (N + 15) / 16;
    for (int layer = 0; layer < 3; ++layer) {
        int mode = (layer < 2) ? 0 : 1;
        conv_sliced_kernel<<<ngroups * 8, 256, 0, stream>>>(
            cur, nxt, row_ptr, csr_src, inv_out, inv_in, bias[layer], N, mode);
        float* tmp = cur; cur = nxt; nxt = tmp;
    }

    mlp_kernel<<<B, 128, 0, stream>>>(cur, pairs, W1, b1, W2, b2, (float*)d_out, B);
}

// Round 7
// 682.708 us; speedup vs baseline: 1.2798x; 1.2798x over previous
//
#include <hip/hip_runtime.h>

#define HDIM 128
#define SCAN_CHUNK 1024
#define NBKT 8     // dst-range buckets (one per XCD via blockIdx%8 round-robin)
#define NSUB 32    // sub-blocks streaming the edge list per bucket

// ---------- degree histogram ----------
__global__ void deg_kernel(const int* __restrict__ src, const int* __restrict__ dst,
                           int* __restrict__ deg_out, int* __restrict__ deg_in, int E) {
    int e = blockIdx.x * blockDim.x + threadIdx.x;
    if (e < E) {
        atomicAdd(&deg_out[src[e]], 1);
        atomicAdd(&deg_in[dst[e]], 1);
    }
}

// ---------- inverse-sqrt degree ----------
__global__ void inv_kernel(const int* __restrict__ deg_out, const int* __restrict__ deg_in,
                           float* __restrict__ inv_out, float* __restrict__ inv_in, int N) {
    int n = blockIdx.x * blockDim.x + threadIdx.x;
    if (n < N) {
        float dO = (float)(deg_out[n] > 1 ? deg_out[n] : 1);
        float dI = (float)(deg_in[n]  > 1 ? deg_in[n]  : 1);
        inv_out[n] = 1.0f / sqrtf(dO);
        inv_in[n]  = 1.0f / sqrtf(dI);
    }
}

// ---------- hierarchical scan pass 1: per-block sums ----------
__global__ __launch_bounds__(1024) void scan_blk_sum(const int* __restrict__ deg,
                                                     int* __restrict__ blk_sum, int n) {
    __shared__ int red[1024];
    int tid = threadIdx.x;
    int i = blockIdx.x * SCAN_CHUNK + tid;
    red[tid] = (i < n) ? deg[i] : 0;
    __syncthreads();
    for (int s = 512; s > 0; s >>= 1) {
        if (tid < s) red[tid] += red[tid + s];
        __syncthreads();
    }
    if (tid == 0) blk_sum[blockIdx.x] = red[0];
}

// ---------- hierarchical scan pass 2: exclusive scan of block sums (nblk <= 128) ----------
__global__ __launch_bounds__(128) void scan_blk_off(const int* __restrict__ blk_sum,
                                                    int* __restrict__ blk_off, int nblk) {
    __shared__ int buf[128];
    int tid = threadIdx.x;
    int v = (tid < nblk) ? blk_sum[tid] : 0;
    buf[tid] = v;
    __syncthreads();
    for (int offset = 1; offset < 128; offset <<= 1) {
        int t = (tid >= offset) ? buf[tid - offset] : 0;
        __syncthreads();
        buf[tid] += t;
        __syncthreads();
    }
    if (tid < nblk) blk_off[tid] = buf[tid] - v;   // exclusive
}

// ---------- hierarchical scan pass 3: per-block inclusive scan + offset ----------
__global__ __launch_bounds__(1024) void scan_apply(const int* __restrict__ deg,
                                                   const int* __restrict__ blk_off,
                                                   int* __restrict__ row_ptr,
                                                   int* __restrict__ pos, int n) {
    __shared__ int buf[1024];
    int tid = threadIdx.x;
    int i = blockIdx.x * SCAN_CHUNK + tid;
    int v = (i < n) ? deg[i] : 0;
    buf[tid] = v;
    __syncthreads();
    for (int offset = 1; offset < 1024; offset <<= 1) {
        int t = (tid >= offset) ? buf[tid - offset] : 0;
        __syncthreads();
        buf[tid] += t;
        __syncthreads();
    }
    int base = blk_off[blockIdx.x];
    if (i < n) {
        int incl = base + buf[tid];
        row_ptr[i + 1] = incl;
        pos[i] = incl - v;
    }
    if (i == 0) row_ptr[0] = 0;
}

// ---------- XCD-filtered streaming fill ----------
// bucket = blockIdx%8 -> one XCD per dst-range bucket (round-robin heuristic).
// Each block streams a contiguous 1/NSUB chunk of the edge list (coalesced)
// and scatters only edges in its bucket's dst range; the bucket's pos (50 KB)
// + csr (~800 KB) windows stay L2-resident on one XCD until lines fill.
__global__ __launch_bounds__(256) void fill_xcd_kernel(
        const int* __restrict__ src, const int* __restrict__ dst,
        int* __restrict__ pos, int* __restrict__ csr_src, int E, int N) {
    int bucket = blockIdx.x & (NBKT - 1);
    int sub    = blockIdx.x >> 3;            // 0..NSUB-1
    int chunk  = (E + NSUB - 1) / NSUB;
    int lo = sub * chunk;
    int hi = lo + chunk; if (hi > E) hi = E;
    for (int e = lo + threadIdx.x; e < hi; e += 256) {
        int d = dst[e];
        int b = (int)(((long long)d * NBKT) / N);
        if (b == bucket) {
            int idx = atomicAdd(&pos[d], 1);
            csr_src[idx] = src[e];
        }
    }
}

// ---------- embedding gather, pre-scaled: x[n] = z_table[z[n]] * inv_out[n] ----------
__global__ void embed_kernel(const int* __restrict__ z, const float* __restrict__ z_table,
                             const float* __restrict__ inv_out,
                             float* __restrict__ x, int N) {
    int t = blockIdx.x * blockDim.x + threadIdx.x;
    int n = t >> 5;          // 32 float4 per row (H=128)
    int c = t & 31;
    if (n < N) {
        int zz = z[n];
        float w = inv_out[n];
        float4 v = reinterpret_cast<const float4*>(z_table)[(size_t)zz * 32 + c];
        v.x *= w; v.y *= w; v.z *= w; v.w *= w;
        reinterpret_cast<float4*>(x)[(size_t)n * 32 + c] = v;
    }
}

// ---------- pull-based GraphConv, 8-way unrolled, 2 waves/block ----------
// input xs is PRE-SCALED by inv_out. mode 0: out = relu(acc*inv_in+b)*inv_out
//                                    mode 1: out = acc*inv_in+b (final layer)
__global__ __launch_bounds__(128) void conv_kernel(
        const float* __restrict__ xs, float* __restrict__ out,
        const int* __restrict__ row_ptr, const int* __restrict__ csr_src,
        const float* __restrict__ inv_out, const float* __restrict__ inv_in,
        const float* __restrict__ bias, int N, int mode) {
    int gtid = blockIdx.x * blockDim.x + threadIdx.x;
    int n = gtid >> 6;       // wave per node
    int lane = threadIdx.x & 63;
    if (n >= N) return;

    int start = row_ptr[n];
    int end   = row_ptr[n + 1];

    float2 a0 = make_float2(0.f, 0.f), a1 = a0, a2 = a0, a3 = a0;
    float2 a4 = a0, a5 = a0, a6 = a0, a7 = a0;
    int e = start;
    for (; e + 8 <= end; e += 8) {
        int s0 = csr_src[e + 0], s1 = csr_src[e + 1];
        int s2 = csr_src[e + 2], s3 = csr_src[e + 3];
        int s4 = csr_src[e + 4], s5 = csr_src[e + 5];
        int s6 = csr_src[e + 6], s7 = csr_src[e + 7];
        float2 v0 = reinterpret_cast<const float2*>(xs + (size_t)s0 * HDIM)[lane];
        float2 v1 = reinterpret_cast<const float2*>(xs + (size_t)s1 * HDIM)[lane];
        float2 v2 = reinterpret_cast<const float2*>(xs + (size_t)s2 * HDIM)[lane];
        float2 v3 = reinterpret_cast<const float2*>(xs + (size_t)s3 * HDIM)[lane];
        float2 v4 = reinterpret_cast<const float2*>(xs + (size_t)s4 * HDIM)[lane];
        float2 v5 = reinterpret_cast<const float2*>(xs + (size_t)s5 * HDIM)[lane];
        float2 v6 = reinterpret_cast<const float2*>(xs + (size_t)s6 * HDIM)[lane];
        float2 v7 = reinterpret_cast<const float2*>(xs + (size_t)s7 * HDIM)[lane];
        a0.x += v0.x; a0.y += v0.y;  a1.x += v1.x; a1.y += v1.y;
        a2.x += v2.x; a2.y += v2.y;  a3.x += v3.x; a3.y += v3.y;
        a4.x += v4.x; a4.y += v4.y;  a5.x += v5.x; a5.y += v5.y;
        a6.x += v6.x; a6.y += v6.y;  a7.x += v7.x; a7.y += v7.y;
    }
    if (e + 4 <= end) {
        int s0 = csr_src[e + 0], s1 = csr_src[e + 1];
        int s2 = csr_src[e + 2], s3 = csr_src[e + 3];
        float2 v0 = reinterpret_cast<const float2*>(xs + (size_t)s0 * HDIM)[lane];
        float2 v1 = reinterpret_cast<const float2*>(xs + (size_t)s1 * HDIM)[lane];
        float2 v2 = reinterpret_cast<const float2*>(xs + (size_t)s2 * HDIM)[lane];
        float2 v3 = reinterpret_cast<const float2*>(xs + (size_t)s3 * HDIM)[lane];
        a0.x += v0.x; a0.y += v0.y;  a1.x += v1.x; a1.y += v1.y;
        a2.x += v2.x; a2.y += v2.y;  a3.x += v3.x; a3.y += v3.y;
        e += 4;
    }
    for (; e < end; ++e) {
        int s = csr_src[e];
        float2 v = reinterpret_cast<const float2*>(xs + (size_t)s * HDIM)[lane];
        a0.x += v.x; a0.y += v.y;
    }
    float2 acc;
    acc.x = ((a0.x + a1.x) + (a2.x + a3.x)) + ((a4.x + a5.x) + (a6.x + a7.x));
    acc.y = ((a0.y + a1.y) + (a2.y + a3.y)) + ((a4.y + a5.y) + (a6.y + a7.y));

    float win = inv_in[n];
    float2 b = reinterpret_cast<const float2*>(bias)[lane];
    float2 o;
    o.x = acc.x * win + b.x;
    o.y = acc.y * win + b.y;
    if (mode == 0) {
        float wout = inv_out[n];
        o.x = fmaxf(o.x, 0.0f) * wout;
        o.y = fmaxf(o.y, 0.0f) * wout;
    }
    reinterpret_cast<float2*>(out + (size_t)n * HDIM)[lane] = o;
}

// ---------- center pooling + 2-layer MLP: one block (128 thr) per pair ----------
__global__ __launch_bounds__(128) void mlp_kernel(
        const float* __restrict__ x, const int* __restrict__ pairs,
        const float* __restrict__ W1, const float* __restrict__ b1,
        const float* __restrict__ W2, const float* __restrict__ b2,
        float* __restrict__ out, int B) {
    __shared__ float xp[HDIM];
    __shared__ float red[HDIM];
    int p = blockIdx.x;
    int t = threadIdx.x;
    int a = pairs[p];
    int bnode = pairs[B + p];
    xp[t] = x[(size_t)a * HDIM + t] * x[(size_t)bnode * HDIM + t];
    __syncthreads();
    float h = b1[t];
    #pragma unroll 8
    for (int k = 0; k < HDIM; ++k) h += xp[k] * W1[k * HDIM + t];
    h = fmaxf(h, 0.0f);
    red[t] = h * W2[t];
    __syncthreads();
    for (int s = 64; s > 0; s >>= 1) {
        if (t < s) red[t] += red[t + s];
        __syncthreads();
    }
    if (t == 0) out[p] = red[0] + b2[0];
}

extern "C" void kernel_launch(void* const* d_in, const int* in_sizes, int n_in,
                              void* d_out, int out_size, void* d_ws, size_t ws_size,
                              hipStream_t stream) {
    const int*   z       = (const int*)d_in[0];
    const int*   src     = (const int*)d_in[1];
    const int*   dst     = (const int*)d_in[2];
    const int*   pairs   = (const int*)d_in[3];
    const float* z_table = (const float*)d_in[4];
    const float* bias[3] = {(const float*)d_in[5], (const float*)d_in[6], (const float*)d_in[7]};
    const float* W1      = (const float*)d_in[8];
    const float* b1      = (const float*)d_in[9];
    const float* W2      = (const float*)d_in[10];
    const float* b2      = (const float*)d_in[11];

    const int N = in_sizes[0];
    const int E = in_sizes[1];
    const int B = in_sizes[3] / 2;
    const int nblk = (N + SCAN_CHUNK - 1) / SCAN_CHUNK;

    char* ws = (char*)d_ws;
    size_t off = 0;
    auto carve = [&](size_t bytes) -> void* {
        void* p = ws + off;
        off = (off + bytes + 255) & ~(size_t)255;
        return p;
    };
    int*   deg_out = (int*)carve((size_t)N * 4);
    int*   deg_in  = (int*)carve((size_t)N * 4);
    float* inv_out = (float*)carve((size_t)N * 4);
    float* inv_in  = (float*)carve((size_t)N * 4);
    int*   row_ptr = (int*)carve((size_t)(N + 1) * 4);
    int*   pos     = (int*)carve((size_t)N * 4);
    int*   blk_sum = (int*)carve((size_t)nblk * 4);
    int*   blk_off = (int*)carve((size_t)nblk * 4);
    int*   csr_src = (int*)carve((size_t)E * 4);
    float* xb      = (float*)carve((size_t)N * HDIM * 4);
    float* mb      = (float*)carve((size_t)N * HDIM * 4);

    hipMemsetAsync(deg_out, 0, (size_t)N * 4, stream);
    hipMemsetAsync(deg_in,  0, (size_t)N * 4, stream);

    deg_kernel<<<(E + 255) / 256, 256, 0, stream>>>(src, dst, deg_out, deg_in, E);
    inv_kernel<<<(N + 255) / 256, 256, 0, stream>>>(deg_out, deg_in, inv_out, inv_in, N);

    scan_blk_sum<<<nblk, 1024, 0, stream>>>(deg_in, blk_sum, N);
    scan_blk_off<<<1, 128, 0, stream>>>(blk_sum, blk_off, nblk);
    scan_apply<<<nblk, 1024, 0, stream>>>(deg_in, blk_off, row_ptr, pos, N);

    fill_xcd_kernel<<<NBKT * NSUB, 256, 0, stream>>>(src, dst, pos, csr_src, E, N);
    embed_kernel<<<((size_t)N * 32 + 255) / 256, 256, 0, stream>>>(z, z_table, inv_out, xb, N);

    float* cur = xb;
    float* nxt = mb;
    for (int layer = 0; layer < 3; ++layer) {
        int mode = (layer < 2) ? 0 : 1;
        long long threads = (long long)N * 64;
        conv_kernel<<<(threads + 127) / 128, 128, 0, stream>>>(
            cur, nxt, row_ptr, csr_src, inv_out, inv_in, bias[layer], N, mode);
        float* tmp = cur; cur = nxt; nxt = tmp;
    }

    mlp_kernel<<<B, 128, 0, stream>>>(cur, pairs, W1, b1, W2, b2, (float*)d_out, B);
}

// Round 8
// 481.125 us; speedup vs baseline: 1.8160x; 1.4190x over previous
//
#include <hip/hip_runtime.h>

#define HDIM 128
#define SCAN_CHUNK 1024

// ---------- bf16x2 pack/unpack (RNE) ----------
__device__ inline unsigned pack_bf16x2(float a, float b) {
    unsigned ua = __float_as_uint(a);
    unsigned ub = __float_as_uint(b);
    ua = (ua + 0x7FFFu + ((ua >> 16) & 1u)) >> 16;
    ub = (ub + 0x7FFFu + ((ub >> 16) & 1u)) >> 16;
    return ua | (ub << 16);
}
__device__ inline float bf16_lo(unsigned v) { return __uint_as_float(v << 16); }
__device__ inline float bf16_hi(unsigned v) { return __uint_as_float(v & 0xFFFF0000u); }

// ---------- degree histogram ----------
__global__ void deg_kernel(const int* __restrict__ src, const int* __restrict__ dst,
                           int* __restrict__ deg_out, int* __restrict__ deg_in, int E) {
    int e = blockIdx.x * blockDim.x + threadIdx.x;
    if (e < E) {
        atomicAdd(&deg_out[src[e]], 1);
        atomicAdd(&deg_in[dst[e]], 1);
    }
}

// ---------- inverse-sqrt degree ----------
__global__ void inv_kernel(const int* __restrict__ deg_out, const int* __restrict__ deg_in,
                           float* __restrict__ inv_out, float* __restrict__ inv_in, int N) {
    int n = blockIdx.x * blockDim.x + threadIdx.x;
    if (n < N) {
        float dO = (float)(deg_out[n] > 1 ? deg_out[n] : 1);
        float dI = (float)(deg_in[n]  > 1 ? deg_in[n]  : 1);
        inv_out[n] = 1.0f / sqrtf(dO);
        inv_in[n]  = 1.0f / sqrtf(dI);
    }
}

// ---------- hierarchical scan pass 1: per-block sums ----------
__global__ __launch_bounds__(1024) void scan_blk_sum(const int* __restrict__ deg,
                                                     int* __restrict__ blk_sum, int n) {
    __shared__ int red[1024];
    int tid = threadIdx.x;
    int i = blockIdx.x * SCAN_CHUNK + tid;
    red[tid] = (i < n) ? deg[i] : 0;
    __syncthreads();
    for (int s = 512; s > 0; s >>= 1) {
        if (tid < s) red[tid] += red[tid + s];
        __syncthreads();
    }
    if (tid == 0) blk_sum[blockIdx.x] = red[0];
}

// ---------- hierarchical scan pass 2: exclusive scan of block sums (nblk <= 128) ----------
__global__ __launch_bounds__(128) void scan_blk_off(const int* __restrict__ blk_sum,
                                                    int* __restrict__ blk_off, int nblk) {
    __shared__ int buf[128];
    int tid = threadIdx.x;
    int v = (tid < nblk) ? blk_sum[tid] : 0;
    buf[tid] = v;
    __syncthreads();
    for (int offset = 1; offset < 128; offset <<= 1) {
        int t = (tid >= offset) ? buf[tid - offset] : 0;
        __syncthreads();
        buf[tid] += t;
        __syncthreads();
    }
    if (tid < nblk) blk_off[tid] = buf[tid] - v;   // exclusive
}

// ---------- hierarchical scan pass 3: per-block inclusive scan + offset ----------
__global__ __launch_bounds__(1024) void scan_apply(const int* __restrict__ deg,
                                                   const int* __restrict__ blk_off,
                                                   int* __restrict__ row_ptr,
                                                   int* __restrict__ pos, int n) {
    __shared__ int buf[1024];
    int tid = threadIdx.x;
    int i = blockIdx.x * SCAN_CHUNK + tid;
    int v = (i < n) ? deg[i] : 0;
    buf[tid] = v;
    __syncthreads();
    for (int offset = 1; offset < 1024; offset <<= 1) {
        int t = (tid >= offset) ? buf[tid - offset] : 0;
        __syncthreads();
        buf[tid] += t;
        __syncthreads();
    }
    int base = blk_off[blockIdx.x];
    if (i < n) {
        int incl = base + buf[tid];
        row_ptr[i + 1] = incl;
        pos[i] = incl - v;
    }
    if (i == 0) row_ptr[0] = 0;
}

// ---------- scatter edges into CSR (grouped by dst) ----------
__global__ void fill_kernel(const int* __restrict__ src, const int* __restrict__ dst,
                            int* __restrict__ pos, int* __restrict__ csr_src, int E) {
    int e = blockIdx.x * blockDim.x + threadIdx.x;
    if (e < E) {
        int d = dst[e];
        int idx = atomicAdd(&pos[d], 1);
        csr_src[idx] = src[e];
    }
}

// ---------- embedding gather, pre-scaled + bf16 pack ----------
// thread handles 4 cols: xs_u2[n*32+c] = pack(z_table[z[n]][4c..4c+3] * inv_out[n])
__global__ void embed_kernel(const int* __restrict__ z, const float* __restrict__ z_table,
                             const float* __restrict__ inv_out,
                             uint2* __restrict__ xs, int N) {
    int t = blockIdx.x * blockDim.x + threadIdx.x;
    int n = t >> 5;          // 32 uint2 per row (H=128 bf16)
    int c = t & 31;
    if (n < N) {
        int zz = z[n];
        float w = inv_out[n];
        float4 v = reinterpret_cast<const float4*>(z_table)[(size_t)zz * 32 + c];
        uint2 p;
        p.x = pack_bf16x2(v.x * w, v.y * w);
        p.y = pack_bf16x2(v.z * w, v.w * w);
        xs[(size_t)n * 32 + c] = p;
    }
}

// ---------- pull-based GraphConv, bf16 features, 8-way unrolled, 2 waves/block ----------
// xs is bf16x2-packed, PRE-SCALED by inv_out. Lane handles cols {2*lane, 2*lane+1}.
// mode 0: out_bf = pack(relu(acc*inv_in+b)*inv_out)   (feeds next conv)
// mode 1: out_f32 = acc*inv_in+b                      (final layer, feeds MLP)
__global__ __launch_bounds__(128) void conv_kernel(
        const unsigned* __restrict__ xs, unsigned* __restrict__ out_bf,
        float* __restrict__ out_f32,
        const int* __restrict__ row_ptr, const int* __restrict__ csr_src,
        const float* __restrict__ inv_out, const float* __restrict__ inv_in,
        const float* __restrict__ bias, int N, int mode) {
    int gtid = blockIdx.x * blockDim.x + threadIdx.x;
    int n = gtid >> 6;       // wave per node
    int lane = threadIdx.x & 63;
    if (n >= N) return;

    int start = row_ptr[n];
    int end   = row_ptr[n + 1];

    float ax0 = 0.f, ay0 = 0.f, ax1 = 0.f, ay1 = 0.f;
    float ax2 = 0.f, ay2 = 0.f, ax3 = 0.f, ay3 = 0.f;
    float ax4 = 0.f, ay4 = 0.f, ax5 = 0.f, ay5 = 0.f;
    float ax6 = 0.f, ay6 = 0.f, ax7 = 0.f, ay7 = 0.f;
    int e = start;
    for (; e + 8 <= end; e += 8) {
        int s0 = csr_src[e + 0], s1 = csr_src[e + 1];
        int s2 = csr_src[e + 2], s3 = csr_src[e + 3];
        int s4 = csr_src[e + 4], s5 = csr_src[e + 5];
        int s6 = csr_src[e + 6], s7 = csr_src[e + 7];
        unsigned v0 = xs[(size_t)s0 * 64 + lane];
        unsigned v1 = xs[(size_t)s1 * 64 + lane];
        unsigned v2 = xs[(size_t)s2 * 64 + lane];
        unsigned v3 = xs[(size_t)s3 * 64 + lane];
        unsigned v4 = xs[(size_t)s4 * 64 + lane];
        unsigned v5 = xs[(size_t)s5 * 64 + lane];
        unsigned v6 = xs[(size_t)s6 * 64 + lane];
        unsigned v7 = xs[(size_t)s7 * 64 + lane];
        ax0 += bf16_lo(v0); ay0 += bf16_hi(v0);
        ax1 += bf16_lo(v1); ay1 += bf16_hi(v1);
        ax2 += bf16_lo(v2); ay2 += bf16_hi(v2);
        ax3 += bf16_lo(v3); ay3 += bf16_hi(v3);
        ax4 += bf16_lo(v4); ay4 += bf16_hi(v4);
        ax5 += bf16_lo(v5); ay5 += bf16_hi(v5);
        ax6 += bf16_lo(v6); ay6 += bf16_hi(v6);
        ax7 += bf16_lo(v7); ay7 += bf16_hi(v7);
    }
    if (e + 4 <= end) {
        int s0 = csr_src[e + 0], s1 = csr_src[e + 1];
        int s2 = csr_src[e + 2], s3 = csr_src[e + 3];
        unsigned v0 = xs[(size_t)s0 * 64 + lane];
        unsigned v1 = xs[(size_t)s1 * 64 + lane];
        unsigned v2 = xs[(size_t)s2 * 64 + lane];
        unsigned v3 = xs[(size_t)s3 * 64 + lane];
        ax0 += bf16_lo(v0); ay0 += bf16_hi(v0);
        ax1 += bf16_lo(v1); ay1 += bf16_hi(v1);
        ax2 += bf16_lo(v2); ay2 += bf16_hi(v2);
        ax3 += bf16_lo(v3); ay3 += bf16_hi(v3);
        e += 4;
    }
    for (; e < end; ++e) {
        unsigned v = xs[(size_t)csr_src[e] * 64 + lane];
        ax0 += bf16_lo(v); ay0 += bf16_hi(v);
    }
    float accx = ((ax0 + ax1) + (ax2 + ax3)) + ((ax4 + ax5) + (ax6 + ax7));
    float accy = ((ay0 + ay1) + (ay2 + ay3)) + ((ay4 + ay5) + (ay6 + ay7));

    float win = inv_in[n];
    float2 b = reinterpret_cast<const float2*>(bias)[lane];
    float ox = accx * win + b.x;
    float oy = accy * win + b.y;
    if (mode == 0) {
        float wout = inv_out[n];
        ox = fmaxf(ox, 0.0f) * wout;
        oy = fmaxf(oy, 0.0f) * wout;
        out_bf[(size_t)n * 64 + lane] = pack_bf16x2(ox, oy);
    } else {
        reinterpret_cast<float2*>(out_f32 + (size_t)n * HDIM)[lane] = make_float2(ox, oy);
    }
}

// ---------- center pooling + 2-layer MLP: one block (128 thr) per pair ----------
__global__ __launch_bounds__(128) void mlp_kernel(
        const float* __restrict__ x, const int* __restrict__ pairs,
        const float* __restrict__ W1, const float* __restrict__ b1,
        const float* __restrict__ W2, const float* __restrict__ b2,
        float* __restrict__ out, int B) {
    __shared__ float xp[HDIM];
    __shared__ float red[HDIM];
    int p = blockIdx.x;
    int t = threadIdx.x;
    int a = pairs[p];
    int bnode = pairs[B + p];
    xp[t] = x[(size_t)a * HDIM + t] * x[(size_t)bnode * HDIM + t];
    __syncthreads();
    float h = b1[t];
    #pragma unroll 8
    for (int k = 0; k < HDIM; ++k) h += xp[k] * W1[k * HDIM + t];
    h = fmaxf(h, 0.0f);
    red[t] = h * W2[t];
    __syncthreads();
    for (int s = 64; s > 0; s >>= 1) {
        if (t < s) red[t] += red[t + s];
        __syncthreads();
    }
    if (t == 0) out[p] = red[0] + b2[0];
}

extern "C" void kernel_launch(void* const* d_in, const int* in_sizes, int n_in,
                              void* d_out, int out_size, void* d_ws, size_t ws_size,
                              hipStream_t stream) {
    const int*   z       = (const int*)d_in[0];
    const int*   src     = (const int*)d_in[1];
    const int*   dst     = (const int*)d_in[2];
    const int*   pairs   = (const int*)d_in[3];
    const float* z_table = (const float*)d_in[4];
    const float* bias[3] = {(const float*)d_in[5], (const float*)d_in[6], (const float*)d_in[7]};
    const float* W1      = (const float*)d_in[8];
    const float* b1      = (const float*)d_in[9];
    const float* W2      = (const float*)d_in[10];
    const float* b2      = (const float*)d_in[11];

    const int N = in_sizes[0];
    const int E = in_sizes[1];
    const int B = in_sizes[3] / 2;
    const int nblk = (N + SCAN_CHUNK - 1) / SCAN_CHUNK;

    char* ws = (char*)d_ws;
    size_t off = 0;
    auto carve = [&](size_t bytes) -> void* {
        void* p = ws + off;
        off = (off + bytes + 255) & ~(size_t)255;
        return p;
    };
    int*      deg_out = (int*)carve((size_t)N * 4);
    int*      deg_in  = (int*)carve((size_t)N * 4);
    float*    inv_out = (float*)carve((size_t)N * 4);
    float*    inv_in  = (float*)carve((size_t)N * 4);
    int*      row_ptr = (int*)carve((size_t)(N + 1) * 4);
    int*      pos     = (int*)carve((size_t)N * 4);
    int*      blk_sum = (int*)carve((size_t)nblk * 4);
    int*      blk_off = (int*)carve((size_t)nblk * 4);
    int*      csr_src = (int*)carve((size_t)E * 4);
    unsigned* xb      = (unsigned*)carve((size_t)N * 64 * 4);   // bf16x2 [N][64]
    unsigned* mbuf    = (unsigned*)carve((size_t)N * 64 * 4);   // bf16x2 [N][64]
    float*    xf      = (float*)carve((size_t)N * HDIM * 4);    // f32 final features

    hipMemsetAsync(deg_out, 0, (size_t)N * 4, stream);
    hipMemsetAsync(deg_in,  0, (size_t)N * 4, stream);

    deg_kernel<<<(E + 255) / 256, 256, 0, stream>>>(src, dst, deg_out, deg_in, E);
    inv_kernel<<<(N + 255) / 256, 256, 0, stream>>>(deg_out, deg_in, inv_out, inv_in, N);

    scan_blk_sum<<<nblk, 1024, 0, stream>>>(deg_in, blk_sum, N);
    scan_blk_off<<<1, 128, 0, stream>>>(blk_sum, blk_off, nblk);
    scan_apply<<<nblk, 1024, 0, stream>>>(deg_in, blk_off, row_ptr, pos, N);

    fill_kernel<<<(E + 255) / 256, 256, 0, stream>>>(src, dst, pos, csr_src, E);
    embed_kernel<<<((size_t)N * 32 + 255) / 256, 256, 0, stream>>>(
        z, z_table, inv_out, (uint2*)xb, N);

    unsigned* cur = xb;
    unsigned* nxt = mbuf;
    long long threads = (long long)N * 64;
    for (int layer = 0; layer < 3; ++layer) {
        int mode = (layer < 2) ? 0 : 1;
        conv_kernel<<<(threads + 127) / 128, 128, 0, stream>>>(
            cur, nxt, xf, row_ptr, csr_src, inv_out, inv_in, bias[layer], N, mode);
        unsigned* tmp = cur; cur = nxt; nxt = tmp;
    }

    mlp_kernel<<<B, 128, 0, stream>>>(xf, pairs, W1, b1, W2, b2, (float*)d_out, B);
}

// Round 9
// 417.416 us; speedup vs baseline: 2.0932x; 1.1526x over previous
//
#include <hip/hip_runtime.h>

#define HDIM 128
#define SCAN_CHUNK 1024
#define NBUK 256          // dst-range buckets for radix-partition fill
#define PART_EPT 2        // edges per thread in partition kernel

// ---------- bf16x2 pack/unpack (RNE) ----------
__device__ inline unsigned pack_bf16x2(float a, float b) {
    unsigned ua = __float_as_uint(a);
    unsigned ub = __float_as_uint(b);
    ua = (ua + 0x7FFFu + ((ua >> 16) & 1u)) >> 16;
    ub = (ub + 0x7FFFu + ((ub >> 16) & 1u)) >> 16;
    return ua | (ub << 16);
}
__device__ inline float bf16_lo(unsigned v) { return __uint_as_float(v << 16); }
__device__ inline float bf16_hi(unsigned v) { return __uint_as_float(v & 0xFFFF0000u); }

// ---------- degree histogram ----------
__global__ void deg_kernel(const int* __restrict__ src, const int* __restrict__ dst,
                           int* __restrict__ deg_out, int* __restrict__ deg_in, int E) {
    int e = blockIdx.x * blockDim.x + threadIdx.x;
    if (e < E) {
        atomicAdd(&deg_out[src[e]], 1);
        atomicAdd(&deg_in[dst[e]], 1);
    }
}

// ---------- inverse-sqrt degree ----------
__global__ void inv_kernel(const int* __restrict__ deg_out, const int* __restrict__ deg_in,
                           float* __restrict__ inv_out, float* __restrict__ inv_in, int N) {
    int n = blockIdx.x * blockDim.x + threadIdx.x;
    if (n < N) {
        float dO = (float)(deg_out[n] > 1 ? deg_out[n] : 1);
        float dI = (float)(deg_in[n]  > 1 ? deg_in[n]  : 1);
        inv_out[n] = 1.0f / sqrtf(dO);
        inv_in[n]  = 1.0f / sqrtf(dI);
    }
}

// ---------- hierarchical scan pass 1: per-block sums ----------
__global__ __launch_bounds__(1024) void scan_blk_sum(const int* __restrict__ deg,
                                                     int* __restrict__ blk_sum, int n) {
    __shared__ int red[1024];
    int tid = threadIdx.x;
    int i = blockIdx.x * SCAN_CHUNK + tid;
    red[tid] = (i < n) ? deg[i] : 0;
    __syncthreads();
    for (int s = 512; s > 0; s >>= 1) {
        if (tid < s) red[tid] += red[tid + s];
        __syncthreads();
    }
    if (tid == 0) blk_sum[blockIdx.x] = red[0];
}

// ---------- hierarchical scan pass 2: exclusive scan of block sums (nblk <= 128) ----------
__global__ __launch_bounds__(128) void scan_blk_off(const int* __restrict__ blk_sum,
                                                    int* __restrict__ blk_off, int nblk) {
    __shared__ int buf[128];
    int tid = threadIdx.x;
    int v = (tid < nblk) ? blk_sum[tid] : 0;
    buf[tid] = v;
    __syncthreads();
    for (int offset = 1; offset < 128; offset <<= 1) {
        int t = (tid >= offset) ? buf[tid - offset] : 0;
        __syncthreads();
        buf[tid] += t;
        __syncthreads();
    }
    if (tid < nblk) blk_off[tid] = buf[tid] - v;   // exclusive
}

// ---------- hierarchical scan pass 3: per-block inclusive scan + offset ----------
__global__ __launch_bounds__(1024) void scan_apply(const int* __restrict__ deg,
                                                   const int* __restrict__ blk_off,
                                                   int* __restrict__ row_ptr,
                                                   int* __restrict__ pos, int n) {
    __shared__ int buf[1024];
    int tid = threadIdx.x;
    int i = blockIdx.x * SCAN_CHUNK + tid;
    int v = (i < n) ? deg[i] : 0;
    buf[tid] = v;
    __syncthreads();
    for (int offset = 1; offset < 1024; offset <<= 1) {
        int t = (tid >= offset) ? buf[tid - offset] : 0;
        __syncthreads();
        buf[tid] += t;
        __syncthreads();
    }
    int base = blk_off[blockIdx.x];
    if (i < n) {
        int incl = base + buf[tid];
        row_ptr[i + 1] = incl;
        pos[i] = incl - v;
    }
    if (i == 0) row_ptr[0] = 0;
}

// ---------- plain scatter fill (fallback if ws too small) ----------
__global__ void fill_kernel(const int* __restrict__ src, const int* __restrict__ dst,
                            int* __restrict__ pos, int* __restrict__ csr_src, int E) {
    int e = blockIdx.x * blockDim.x + threadIdx.x;
    if (e < E) {
        int d = dst[e];
        int idx = atomicAdd(&pos[d], 1);
        csr_src[idx] = src[e];
    }
}

// ---------- radix-partition fill: init bucket allocators ----------
__global__ void init_alloc_kernel(int* __restrict__ alloc, int cap) {
    int i = threadIdx.x;        // one block of NBUK threads
    alloc[i] = i * cap;
}

// ---------- radix-partition fill phase 1: LDS-binned partition by dst range ----------
// Each block: LDS histogram (rank via LDS atomic), ONE global atomic per bucket
// per block to claim a contiguous chunk, then write (src,dst) int2 into its
// chunk. Per-block-per-bucket chunk ~8 edges = 64 B = one line.
__global__ __launch_bounds__(1024) void partition_kernel(
        const int* __restrict__ src, const int* __restrict__ dst,
        int* __restrict__ alloc, int2* __restrict__ staging,
        int E, int N, int cap) {
    __shared__ int lcnt[NBUK];
    __shared__ int lbase[NBUK];
    int tid = threadIdx.x;
    if (tid < NBUK) lcnt[tid] = 0;
    __syncthreads();
    int base_e = blockIdx.x * (1024 * PART_EPT);
    int s[PART_EPT], d[PART_EPT], bk[PART_EPT], rk[PART_EPT];
    #pragma unroll
    for (int j = 0; j < PART_EPT; ++j) {
        int e = base_e + j * 1024 + tid;    // coalesced
        if (e < E) {
            s[j] = src[e];
            d[j] = dst[e];
            bk[j] = (int)(((long long)d[j] * NBUK) / N);
            rk[j] = atomicAdd(&lcnt[bk[j]], 1);
        } else {
            bk[j] = -1;
        }
    }
    __syncthreads();
    if (tid < NBUK) {
        int c = lcnt[tid];
        lbase[tid] = (c > 0) ? atomicAdd(&alloc[tid], c) : 0;
    }
    __syncthreads();
    #pragma unroll
    for (int j = 0; j < PART_EPT; ++j) {
        if (bk[j] >= 0) {
            int idx = lbase[bk[j]] + rk[j];
            if (idx < (bk[j] + 1) * cap)    // overflow clamp (>=24 sigma headroom)
                staging[idx] = make_int2(s[j], d[j]);
        }
    }
}

// ---------- radix-partition fill phase 2: per-bucket window-local scatter ----------
// One block per bucket: pos window ~1.6 KB + csr window ~25 KB, single writer,
// stays L2-resident until lines are fully filled.
__global__ __launch_bounds__(256) void scatter_kernel(
        const int* __restrict__ alloc, const int2* __restrict__ staging,
        int* __restrict__ pos, int* __restrict__ csr_src, int cap) {
    int b = blockIdx.x;
    int base = b * cap;
    int cnt = alloc[b] - base;
    if (cnt > cap) cnt = cap;
    for (int i = threadIdx.x; i < cnt; i += 256) {
        int2 sd = staging[base + i];
        int slot = atomicAdd(&pos[sd.y], 1);
        csr_src[slot] = sd.x;
    }
}

// ---------- embedding gather, pre-scaled + bf16 pack ----------
__global__ void embed_kernel(const int* __restrict__ z, const float* __restrict__ z_table,
                             const float* __restrict__ inv_out,
                             uint2* __restrict__ xs, int N) {
    int t = blockIdx.x * blockDim.x + threadIdx.x;
    int n = t >> 5;          // 32 uint2 per row (H=128 bf16)
    int c = t & 31;
    if (n < N) {
        int zz = z[n];
        float w = inv_out[n];
        float4 v = reinterpret_cast<const float4*>(z_table)[(size_t)zz * 32 + c];
        uint2 p;
        p.x = pack_bf16x2(v.x * w, v.y * w);
        p.y = pack_bf16x2(v.z * w, v.w * w);
        xs[(size_t)n * 32 + c] = p;
    }
}

// ---------- pull-based GraphConv, bf16 features, 8-way unrolled, 2 waves/block ----------
// xs is bf16x2-packed, PRE-SCALED by inv_out. Lane handles cols {2*lane, 2*lane+1}.
// mode 0: out_bf = pack(relu(acc*inv_in+b)*inv_out)   (feeds next conv)
// mode 1: out_f32 = acc*inv_in+b                      (final layer, feeds MLP)
__global__ __launch_bounds__(128) void conv_kernel(
        const unsigned* __restrict__ xs, unsigned* __restrict__ out_bf,
        float* __restrict__ out_f32,
        const int* __restrict__ row_ptr, const int* __restrict__ csr_src,
        const float* __restrict__ inv_out, const float* __restrict__ inv_in,
        const float* __restrict__ bias, int N, int mode) {
    int gtid = blockIdx.x * blockDim.x + threadIdx.x;
    int n = gtid >> 6;       // wave per node
    int lane = threadIdx.x & 63;
    if (n >= N) return;

    int start = row_ptr[n];
    int end   = row_ptr[n + 1];

    float ax0 = 0.f, ay0 = 0.f, ax1 = 0.f, ay1 = 0.f;
    float ax2 = 0.f, ay2 = 0.f, ax3 = 0.f, ay3 = 0.f;
    float ax4 = 0.f, ay4 = 0.f, ax5 = 0.f, ay5 = 0.f;
    float ax6 = 0.f, ay6 = 0.f, ax7 = 0.f, ay7 = 0.f;
    int e = start;
    for (; e + 8 <= end; e += 8) {
        int s0 = csr_src[e + 0], s1 = csr_src[e + 1];
        int s2 = csr_src[e + 2], s3 = csr_src[e + 3];
        int s4 = csr_src[e + 4], s5 = csr_src[e + 5];
        int s6 = csr_src[e + 6], s7 = csr_src[e + 7];
        unsigned v0 = xs[(size_t)s0 * 64 + lane];
        unsigned v1 = xs[(size_t)s1 * 64 + lane];
        unsigned v2 = xs[(size_t)s2 * 64 + lane];
        unsigned v3 = xs[(size_t)s3 * 64 + lane];
        unsigned v4 = xs[(size_t)s4 * 64 + lane];
        unsigned v5 = xs[(size_t)s5 * 64 + lane];
        unsigned v6 = xs[(size_t)s6 * 64 + lane];
        unsigned v7 = xs[(size_t)s7 * 64 + lane];
        ax0 += bf16_lo(v0); ay0 += bf16_hi(v0);
        ax1 += bf16_lo(v1); ay1 += bf16_hi(v1);
        ax2 += bf16_lo(v2); ay2 += bf16_hi(v2);
        ax3 += bf16_lo(v3); ay3 += bf16_hi(v3);
        ax4 += bf16_lo(v4); ay4 += bf16_hi(v4);
        ax5 += bf16_lo(v5); ay5 += bf16_hi(v5);
        ax6 += bf16_lo(v6); ay6 += bf16_hi(v6);
        ax7 += bf16_lo(v7); ay7 += bf16_hi(v7);
    }
    if (e + 4 <= end) {
        int s0 = csr_src[e + 0], s1 = csr_src[e + 1];
        int s2 = csr_src[e + 2], s3 = csr_src[e + 3];
        unsigned v0 = xs[(size_t)s0 * 64 + lane];
        unsigned v1 = xs[(size_t)s1 * 64 + lane];
        unsigned v2 = xs[(size_t)s2 * 64 + lane];
        unsigned v3 = xs[(size_t)s3 * 64 + lane];
        ax0 += bf16_lo(v0); ay0 += bf16_hi(v0);
        ax1 += bf16_lo(v1); ay1 += bf16_hi(v1);
        ax2 += bf16_lo(v2); ay2 += bf16_hi(v2);
        ax3 += bf16_lo(v3); ay3 += bf16_hi(v3);
        e += 4;
    }
    for (; e < end; ++e) {
        unsigned v = xs[(size_t)csr_src[e] * 64 + lane];
        ax0 += bf16_lo(v); ay0 += bf16_hi(v);
    }
    float accx = ((ax0 + ax1) + (ax2 + ax3)) + ((ax4 + ax5) + (ax6 + ax7));
    float accy = ((ay0 + ay1) + (ay2 + ay3)) + ((ay4 + ay5) + (ay6 + ay7));

    float win = inv_in[n];
    float2 b = reinterpret_cast<const float2*>(bias)[lane];
    float ox = accx * win + b.x;
    float oy = accy * win + b.y;
    if (mode == 0) {
        float wout = inv_out[n];
        ox = fmaxf(ox, 0.0f) * wout;
        oy = fmaxf(oy, 0.0f) * wout;
        out_bf[(size_t)n * 64 + lane] = pack_bf16x2(ox, oy);
    } else {
        reinterpret_cast<float2*>(out_f32 + (size_t)n * HDIM)[lane] = make_float2(ox, oy);
    }
}

// ---------- center pooling + 2-layer MLP: one block (128 thr) per pair ----------
__global__ __launch_bounds__(128) void mlp_kernel(
        const float* __restrict__ x, const int* __restrict__ pairs,
        const float* __restrict__ W1, const float* __restrict__ b1,
        const float* __restrict__ W2, const float* __restrict__ b2,
        float* __restrict__ out, int B) {
    __shared__ float xp[HDIM];
    __shared__ float red[HDIM];
    int p = blockIdx.x;
    int t = threadIdx.x;
    int a = pairs[p];
    int bnode = pairs[B + p];
    xp[t] = x[(size_t)a * HDIM + t] * x[(size_t)bnode * HDIM + t];
    __syncthreads();
    float h = b1[t];
    #pragma unroll 8
    for (int k = 0; k < HDIM; ++k) h += xp[k] * W1[k * HDIM + t];
    h = fmaxf(h, 0.0f);
    red[t] = h * W2[t];
    __syncthreads();
    for (int s = 64; s > 0; s >>= 1) {
        if (t < s) red[t] += red[t + s];
        __syncthreads();
    }
    if (t == 0) out[p] = red[0] + b2[0];
}

extern "C" void kernel_launch(void* const* d_in, const int* in_sizes, int n_in,
                              void* d_out, int out_size, void* d_ws, size_t ws_size,
                              hipStream_t stream) {
    const int*   z       = (const int*)d_in[0];
    const int*   src     = (const int*)d_in[1];
    const int*   dst     = (const int*)d_in[2];
    const int*   pairs   = (const int*)d_in[3];
    const float* z_table = (const float*)d_in[4];
    const float* bias[3] = {(const float*)d_in[5], (const float*)d_in[6], (const float*)d_in[7]};
    const float* W1      = (const float*)d_in[8];
    const float* b1      = (const float*)d_in[9];
    const float* W2      = (const float*)d_in[10];
    const float* b2      = (const float*)d_in[11];

    const int N = in_sizes[0];
    const int E = in_sizes[1];
    const int B = in_sizes[3] / 2;
    const int nblk = (N + SCAN_CHUNK - 1) / SCAN_CHUNK;

    char* ws = (char*)d_ws;
    size_t off = 0;
    auto carve = [&](size_t bytes) -> void* {
        void* p = ws + off;
        off = (off + bytes + 255) & ~(size_t)255;
        return p;
    };
    int*      deg_out = (int*)carve((size_t)N * 4);
    int*      deg_in  = (int*)carve((size_t)N * 4);
    float*    inv_out = (float*)carve((size_t)N * 4);
    float*    inv_in  = (float*)carve((size_t)N * 4);
    int*      row_ptr = (int*)carve((size_t)(N + 1) * 4);
    int*      pos     = (int*)carve((size_t)N * 4);
    int*      blk_sum = (int*)carve((size_t)nblk * 4);
    int*      blk_off = (int*)carve((size_t)nblk * 4);
    int*      csr_src = (int*)carve((size_t)E * 4);
    unsigned* xb      = (unsigned*)carve((size_t)N * 64 * 4);   // bf16x2 [N][64]
    unsigned* mbuf    = (unsigned*)carve((size_t)N * 64 * 4);   // bf16x2 [N][64]
    float*    xf      = (float*)carve((size_t)N * HDIM * 4);    // f32 final features

    // radix-partition fill extras (appended; base layout unchanged)
    const int mean = (E + NBUK - 1) / NBUK;
    const int cap  = (int)((((size_t)mean * 2) + 255) / 256) * 256;   // 2x headroom
    int*  alloc   = (int*)carve((size_t)NBUK * 4);
    int2* staging = (int2*)carve((size_t)NBUK * (size_t)cap * 8);
    const bool use_part = (off <= ws_size);

    hipMemsetAsync(deg_out, 0, (size_t)N * 4, stream);
    hipMemsetAsync(deg_in,  0, (size_t)N * 4, stream);

    deg_kernel<<<(E + 255) / 256, 256, 0, stream>>>(src, dst, deg_out, deg_in, E);
    inv_kernel<<<(N + 255) / 256, 256, 0, stream>>>(deg_out, deg_in, inv_out, inv_in, N);

    scan_blk_sum<<<nblk, 1024, 0, stream>>>(deg_in, blk_sum, N);
    scan_blk_off<<<1, 128, 0, stream>>>(blk_sum, blk_off, nblk);
    scan_apply<<<nblk, 1024, 0, stream>>>(deg_in, blk_off, row_ptr, pos, N);

    if (use_part) {
        const int edges_per_block = 1024 * PART_EPT;
        const int pblocks = (E + edges_per_block - 1) / edges_per_block;
        init_alloc_kernel<<<1, NBUK, 0, stream>>>(alloc, cap);
        partition_kernel<<<pblocks, 1024, 0, stream>>>(src, dst, alloc, staging, E, N, cap);
        scatter_kernel<<<NBUK, 256, 0, stream>>>(alloc, staging, pos, csr_src, cap);
    } else {
        fill_kernel<<<(E + 255) / 256, 256, 0, stream>>>(src, dst, pos, csr_src, E);
    }

    embed_kernel<<<((size_t)N * 32 + 255) / 256, 256, 0, stream>>>(
        z, z_table, inv_out, (uint2*)xb, N);

    unsigned* cur = xb;
    unsigned* nxt = mbuf;
    long long threads = (long long)N * 64;
    for (int layer = 0; layer < 3; ++layer) {
        int mode = (layer < 2) ? 0 : 1;
        conv_kernel<<<(threads + 127) / 128, 128, 0, stream>>>(
            cur, nxt, xf, row_ptr, csr_src, inv_out, inv_in, bias[layer], N, mode);
        unsigned* tmp = cur; cur = nxt; nxt = tmp;
    }

    mlp_kernel<<<B, 128, 0, stream>>>(xf, pairs, W1, b1, W2, b2, (float*)d_out, B);
}

// Round 10
// 312.908 us; speedup vs baseline: 2.7923x; 1.3340x over previous
//
#include <hip/hip_runtime.h>

#define HDIM 128
#define SCAN_CHUNK 1024
#define NBUK 256          // range buckets for radix partition
#define PART_EPT 2        // edges per thread in partition kernel

// ---------- bf16x2 pack/unpack (RNE) ----------
__device__ inline unsigned pack_bf16x2(float a, float b) {
    unsigned ua = __float_as_uint(a);
    unsigned ub = __float_as_uint(b);
    ua = (ua + 0x7FFFu + ((ua >> 16) & 1u)) >> 16;
    ub = (ub + 0x7FFFu + ((ub >> 16) & 1u)) >> 16;
    return ua | (ub << 16);
}
__device__ inline float bf16_lo(unsigned v) { return __uint_as_float(v << 16); }
__device__ inline float bf16_hi(unsigned v) { return __uint_as_float(v & 0xFFFF0000u); }

// ---------- fallback: degree histogram via global atomics ----------
__global__ void deg_kernel(const int* __restrict__ src, const int* __restrict__ dst,
                           int* __restrict__ deg_out, int* __restrict__ deg_in, int E) {
    int e = blockIdx.x * blockDim.x + threadIdx.x;
    if (e < E) {
        atomicAdd(&deg_out[src[e]], 1);
        atomicAdd(&deg_in[dst[e]], 1);
    }
}

// ---------- inverse-sqrt degree ----------
__global__ void inv_kernel(const int* __restrict__ deg_out, const int* __restrict__ deg_in,
                           float* __restrict__ inv_out, float* __restrict__ inv_in, int N) {
    int n = blockIdx.x * blockDim.x + threadIdx.x;
    if (n < N) {
        float dO = (float)(deg_out[n] > 1 ? deg_out[n] : 1);
        float dI = (float)(deg_in[n]  > 1 ? deg_in[n]  : 1);
        inv_out[n] = 1.0f / sqrtf(dO);
        inv_in[n]  = 1.0f / sqrtf(dI);
    }
}

// ---------- hierarchical scan pass 1: per-block sums ----------
__global__ __launch_bounds__(1024) void scan_blk_sum(const int* __restrict__ deg,
                                                     int* __restrict__ blk_sum, int n) {
    __shared__ int red[1024];
    int tid = threadIdx.x;
    int i = blockIdx.x * SCAN_CHUNK + tid;
    red[tid] = (i < n) ? deg[i] : 0;
    __syncthreads();
    for (int s = 512; s > 0; s >>= 1) {
        if (tid < s) red[tid] += red[tid + s];
        __syncthreads();
    }
    if (tid == 0) blk_sum[blockIdx.x] = red[0];
}

// ---------- hierarchical scan pass 2: exclusive scan of block sums (nblk <= 128) ----------
__global__ __launch_bounds__(128) void scan_blk_off(const int* __restrict__ blk_sum,
                                                    int* __restrict__ blk_off, int nblk) {
    __shared__ int buf[128];
    int tid = threadIdx.x;
    int v = (tid < nblk) ? blk_sum[tid] : 0;
    buf[tid] = v;
    __syncthreads();
    for (int offset = 1; offset < 128; offset <<= 1) {
        int t = (tid >= offset) ? buf[tid - offset] : 0;
        __syncthreads();
        buf[tid] += t;
        __syncthreads();
    }
    if (tid < nblk) blk_off[tid] = buf[tid] - v;   // exclusive
}

// ---------- hierarchical scan pass 3: per-block inclusive scan + offset ----------
__global__ __launch_bounds__(1024) void scan_apply(const int* __restrict__ deg,
                                                   const int* __restrict__ blk_off,
                                                   int* __restrict__ row_ptr,
                                                   int* __restrict__ pos, int n) {
    __shared__ int buf[1024];
    int tid = threadIdx.x;
    int i = blockIdx.x * SCAN_CHUNK + tid;
    int v = (i < n) ? deg[i] : 0;
    buf[tid] = v;
    __syncthreads();
    for (int offset = 1; offset < 1024; offset <<= 1) {
        int t = (tid >= offset) ? buf[tid - offset] : 0;
        __syncthreads();
        buf[tid] += t;
        __syncthreads();
    }
    int base = blk_off[blockIdx.x];
    if (i < n) {
        int incl = base + buf[tid];
        row_ptr[i + 1] = incl;
        pos[i] = incl - v;
    }
    if (i == 0) row_ptr[0] = 0;
}

// ---------- fallback: plain scatter fill ----------
__global__ void fill_kernel(const int* __restrict__ src, const int* __restrict__ dst,
                            int* __restrict__ pos, int* __restrict__ csr_src, int E) {
    int e = blockIdx.x * blockDim.x + threadIdx.x;
    if (e < E) {
        int d = dst[e];
        int idx = atomicAdd(&pos[d], 1);
        csr_src[idx] = src[e];
    }
}

// ---------- radix-partition: init bucket allocators ----------
__global__ void init_alloc_kernel(int* __restrict__ alloc, int* __restrict__ alloc2, int cap) {
    int i = threadIdx.x;        // one block of NBUK threads
    alloc[i]  = i * cap;
    alloc2[i] = i * cap;
}

// ---------- radix partition: dst-bucketed (src,dst) int2 + src-bucketed src int ----------
// LDS histogram gives in-block rank; ONE global atomic per bucket per block
// claims a contiguous chunk; writes are dense within chunks (near-full lines).
__global__ __launch_bounds__(1024) void partition_kernel(
        const int* __restrict__ src, const int* __restrict__ dst,
        int* __restrict__ alloc, int* __restrict__ alloc2,
        int2* __restrict__ staging, int* __restrict__ staging2,
        int E, int N, int cap) {
    __shared__ int lcnt[NBUK];
    __shared__ int lbase[NBUK];
    __shared__ int lcnt2[NBUK];
    __shared__ int lbase2[NBUK];
    int tid = threadIdx.x;
    if (tid < NBUK) { lcnt[tid] = 0; lcnt2[tid] = 0; }
    __syncthreads();
    int base_e = blockIdx.x * (1024 * PART_EPT);
    int s[PART_EPT], d[PART_EPT], bk[PART_EPT], rk[PART_EPT], bs[PART_EPT], rs[PART_EPT];
    #pragma unroll
    for (int j = 0; j < PART_EPT; ++j) {
        int e = base_e + j * 1024 + tid;    // coalesced
        if (e < E) {
            s[j] = src[e];
            d[j] = dst[e];
            bk[j] = (int)(((long long)d[j] * NBUK) / N);
            rk[j] = atomicAdd(&lcnt[bk[j]], 1);
            bs[j] = (int)(((long long)s[j] * NBUK) / N);
            rs[j] = atomicAdd(&lcnt2[bs[j]], 1);
        } else {
            bk[j] = -1;
        }
    }
    __syncthreads();
    if (tid < NBUK) {
        int c = lcnt[tid];
        lbase[tid] = (c > 0) ? atomicAdd(&alloc[tid], c) : 0;
        int c2 = lcnt2[tid];
        lbase2[tid] = (c2 > 0) ? atomicAdd(&alloc2[tid], c2) : 0;
    }
    __syncthreads();
    #pragma unroll
    for (int j = 0; j < PART_EPT; ++j) {
        if (bk[j] >= 0) {
            int idx = lbase[bk[j]] + rk[j];
            if (idx < (bk[j] + 1) * cap)    // overflow clamp (>=24 sigma headroom)
                staging[idx] = make_int2(s[j], d[j]);
            int idx2 = lbase2[bs[j]] + rs[j];
            if (idx2 < (bs[j] + 1) * cap)
                staging2[idx2] = s[j];
        }
    }
}

// ---------- per-bucket degree histograms from staged data ----------
// Bucket b covers nodes [ceil(b*N/256), ceil((b+1)*N/256)) — window <= 391.
// LDS histogram + dense full-line write of the deg window.
__global__ __launch_bounds__(256) void hist_in_kernel(
        const int* __restrict__ alloc, const int2* __restrict__ staging,
        int* __restrict__ deg_in, int cap, int N) {
    __shared__ int h[400];
    int b = blockIdx.x;
    int lo = (b * N + NBUK - 1) / NBUK;
    int hi = ((b + 1) * N + NBUK - 1) / NBUK;
    if (hi > N) hi = N;
    int w = hi - lo;
    for (int t = threadIdx.x; t < w; t += 256) h[t] = 0;
    __syncthreads();
    int base = b * cap;
    int cnt = alloc[b] - base; if (cnt > cap) cnt = cap;
    for (int i = threadIdx.x; i < cnt; i += 256)
        atomicAdd(&h[staging[base + i].y - lo], 1);
    __syncthreads();
    for (int t = threadIdx.x; t < w; t += 256) deg_in[lo + t] = h[t];
}

__global__ __launch_bounds__(256) void hist_out_kernel(
        const int* __restrict__ alloc2, const int* __restrict__ staging2,
        int* __restrict__ deg_out, int cap, int N) {
    __shared__ int h[400];
    int b = blockIdx.x;
    int lo = (b * N + NBUK - 1) / NBUK;
    int hi = ((b + 1) * N + NBUK - 1) / NBUK;
    if (hi > N) hi = N;
    int w = hi - lo;
    for (int t = threadIdx.x; t < w; t += 256) h[t] = 0;
    __syncthreads();
    int base = b * cap;
    int cnt = alloc2[b] - base; if (cnt > cap) cnt = cap;
    for (int i = threadIdx.x; i < cnt; i += 256)
        atomicAdd(&h[staging2[base + i] - lo], 1);
    __syncthreads();
    for (int t = threadIdx.x; t < w; t += 256) deg_out[lo + t] = h[t];
}

// ---------- radix fill phase 2: per-bucket window-local scatter ----------
__global__ __launch_bounds__(256) void scatter_kernel(
        const int* __restrict__ alloc, const int2* __restrict__ staging,
        int* __restrict__ pos, int* __restrict__ csr_src, int cap) {
    int b = blockIdx.x;
    int base = b * cap;
    int cnt = alloc[b] - base;
    if (cnt > cap) cnt = cap;
    for (int i = threadIdx.x; i < cnt; i += 256) {
        int2 sd = staging[base + i];
        int slot = atomicAdd(&pos[sd.y], 1);
        csr_src[slot] = sd.x;
    }
}

// ---------- embedding gather, pre-scaled + bf16 pack ----------
__global__ void embed_kernel(const int* __restrict__ z, const float* __restrict__ z_table,
                             const float* __restrict__ inv_out,
                             uint2* __restrict__ xs, int N) {
    int t = blockIdx.x * blockDim.x + threadIdx.x;
    int n = t >> 5;          // 32 uint2 per row (H=128 bf16)
    int c = t & 31;
    if (n < N) {
        int zz = z[n];
        float w = inv_out[n];
        float4 v = reinterpret_cast<const float4*>(z_table)[(size_t)zz * 32 + c];
        uint2 p;
        p.x = pack_bf16x2(v.x * w, v.y * w);
        p.y = pack_bf16x2(v.z * w, v.w * w);
        xs[(size_t)n * 32 + c] = p;
    }
}

// ---------- pull-based GraphConv, bf16 features, 8-way unrolled, 2 waves/block ----------
// xs is bf16x2-packed, PRE-SCALED by inv_out. Lane handles cols {2*lane, 2*lane+1}.
// mode 0: out_bf = pack(relu(acc*inv_in+b)*inv_out)   (feeds next conv)
// mode 1: out_f32 = acc*inv_in+b                      (final layer, feeds MLP)
__global__ __launch_bounds__(128) void conv_kernel(
        const unsigned* __restrict__ xs, unsigned* __restrict__ out_bf,
        float* __restrict__ out_f32,
        const int* __restrict__ row_ptr, const int* __restrict__ csr_src,
        const float* __restrict__ inv_out, const float* __restrict__ inv_in,
        const float* __restrict__ bias, int N, int mode) {
    int gtid = blockIdx.x * blockDim.x + threadIdx.x;
    int n = gtid >> 6;       // wave per node
    int lane = threadIdx.x & 63;
    if (n >= N) return;

    int start = row_ptr[n];
    int end   = row_ptr[n + 1];

    float ax0 = 0.f, ay0 = 0.f, ax1 = 0.f, ay1 = 0.f;
    float ax2 = 0.f, ay2 = 0.f, ax3 = 0.f, ay3 = 0.f;
    float ax4 = 0.f, ay4 = 0.f, ax5 = 0.f, ay5 = 0.f;
    float ax6 = 0.f, ay6 = 0.f, ax7 = 0.f, ay7 = 0.f;
    int e = start;
    for (; e + 8 <= end; e += 8) {
        int s0 = csr_src[e + 0], s1 = csr_src[e + 1];
        int s2 = csr_src[e + 2], s3 = csr_src[e + 3];
        int s4 = csr_src[e + 4], s5 = csr_src[e + 5];
        int s6 = csr_src[e + 6], s7 = csr_src[e + 7];
        unsigned v0 = xs[(size_t)s0 * 64 + lane];
        unsigned v1 = xs[(size_t)s1 * 64 + lane];
        unsigned v2 = xs[(size_t)s2 * 64 + lane];
        unsigned v3 = xs[(size_t)s3 * 64 + lane];
        unsigned v4 = xs[(size_t)s4 * 64 + lane];
        unsigned v5 = xs[(size_t)s5 * 64 + lane];
        unsigned v6 = xs[(size_t)s6 * 64 + lane];
        unsigned v7 = xs[(size_t)s7 * 64 + lane];
        ax0 += bf16_lo(v0); ay0 += bf16_hi(v0);
        ax1 += bf16_lo(v1); ay1 += bf16_hi(v1);
        ax2 += bf16_lo(v2); ay2 += bf16_hi(v2);
        ax3 += bf16_lo(v3); ay3 += bf16_hi(v3);
        ax4 += bf16_lo(v4); ay4 += bf16_hi(v4);
        ax5 += bf16_lo(v5); ay5 += bf16_hi(v5);
        ax6 += bf16_lo(v6); ay6 += bf16_hi(v6);
        ax7 += bf16_lo(v7); ay7 += bf16_hi(v7);
    }
    if (e + 4 <= end) {
        int s0 = csr_src[e + 0], s1 = csr_src[e + 1];
        int s2 = csr_src[e + 2], s3 = csr_src[e + 3];
        unsigned v0 = xs[(size_t)s0 * 64 + lane];
        unsigned v1 = xs[(size_t)s1 * 64 + lane];
        unsigned v2 = xs[(size_t)s2 * 64 + lane];
        unsigned v3 = xs[(size_t)s3 * 64 + lane];
        ax0 += bf16_lo(v0); ay0 += bf16_hi(v0);
        ax1 += bf16_lo(v1); ay1 += bf16_hi(v1);
        ax2 += bf16_lo(v2); ay2 += bf16_hi(v2);
        ax3 += bf16_lo(v3); ay3 += bf16_hi(v3);
        e += 4;
    }
    for (; e < end; ++e) {
        unsigned v = xs[(size_t)csr_src[e] * 64 + lane];
        ax0 += bf16_lo(v); ay0 += bf16_hi(v);
    }
    float accx = ((ax0 + ax1) + (ax2 + ax3)) + ((ax4 + ax5) + (ax6 + ax7));
    float accy = ((ay0 + ay1) + (ay2 + ay3)) + ((ay4 + ay5) + (ay6 + ay7));

    float win = inv_in[n];
    float2 b = reinterpret_cast<const float2*>(bias)[lane];
    float ox = accx * win + b.x;
    float oy = accy * win + b.y;
    if (mode == 0) {
        float wout = inv_out[n];
        ox = fmaxf(ox, 0.0f) * wout;
        oy = fmaxf(oy, 0.0f) * wout;
        out_bf[(size_t)n * 64 + lane] = pack_bf16x2(ox, oy);
    } else {
        reinterpret_cast<float2*>(out_f32 + (size_t)n * HDIM)[lane] = make_float2(ox, oy);
    }
}

// ---------- center pooling + 2-layer MLP: one block (128 thr) per pair ----------
__global__ __launch_bounds__(128) void mlp_kernel(
        const float* __restrict__ x, const int* __restrict__ pairs,
        const float* __restrict__ W1, const float* __restrict__ b1,
        const float* __restrict__ W2, const float* __restrict__ b2,
        float* __restrict__ out, int B) {
    __shared__ float xp[HDIM];
    __shared__ float red[HDIM];
    int p = blockIdx.x;
    int t = threadIdx.x;
    int a = pairs[p];
    int bnode = pairs[B + p];
    xp[t] = x[(size_t)a * HDIM + t] * x[(size_t)bnode * HDIM + t];
    __syncthreads();
    float h = b1[t];
    #pragma unroll 8
    for (int k = 0; k < HDIM; ++k) h += xp[k] * W1[k * HDIM + t];
    h = fmaxf(h, 0.0f);
    red[t] = h * W2[t];
    __syncthreads();
    for (int s = 64; s > 0; s >>= 1) {
        if (t < s) red[t] += red[t + s];
        __syncthreads();
    }
    if (t == 0) out[p] = red[0] + b2[0];
}

extern "C" void kernel_launch(void* const* d_in, const int* in_sizes, int n_in,
                              void* d_out, int out_size, void* d_ws, size_t ws_size,
                              hipStream_t stream) {
    const int*   z       = (const int*)d_in[0];
    const int*   src     = (const int*)d_in[1];
    const int*   dst     = (const int*)d_in[2];
    const int*   pairs   = (const int*)d_in[3];
    const float* z_table = (const float*)d_in[4];
    const float* bias[3] = {(const float*)d_in[5], (const float*)d_in[6], (const float*)d_in[7]};
    const float* W1      = (const float*)d_in[8];
    const float* b1      = (const float*)d_in[9];
    const float* W2      = (const float*)d_in[10];
    const float* b2      = (const float*)d_in[11];

    const int N = in_sizes[0];
    const int E = in_sizes[1];
    const int B = in_sizes[3] / 2;
    const int nblk = (N + SCAN_CHUNK - 1) / SCAN_CHUNK;

    char* ws = (char*)d_ws;
    size_t off = 0;
    auto carve = [&](size_t bytes) -> void* {
        void* p = ws + off;
        off = (off + bytes + 255) & ~(size_t)255;
        return p;
    };
    int*      deg_out = (int*)carve((size_t)N * 4);
    int*      deg_in  = (int*)carve((size_t)N * 4);
    float*    inv_out = (float*)carve((size_t)N * 4);
    float*    inv_in  = (float*)carve((size_t)N * 4);
    int*      row_ptr = (int*)carve((size_t)(N + 1) * 4);
    int*      pos     = (int*)carve((size_t)N * 4);
    int*      blk_sum = (int*)carve((size_t)nblk * 4);
    int*      blk_off = (int*)carve((size_t)nblk * 4);
    int*      csr_src = (int*)carve((size_t)E * 4);
    unsigned* xb      = (unsigned*)carve((size_t)N * 64 * 4);   // bf16x2 [N][64]
    unsigned* mbuf    = (unsigned*)carve((size_t)N * 64 * 4);   // bf16x2 [N][64]
    float*    xf      = (float*)carve((size_t)N * HDIM * 4);    // f32 final features

    // radix-partition extras (appended; base layout unchanged)
    const int mean = (E + NBUK - 1) / NBUK;
    const int cap  = (int)((((size_t)mean * 2) + 255) / 256) * 256;   // 2x headroom
    int*  alloc    = (int*)carve((size_t)NBUK * 4);
    int*  alloc2   = (int*)carve((size_t)NBUK * 4);
    int2* staging  = (int2*)carve((size_t)NBUK * (size_t)cap * 8);
    int*  staging2 = (int*)carve((size_t)NBUK * (size_t)cap * 4);
    const bool use_part = (off <= ws_size);

    if (use_part) {
        const int edges_per_block = 1024 * PART_EPT;
        const int pblocks = (E + edges_per_block - 1) / edges_per_block;
        init_alloc_kernel<<<1, NBUK, 0, stream>>>(alloc, alloc2, cap);
        partition_kernel<<<pblocks, 1024, 0, stream>>>(
            src, dst, alloc, alloc2, staging, staging2, E, N, cap);
        hist_in_kernel<<<NBUK, 256, 0, stream>>>(alloc, staging, deg_in, cap, N);
        hist_out_kernel<<<NBUK, 256, 0, stream>>>(alloc2, staging2, deg_out, cap, N);
        inv_kernel<<<(N + 255) / 256, 256, 0, stream>>>(deg_out, deg_in, inv_out, inv_in, N);
        scan_blk_sum<<<nblk, 1024, 0, stream>>>(deg_in, blk_sum, N);
        scan_blk_off<<<1, 128, 0, stream>>>(blk_sum, blk_off, nblk);
        scan_apply<<<nblk, 1024, 0, stream>>>(deg_in, blk_off, row_ptr, pos, N);
        scatter_kernel<<<NBUK, 256, 0, stream>>>(alloc, staging, pos, csr_src, cap);
    } else {
        hipMemsetAsync(deg_out, 0, (size_t)N * 4, stream);
        hipMemsetAsync(deg_in,  0, (size_t)N * 4, stream);
        deg_kernel<<<(E + 255) / 256, 256, 0, stream>>>(src, dst, deg_out, deg_in, E);
        inv_kernel<<<(N + 255) / 256, 256, 0, stream>>>(deg_out, deg_in, inv_out, inv_in, N);
        scan_blk_sum<<<nblk, 1024, 0, stream>>>(deg_in, blk_sum, N);
        scan_blk_off<<<1, 128, 0, stream>>>(blk_sum, blk_off, nblk);
        scan_apply<<<nblk, 1024, 0, stream>>>(deg_in, blk_off, row_ptr, pos, N);
        fill_kernel<<<(E + 255) / 256, 256, 0, stream>>>(src, dst, pos, csr_src, E);
    }

    embed_kernel<<<((size_t)N * 32 + 255) / 256, 256, 0, stream>>>(
        z, z_table, inv_out, (uint2*)xb, N);

    unsigned* cur = xb;
    unsigned* nxt = mbuf;
    long long threads = (long long)N * 64;
    for (int layer = 0; layer < 3; ++layer) {
        int mode = (layer < 2) ? 0 : 1;
        conv_kernel<<<(threads + 127) / 128, 128, 0, stream>>>(
            cur, nxt, xf, row_ptr, csr_src, inv_out, inv_in, bias[layer], N, mode);
        unsigned* tmp = cur; cur = nxt; nxt = tmp;
    }

    mlp_kernel<<<B, 128, 0, stream>>>(xf, pairs, W1, b1, W2, b2, (float*)d_out, B);
}

// Round 11
// 275.911 us; speedup vs baseline: 3.1667x; 1.1341x over previous
//
#include <hip/hip_runtime.h>

#define HDIM 128
#define SCAN_CHUNK 1024
#define NBUK 256          // range buckets for radix partition
#define PART_EPT 2        // edges per thread in partition kernel

// ---------- bf16x2 pack/unpack (RNE) ----------
__device__ inline unsigned pack_bf16x2(float a, float b) {
    unsigned ua = __float_as_uint(a);
    unsigned ub = __float_as_uint(b);
    ua = (ua + 0x7FFFu + ((ua >> 16) & 1u)) >> 16;
    ub = (ub + 0x7FFFu + ((ub >> 16) & 1u)) >> 16;
    return ua | (ub << 16);
}
__device__ inline float bf16_lo(unsigned v) { return __uint_as_float(v << 16); }
__device__ inline float bf16_hi(unsigned v) { return __uint_as_float(v & 0xFFFF0000u); }

// ---------- fallback: degree histogram via global atomics ----------
__global__ void deg_kernel(const int* __restrict__ src, const int* __restrict__ dst,
                           int* __restrict__ deg_out, int* __restrict__ deg_in, int E) {
    int e = blockIdx.x * blockDim.x + threadIdx.x;
    if (e < E) {
        atomicAdd(&deg_out[src[e]], 1);
        atomicAdd(&deg_in[dst[e]], 1);
    }
}

// ---------- inverse-sqrt degree ----------
__global__ void inv_kernel(const int* __restrict__ deg_out, const int* __restrict__ deg_in,
                           float* __restrict__ inv_out, float* __restrict__ inv_in, int N) {
    int n = blockIdx.x * blockDim.x + threadIdx.x;
    if (n < N) {
        float dO = (float)(deg_out[n] > 1 ? deg_out[n] : 1);
        float dI = (float)(deg_in[n]  > 1 ? deg_in[n]  : 1);
        inv_out[n] = 1.0f / sqrtf(dO);
        inv_in[n]  = 1.0f / sqrtf(dI);
    }
}

// ---------- hierarchical scan pass 1: per-block sums ----------
__global__ __launch_bounds__(1024) void scan_blk_sum(const int* __restrict__ deg,
                                                     int* __restrict__ blk_sum, int n) {
    __shared__ int red[1024];
    int tid = threadIdx.x;
    int i = blockIdx.x * SCAN_CHUNK + tid;
    red[tid] = (i < n) ? deg[i] : 0;
    __syncthreads();
    for (int s = 512; s > 0; s >>= 1) {
        if (tid < s) red[tid] += red[tid + s];
        __syncthreads();
    }
    if (tid == 0) blk_sum[blockIdx.x] = red[0];
}

// ---------- hierarchical scan pass 2: exclusive scan of block sums (nblk <= 128) ----------
__global__ __launch_bounds__(128) void scan_blk_off(const int* __restrict__ blk_sum,
                                                    int* __restrict__ blk_off, int nblk) {
    __shared__ int buf[128];
    int tid = threadIdx.x;
    int v = (tid < nblk) ? blk_sum[tid] : 0;
    buf[tid] = v;
    __syncthreads();
    for (int offset = 1; offset < 128; offset <<= 1) {
        int t = (tid >= offset) ? buf[tid - offset] : 0;
        __syncthreads();
        buf[tid] += t;
        __syncthreads();
    }
    if (tid < nblk) blk_off[tid] = buf[tid] - v;   // exclusive
}

// ---------- hierarchical scan pass 3: per-block inclusive scan + offset ----------
__global__ __launch_bounds__(1024) void scan_apply(const int* __restrict__ deg,
                                                   const int* __restrict__ blk_off,
                                                   int* __restrict__ row_ptr,
                                                   int* __restrict__ pos, int n) {
    __shared__ int buf[1024];
    int tid = threadIdx.x;
    int i = blockIdx.x * SCAN_CHUNK + tid;
    int v = (i < n) ? deg[i] : 0;
    buf[tid] = v;
    __syncthreads();
    for (int offset = 1; offset < 1024; offset <<= 1) {
        int t = (tid >= offset) ? buf[tid - offset] : 0;
        __syncthreads();
        buf[tid] += t;
        __syncthreads();
    }
    int base = blk_off[blockIdx.x];
    if (i < n) {
        int incl = base + buf[tid];
        row_ptr[i + 1] = incl;
        pos[i] = incl - v;
    }
    if (i == 0) row_ptr[0] = 0;
}

// ---------- fallback: plain scatter fill ----------
__global__ void fill_kernel(const int* __restrict__ src, const int* __restrict__ dst,
                            int* __restrict__ pos, int* __restrict__ csr_src, int E) {
    int e = blockIdx.x * blockDim.x + threadIdx.x;
    if (e < E) {
        int d = dst[e];
        int idx = atomicAdd(&pos[d], 1);
        csr_src[idx] = src[e];
    }
}

// ---------- radix-partition: init bucket allocators ----------
__global__ void init_alloc_kernel(int* __restrict__ alloc, int* __restrict__ alloc2, int cap) {
    int i = threadIdx.x;        // one block of NBUK threads
    alloc[i]  = i * cap;
    alloc2[i] = i * cap;
}

// ---------- radix partition: dst-bucketed (src,dst) int2 + src-bucketed src int ----------
__global__ __launch_bounds__(1024) void partition_kernel(
        const int* __restrict__ src, const int* __restrict__ dst,
        int* __restrict__ alloc, int* __restrict__ alloc2,
        int2* __restrict__ staging, int* __restrict__ staging2,
        int E, int N, int cap) {
    __shared__ int lcnt[NBUK];
    __shared__ int lbase[NBUK];
    __shared__ int lcnt2[NBUK];
    __shared__ int lbase2[NBUK];
    int tid = threadIdx.x;
    if (tid < NBUK) { lcnt[tid] = 0; lcnt2[tid] = 0; }
    __syncthreads();
    int base_e = blockIdx.x * (1024 * PART_EPT);
    int s[PART_EPT], d[PART_EPT], bk[PART_EPT], rk[PART_EPT], bs[PART_EPT], rs[PART_EPT];
    #pragma unroll
    for (int j = 0; j < PART_EPT; ++j) {
        int e = base_e + j * 1024 + tid;    // coalesced
        if (e < E) {
            s[j] = src[e];
            d[j] = dst[e];
            bk[j] = (int)(((long long)d[j] * NBUK) / N);
            rk[j] = atomicAdd(&lcnt[bk[j]], 1);
            bs[j] = (int)(((long long)s[j] * NBUK) / N);
            rs[j] = atomicAdd(&lcnt2[bs[j]], 1);
        } else {
            bk[j] = -1;
        }
    }
    __syncthreads();
    if (tid < NBUK) {
        int c = lcnt[tid];
        lbase[tid] = (c > 0) ? atomicAdd(&alloc[tid], c) : 0;
        int c2 = lcnt2[tid];
        lbase2[tid] = (c2 > 0) ? atomicAdd(&alloc2[tid], c2) : 0;
    }
    __syncthreads();
    #pragma unroll
    for (int j = 0; j < PART_EPT; ++j) {
        if (bk[j] >= 0) {
            int idx = lbase[bk[j]] + rk[j];
            if (idx < (bk[j] + 1) * cap)    // overflow clamp (>=24 sigma headroom)
                staging[idx] = make_int2(s[j], d[j]);
            int idx2 = lbase2[bs[j]] + rs[j];
            if (idx2 < (bs[j] + 1) * cap)
                staging2[idx2] = s[j];
        }
    }
}

// ---------- per-bucket degree histograms from staged data ----------
__global__ __launch_bounds__(256) void hist_in_kernel(
        const int* __restrict__ alloc, const int2* __restrict__ staging,
        int* __restrict__ deg_in, int cap, int N) {
    __shared__ int h[400];
    int b = blockIdx.x;
    int lo = (b * N + NBUK - 1) / NBUK;
    int hi = ((b + 1) * N + NBUK - 1) / NBUK;
    if (hi > N) hi = N;
    int w = hi - lo;
    for (int t = threadIdx.x; t < w; t += 256) h[t] = 0;
    __syncthreads();
    int base = b * cap;
    int cnt = alloc[b] - base; if (cnt > cap) cnt = cap;
    for (int i = threadIdx.x; i < cnt; i += 256)
        atomicAdd(&h[staging[base + i].y - lo], 1);
    __syncthreads();
    for (int t = threadIdx.x; t < w; t += 256) deg_in[lo + t] = h[t];
}

__global__ __launch_bounds__(256) void hist_out_kernel(
        const int* __restrict__ alloc2, const int* __restrict__ staging2,
        int* __restrict__ deg_out, int cap, int N) {
    __shared__ int h[400];
    int b = blockIdx.x;
    int lo = (b * N + NBUK - 1) / NBUK;
    int hi = ((b + 1) * N + NBUK - 1) / NBUK;
    if (hi > N) hi = N;
    int w = hi - lo;
    for (int t = threadIdx.x; t < w; t += 256) h[t] = 0;
    __syncthreads();
    int base = b * cap;
    int cnt = alloc2[b] - base; if (cnt > cap) cnt = cap;
    for (int i = threadIdx.x; i < cnt; i += 256)
        atomicAdd(&h[staging2[base + i] - lo], 1);
    __syncthreads();
    for (int t = threadIdx.x; t < w; t += 256) deg_out[lo + t] = h[t];
}

// ---------- radix fill phase 2: per-bucket window-local scatter ----------
__global__ __launch_bounds__(256) void scatter_kernel(
        const int* __restrict__ alloc, const int2* __restrict__ staging,
        int* __restrict__ pos, int* __restrict__ csr_src, int cap) {
    int b = blockIdx.x;
    int base = b * cap;
    int cnt = alloc[b] - base;
    if (cnt > cap) cnt = cap;
    for (int i = threadIdx.x; i < cnt; i += 256) {
        int2 sd = staging[base + i];
        int slot = atomicAdd(&pos[sd.y], 1);
        csr_src[slot] = sd.x;
    }
}

// ---------- layer-1 conv, FUSED embedding: gathers z_table[z[s]]*inv_out[s] ----------
// z_table (512 KB) is L2-resident on every XCD -> no big feature fetch at all.
// out = pack_bf16( relu(acc*inv_in+b) * inv_out )  (feeds conv2)
__global__ __launch_bounds__(128) void conv1_kernel(
        const int* __restrict__ z, const float* __restrict__ z_table,
        unsigned* __restrict__ out_bf,
        const int* __restrict__ row_ptr, const int* __restrict__ csr_src,
        const float* __restrict__ inv_out, const float* __restrict__ inv_in,
        const float* __restrict__ bias, int N) {
    int gtid = blockIdx.x * blockDim.x + threadIdx.x;
    int n = gtid >> 6;       // wave per node
    int lane = threadIdx.x & 63;
    if (n >= N) return;

    int start = row_ptr[n];
    int end   = row_ptr[n + 1];

    float ax0 = 0.f, ay0 = 0.f, ax1 = 0.f, ay1 = 0.f;
    float ax2 = 0.f, ay2 = 0.f, ax3 = 0.f, ay3 = 0.f;
    int e = start;
    for (; e + 4 <= end; e += 4) {
        int s0 = csr_src[e + 0], s1 = csr_src[e + 1];
        int s2 = csr_src[e + 2], s3 = csr_src[e + 3];
        int z0 = z[s0], z1 = z[s1], z2 = z[s2], z3 = z[s3];
        float w0 = inv_out[s0], w1 = inv_out[s1], w2 = inv_out[s2], w3 = inv_out[s3];
        float2 v0 = reinterpret_cast<const float2*>(z_table + (size_t)z0 * HDIM)[lane];
        float2 v1 = reinterpret_cast<const float2*>(z_table + (size_t)z1 * HDIM)[lane];
        float2 v2 = reinterpret_cast<const float2*>(z_table + (size_t)z2 * HDIM)[lane];
        float2 v3 = reinterpret_cast<const float2*>(z_table + (size_t)z3 * HDIM)[lane];
        ax0 += w0 * v0.x; ay0 += w0 * v0.y;
        ax1 += w1 * v1.x; ay1 += w1 * v1.y;
        ax2 += w2 * v2.x; ay2 += w2 * v2.y;
        ax3 += w3 * v3.x; ay3 += w3 * v3.y;
    }
    for (; e < end; ++e) {
        int s = csr_src[e];
        float w = inv_out[s];
        float2 v = reinterpret_cast<const float2*>(z_table + (size_t)z[s] * HDIM)[lane];
        ax0 += w * v.x; ay0 += w * v.y;
    }
    float accx = (ax0 + ax1) + (ax2 + ax3);
    float accy = (ay0 + ay1) + (ay2 + ay3);

    float win = inv_in[n];
    float2 b = reinterpret_cast<const float2*>(bias)[lane];
    float ox = fmaxf(accx * win + b.x, 0.0f) * inv_out[n];
    float oy = fmaxf(accy * win + b.y, 0.0f) * inv_out[n];
    out_bf[(size_t)n * 64 + lane] = pack_bf16x2(ox, oy);
}

// ---------- layer-2 conv: bf16 -> bf16, 8-way unrolled, 2 waves/block ----------
__global__ __launch_bounds__(128) void conv2_kernel(
        const unsigned* __restrict__ xs, unsigned* __restrict__ out_bf,
        const int* __restrict__ row_ptr, const int* __restrict__ csr_src,
        const float* __restrict__ inv_out, const float* __restrict__ inv_in,
        const float* __restrict__ bias, int N) {
    int gtid = blockIdx.x * blockDim.x + threadIdx.x;
    int n = gtid >> 6;       // wave per node
    int lane = threadIdx.x & 63;
    if (n >= N) return;

    int start = row_ptr[n];
    int end   = row_ptr[n + 1];

    float ax0 = 0.f, ay0 = 0.f, ax1 = 0.f, ay1 = 0.f;
    float ax2 = 0.f, ay2 = 0.f, ax3 = 0.f, ay3 = 0.f;
    float ax4 = 0.f, ay4 = 0.f, ax5 = 0.f, ay5 = 0.f;
    float ax6 = 0.f, ay6 = 0.f, ax7 = 0.f, ay7 = 0.f;
    int e = start;
    for (; e + 8 <= end; e += 8) {
        int s0 = csr_src[e + 0], s1 = csr_src[e + 1];
        int s2 = csr_src[e + 2], s3 = csr_src[e + 3];
        int s4 = csr_src[e + 4], s5 = csr_src[e + 5];
        int s6 = csr_src[e + 6], s7 = csr_src[e + 7];
        unsigned v0 = xs[(size_t)s0 * 64 + lane];
        unsigned v1 = xs[(size_t)s1 * 64 + lane];
        unsigned v2 = xs[(size_t)s2 * 64 + lane];
        unsigned v3 = xs[(size_t)s3 * 64 + lane];
        unsigned v4 = xs[(size_t)s4 * 64 + lane];
        unsigned v5 = xs[(size_t)s5 * 64 + lane];
        unsigned v6 = xs[(size_t)s6 * 64 + lane];
        unsigned v7 = xs[(size_t)s7 * 64 + lane];
        ax0 += bf16_lo(v0); ay0 += bf16_hi(v0);
        ax1 += bf16_lo(v1); ay1 += bf16_hi(v1);
        ax2 += bf16_lo(v2); ay2 += bf16_hi(v2);
        ax3 += bf16_lo(v3); ay3 += bf16_hi(v3);
        ax4 += bf16_lo(v4); ay4 += bf16_hi(v4);
        ax5 += bf16_lo(v5); ay5 += bf16_hi(v5);
        ax6 += bf16_lo(v6); ay6 += bf16_hi(v6);
        ax7 += bf16_lo(v7); ay7 += bf16_hi(v7);
    }
    if (e + 4 <= end) {
        int s0 = csr_src[e + 0], s1 = csr_src[e + 1];
        int s2 = csr_src[e + 2], s3 = csr_src[e + 3];
        unsigned v0 = xs[(size_t)s0 * 64 + lane];
        unsigned v1 = xs[(size_t)s1 * 64 + lane];
        unsigned v2 = xs[(size_t)s2 * 64 + lane];
        unsigned v3 = xs[(size_t)s3 * 64 + lane];
        ax0 += bf16_lo(v0); ay0 += bf16_hi(v0);
        ax1 += bf16_lo(v1); ay1 += bf16_hi(v1);
        ax2 += bf16_lo(v2); ay2 += bf16_hi(v2);
        ax3 += bf16_lo(v3); ay3 += bf16_hi(v3);
        e += 4;
    }
    for (; e < end; ++e) {
        unsigned v = xs[(size_t)csr_src[e] * 64 + lane];
        ax0 += bf16_lo(v); ay0 += bf16_hi(v);
    }
    float accx = ((ax0 + ax1) + (ax2 + ax3)) + ((ax4 + ax5) + (ax6 + ax7));
    float accy = ((ay0 + ay1) + (ay2 + ay3)) + ((ay4 + ay5) + (ay6 + ay7));

    float win = inv_in[n];
    float2 b = reinterpret_cast<const float2*>(bias)[lane];
    float wout = inv_out[n];
    float ox = fmaxf(accx * win + b.x, 0.0f) * wout;
    float oy = fmaxf(accy * win + b.y, 0.0f) * wout;
    out_bf[(size_t)n * 64 + lane] = pack_bf16x2(ox, oy);
}

// ---------- layer-3 conv, PAIR NODES ONLY (M = 2B rows) ----------
// i-th wave computes node plist[i]; writes compact xf[i][128] f32 (no relu).
__global__ __launch_bounds__(128) void conv3_kernel(
        const unsigned* __restrict__ xs, const int* __restrict__ plist,
        float* __restrict__ xf,
        const int* __restrict__ row_ptr, const int* __restrict__ csr_src,
        const float* __restrict__ inv_in, const float* __restrict__ bias, int M) {
    int gtid = blockIdx.x * blockDim.x + threadIdx.x;
    int i = gtid >> 6;
    int lane = threadIdx.x & 63;
    if (i >= M) return;
    int n = plist[i];

    int start = row_ptr[n];
    int end   = row_ptr[n + 1];

    float ax0 = 0.f, ay0 = 0.f, ax1 = 0.f, ay1 = 0.f;
    float ax2 = 0.f, ay2 = 0.f, ax3 = 0.f, ay3 = 0.f;
    int e = start;
    for (; e + 4 <= end; e += 4) {
        int s0 = csr_src[e + 0], s1 = csr_src[e + 1];
        int s2 = csr_src[e + 2], s3 = csr_src[e + 3];
        unsigned v0 = xs[(size_t)s0 * 64 + lane];
        unsigned v1 = xs[(size_t)s1 * 64 + lane];
        unsigned v2 = xs[(size_t)s2 * 64 + lane];
        unsigned v3 = xs[(size_t)s3 * 64 + lane];
        ax0 += bf16_lo(v0); ay0 += bf16_hi(v0);
        ax1 += bf16_lo(v1); ay1 += bf16_hi(v1);
        ax2 += bf16_lo(v2); ay2 += bf16_hi(v2);
        ax3 += bf16_lo(v3); ay3 += bf16_hi(v3);
    }
    for (; e < end; ++e) {
        unsigned v = xs[(size_t)csr_src[e] * 64 + lane];
        ax0 += bf16_lo(v); ay0 += bf16_hi(v);
    }
    float accx = (ax0 + ax1) + (ax2 + ax3);
    float accy = (ay0 + ay1) + (ay2 + ay3);

    float win = inv_in[n];
    float2 b = reinterpret_cast<const float2*>(bias)[lane];
    float ox = accx * win + b.x;
    float oy = accy * win + b.y;
    reinterpret_cast<float2*>(xf + (size_t)i * HDIM)[lane] = make_float2(ox, oy);
}

// ---------- center pooling + 2-layer MLP over compact xf ----------
__global__ __launch_bounds__(128) void mlp_kernel(
        const float* __restrict__ xf,
        const float* __restrict__ W1, const float* __restrict__ b1,
        const float* __restrict__ W2, const float* __restrict__ b2,
        float* __restrict__ out, int B) {
    __shared__ float xp[HDIM];
    __shared__ float red[HDIM];
    int p = blockIdx.x;
    int t = threadIdx.x;
    xp[t] = xf[(size_t)p * HDIM + t] * xf[(size_t)(B + p) * HDIM + t];
    __syncthreads();
    float h = b1[t];
    #pragma unroll 8
    for (int k = 0; k < HDIM; ++k) h += xp[k] * W1[k * HDIM + t];
    h = fmaxf(h, 0.0f);
    red[t] = h * W2[t];
    __syncthreads();
    for (int s = 64; s > 0; s >>= 1) {
        if (t < s) red[t] += red[t + s];
        __syncthreads();
    }
    if (t == 0) out[p] = red[0] + b2[0];
}

extern "C" void kernel_launch(void* const* d_in, const int* in_sizes, int n_in,
                              void* d_out, int out_size, void* d_ws, size_t ws_size,
                              hipStream_t stream) {
    const int*   z       = (const int*)d_in[0];
    const int*   src     = (const int*)d_in[1];
    const int*   dst     = (const int*)d_in[2];
    const int*   pairs   = (const int*)d_in[3];
    const float* z_table = (const float*)d_in[4];
    const float* bias[3] = {(const float*)d_in[5], (const float*)d_in[6], (const float*)d_in[7]};
    const float* W1      = (const float*)d_in[8];
    const float* b1      = (const float*)d_in[9];
    const float* W2      = (const float*)d_in[10];
    const float* b2      = (const float*)d_in[11];

    const int N = in_sizes[0];
    const int E = in_sizes[1];
    const int B = in_sizes[3] / 2;
    const int M = 2 * B;                       // pair-node list length
    const int nblk = (N + SCAN_CHUNK - 1) / SCAN_CHUNK;

    char* ws = (char*)d_ws;
    size_t off = 0;
    auto carve = [&](size_t bytes) -> void* {
        void* p = ws + off;
        off = (off + bytes + 255) & ~(size_t)255;
        return p;
    };
    int*      deg_out = (int*)carve((size_t)N * 4);
    int*      deg_in  = (int*)carve((size_t)N * 4);
    float*    inv_out = (float*)carve((size_t)N * 4);
    float*    inv_in  = (float*)carve((size_t)N * 4);
    int*      row_ptr = (int*)carve((size_t)(N + 1) * 4);
    int*      pos     = (int*)carve((size_t)N * 4);
    int*      blk_sum = (int*)carve((size_t)nblk * 4);
    int*      blk_off = (int*)carve((size_t)nblk * 4);
    int*      csr_src = (int*)carve((size_t)E * 4);
    unsigned* xb      = (unsigned*)carve((size_t)N * 64 * 4);   // bf16x2 [N][64]
    unsigned* mbuf    = (unsigned*)carve((size_t)N * 64 * 4);   // bf16x2 [N][64]
    float*    xf      = (float*)carve((size_t)M * HDIM * 4);    // compact pair features

    // radix-partition extras (appended; base layout unchanged)
    const int mean = (E + NBUK - 1) / NBUK;
    const int cap  = (int)((((size_t)mean * 2) + 255) / 256) * 256;   // 2x headroom
    int*  alloc    = (int*)carve((size_t)NBUK * 4);
    int*  alloc2   = (int*)carve((size_t)NBUK * 4);
    int2* staging  = (int2*)carve((size_t)NBUK * (size_t)cap * 8);
    int*  staging2 = (int*)carve((size_t)NBUK * (size_t)cap * 4);
    const bool use_part = (off <= ws_size);

    if (use_part) {
        const int edges_per_block = 1024 * PART_EPT;
        const int pblocks = (E + edges_per_block - 1) / edges_per_block;
        init_alloc_kernel<<<1, NBUK, 0, stream>>>(alloc, alloc2, cap);
        partition_kernel<<<pblocks, 1024, 0, stream>>>(
            src, dst, alloc, alloc2, staging, staging2, E, N, cap);
        hist_in_kernel<<<NBUK, 256, 0, stream>>>(alloc, staging, deg_in, cap, N);
        hist_out_kernel<<<NBUK, 256, 0, stream>>>(alloc2, staging2, deg_out, cap, N);
        inv_kernel<<<(N + 255) / 256, 256, 0, stream>>>(deg_out, deg_in, inv_out, inv_in, N);
        scan_blk_sum<<<nblk, 1024, 0, stream>>>(deg_in, blk_sum, N);
        scan_blk_off<<<1, 128, 0, stream>>>(blk_sum, blk_off, nblk);
        scan_apply<<<nblk, 1024, 0, stream>>>(deg_in, blk_off, row_ptr, pos, N);
        scatter_kernel<<<NBUK, 256, 0, stream>>>(alloc, staging, pos, csr_src, cap);
    } else {
        hipMemsetAsync(deg_out, 0, (size_t)N * 4, stream);
        hipMemsetAsync(deg_in,  0, (size_t)N * 4, stream);
        deg_kernel<<<(E + 255) / 256, 256, 0, stream>>>(src, dst, deg_out, deg_in, E);
        inv_kernel<<<(N + 255) / 256, 256, 0, stream>>>(deg_out, deg_in, inv_out, inv_in, N);
        scan_blk_sum<<<nblk, 1024, 0, stream>>>(deg_in, blk_sum, N);
        scan_blk_off<<<1, 128, 0, stream>>>(blk_sum, blk_off, nblk);
        scan_apply<<<nblk, 1024, 0, stream>>>(deg_in, blk_off, row_ptr, pos, N);
        fill_kernel<<<(E + 255) / 256, 256, 0, stream>>>(src, dst, pos, csr_src, E);
    }

    long long threads = (long long)N * 64;
    conv1_kernel<<<(threads + 127) / 128, 128, 0, stream>>>(
        z, z_table, xb, row_ptr, csr_src, inv_out, inv_in, bias[0], N);
    conv2_kernel<<<(threads + 127) / 128, 128, 0, stream>>>(
        xb, mbuf, row_ptr, csr_src, inv_out, inv_in, bias[1], N);
    long long pthreads = (long long)M * 64;
    conv3_kernel<<<(pthreads + 127) / 128, 128, 0, stream>>>(
        mbuf, pairs, xf, row_ptr, csr_src, inv_in, bias[2], M);

    mlp_kernel<<<B, 128, 0, stream>>>(xf, W1, b1, W2, b2, (float*)d_out, B);
}

// Round 12
// 272.877 us; speedup vs baseline: 3.2019x; 1.0111x over previous
//
#include <hip/hip_runtime.h>

#define HDIM 128
#define SCAN_CHUNK 1024
#define NBUK 256          // range buckets for radix partition
#define PART_EPT 2        // edges per thread in partition kernel

// ---------- bf16x2 pack/unpack (RNE) ----------
__device__ inline unsigned pack_bf16x2(float a, float b) {
    unsigned ua = __float_as_uint(a);
    unsigned ub = __float_as_uint(b);
    ua = (ua + 0x7FFFu + ((ua >> 16) & 1u)) >> 16;
    ub = (ub + 0x7FFFu + ((ub >> 16) & 1u)) >> 16;
    return ua | (ub << 16);
}
__device__ inline float bf16_lo(unsigned v) { return __uint_as_float(v << 16); }
__device__ inline float bf16_hi(unsigned v) { return __uint_as_float(v & 0xFFFF0000u); }

// ---------- fallback: degree histogram via global atomics ----------
__global__ void deg_kernel(const int* __restrict__ src, const int* __restrict__ dst,
                           int* __restrict__ deg_out, int* __restrict__ deg_in, int E) {
    int e = blockIdx.x * blockDim.x + threadIdx.x;
    if (e < E) {
        atomicAdd(&deg_out[src[e]], 1);
        atomicAdd(&deg_in[dst[e]], 1);
    }
}

// ---------- inverse-sqrt degree ----------
__global__ void inv_kernel(const int* __restrict__ deg_out, const int* __restrict__ deg_in,
                           float* __restrict__ inv_out, float* __restrict__ inv_in, int N) {
    int n = blockIdx.x * blockDim.x + threadIdx.x;
    if (n < N) {
        float dO = (float)(deg_out[n] > 1 ? deg_out[n] : 1);
        float dI = (float)(deg_in[n]  > 1 ? deg_in[n]  : 1);
        inv_out[n] = 1.0f / sqrtf(dO);
        inv_in[n]  = 1.0f / sqrtf(dI);
    }
}

// ---------- zw pack: zw[n] = (z[n], bits(inv_out[n])) ----------
__global__ void zw_kernel(const int* __restrict__ z, const float* __restrict__ inv_out,
                          int2* __restrict__ zw, int N) {
    int n = blockIdx.x * blockDim.x + threadIdx.x;
    if (n < N) zw[n] = make_int2(z[n], __float_as_int(inv_out[n]));
}

// ---------- hierarchical scan pass 1 ----------
__global__ __launch_bounds__(1024) void scan_blk_sum(const int* __restrict__ deg,
                                                     int* __restrict__ blk_sum, int n) {
    __shared__ int red[1024];
    int tid = threadIdx.x;
    int i = blockIdx.x * SCAN_CHUNK + tid;
    red[tid] = (i < n) ? deg[i] : 0;
    __syncthreads();
    for (int s = 512; s > 0; s >>= 1) {
        if (tid < s) red[tid] += red[tid + s];
        __syncthreads();
    }
    if (tid == 0) blk_sum[blockIdx.x] = red[0];
}

// ---------- hierarchical scan pass 2 (nblk <= 128) ----------
__global__ __launch_bounds__(128) void scan_blk_off(const int* __restrict__ blk_sum,
                                                    int* __restrict__ blk_off, int nblk) {
    __shared__ int buf[128];
    int tid = threadIdx.x;
    int v = (tid < nblk) ? blk_sum[tid] : 0;
    buf[tid] = v;
    __syncthreads();
    for (int offset = 1; offset < 128; offset <<= 1) {
        int t = (tid >= offset) ? buf[tid - offset] : 0;
        __syncthreads();
        buf[tid] += t;
        __syncthreads();
    }
    if (tid < nblk) blk_off[tid] = buf[tid] - v;   // exclusive
}

// ---------- hierarchical scan pass 3 ----------
__global__ __launch_bounds__(1024) void scan_apply(const int* __restrict__ deg,
                                                   const int* __restrict__ blk_off,
                                                   int* __restrict__ row_ptr,
                                                   int* __restrict__ pos, int n) {
    __shared__ int buf[1024];
    int tid = threadIdx.x;
    int i = blockIdx.x * SCAN_CHUNK + tid;
    int v = (i < n) ? deg[i] : 0;
    buf[tid] = v;
    __syncthreads();
    for (int offset = 1; offset < 1024; offset <<= 1) {
        int t = (tid >= offset) ? buf[tid - offset] : 0;
        __syncthreads();
        buf[tid] += t;
        __syncthreads();
    }
    int base = blk_off[blockIdx.x];
    if (i < n) {
        int incl = base + buf[tid];
        row_ptr[i + 1] = incl;
        pos[i] = incl - v;
    }
    if (i == 0) row_ptr[0] = 0;
}

// ---------- fallback: plain scatter fill ----------
__global__ void fill_kernel(const int* __restrict__ src, const int* __restrict__ dst,
                            int* __restrict__ pos, int* __restrict__ csr_src, int E) {
    int e = blockIdx.x * blockDim.x + threadIdx.x;
    if (e < E) {
        int d = dst[e];
        int idx = atomicAdd(&pos[d], 1);
        csr_src[idx] = src[e];
    }
}

// ---------- radix-partition: init bucket allocators ----------
__global__ void init_alloc_kernel(int* __restrict__ alloc, int* __restrict__ alloc2, int cap) {
    int i = threadIdx.x;        // one block of NBUK threads
    alloc[i]  = i * cap;
    alloc2[i] = i * cap;
}

// ---------- radix partition: dst-bucketed (src,dst) int2 + src-bucketed src int ----------
__global__ __launch_bounds__(1024) void partition_kernel(
        const int* __restrict__ src, const int* __restrict__ dst,
        int* __restrict__ alloc, int* __restrict__ alloc2,
        int2* __restrict__ staging, int* __restrict__ staging2,
        int E, int N, int cap) {
    __shared__ int lcnt[NBUK];
    __shared__ int lbase[NBUK];
    __shared__ int lcnt2[NBUK];
    __shared__ int lbase2[NBUK];
    int tid = threadIdx.x;
    if (tid < NBUK) { lcnt[tid] = 0; lcnt2[tid] = 0; }
    __syncthreads();
    int base_e = blockIdx.x * (1024 * PART_EPT);
    int s[PART_EPT], d[PART_EPT], bk[PART_EPT], rk[PART_EPT], bs[PART_EPT], rs[PART_EPT];
    #pragma unroll
    for (int j = 0; j < PART_EPT; ++j) {
        int e = base_e + j * 1024 + tid;    // coalesced
        if (e < E) {
            s[j] = src[e];
            d[j] = dst[e];
            bk[j] = (int)(((long long)d[j] * NBUK) / N);
            rk[j] = atomicAdd(&lcnt[bk[j]], 1);
            bs[j] = (int)(((long long)s[j] * NBUK) / N);
            rs[j] = atomicAdd(&lcnt2[bs[j]], 1);
        } else {
            bk[j] = -1;
        }
    }
    __syncthreads();
    if (tid < NBUK) {
        int c = lcnt[tid];
        lbase[tid] = (c > 0) ? atomicAdd(&alloc[tid], c) : 0;
        int c2 = lcnt2[tid];
        lbase2[tid] = (c2 > 0) ? atomicAdd(&alloc2[tid], c2) : 0;
    }
    __syncthreads();
    #pragma unroll
    for (int j = 0; j < PART_EPT; ++j) {
        if (bk[j] >= 0) {
            int idx = lbase[bk[j]] + rk[j];
            if (idx < (bk[j] + 1) * cap)    // overflow clamp
                staging[idx] = make_int2(s[j], d[j]);
            int idx2 = lbase2[bs[j]] + rs[j];
            if (idx2 < (bs[j] + 1) * cap)
                staging2[idx2] = s[j];
        }
    }
}

// ---------- per-bucket degree histograms from staged data ----------
__global__ __launch_bounds__(256) void hist_in_kernel(
        const int* __restrict__ alloc, const int2* __restrict__ staging,
        int* __restrict__ deg_in, int cap, int N) {
    __shared__ int h[400];
    int b = blockIdx.x;
    int lo = (b * N + NBUK - 1) / NBUK;
    int hi = ((b + 1) * N + NBUK - 1) / NBUK;
    if (hi > N) hi = N;
    int w = hi - lo;
    for (int t = threadIdx.x; t < w; t += 256) h[t] = 0;
    __syncthreads();
    int base = b * cap;
    int cnt = alloc[b] - base; if (cnt > cap) cnt = cap;
    for (int i = threadIdx.x; i < cnt; i += 256)
        atomicAdd(&h[staging[base + i].y - lo], 1);
    __syncthreads();
    for (int t = threadIdx.x; t < w; t += 256) deg_in[lo + t] = h[t];
}

__global__ __launch_bounds__(256) void hist_out_kernel(
        const int* __restrict__ alloc2, const int* __restrict__ staging2,
        int* __restrict__ deg_out, int cap, int N) {
    __shared__ int h[400];
    int b = blockIdx.x;
    int lo = (b * N + NBUK - 1) / NBUK;
    int hi = ((b + 1) * N + NBUK - 1) / NBUK;
    if (hi > N) hi = N;
    int w = hi - lo;
    for (int t = threadIdx.x; t < w; t += 256) h[t] = 0;
    __syncthreads();
    int base = b * cap;
    int cnt = alloc2[b] - base; if (cnt > cap) cnt = cap;
    for (int i = threadIdx.x; i < cnt; i += 256)
        atomicAdd(&h[staging2[base + i] - lo], 1);
    __syncthreads();
    for (int t = threadIdx.x; t < w; t += 256) deg_out[lo + t] = h[t];
}

// ---------- radix fill phase 2: per-bucket window-local scatter ----------
__global__ __launch_bounds__(256) void scatter_kernel(
        const int* __restrict__ alloc, const int2* __restrict__ staging,
        int* __restrict__ pos, int* __restrict__ csr_src, int cap) {
    int b = blockIdx.x;
    int base = b * cap;
    int cnt = alloc[b] - base;
    if (cnt > cap) cnt = cap;
    for (int i = threadIdx.x; i < cnt; i += 256) {
        int2 sd = staging[base + i];
        int slot = atomicAdd(&pos[sd.y], 1);
        csr_src[slot] = sd.x;
    }
}

// ---------- flags2: mark in-neighbors of pair nodes (conv2 needed set) ----------
// racing byte-stores of constant 1 are idempotent -> deterministic.
__global__ __launch_bounds__(128) void flag2_kernel(
        const int* __restrict__ plist, const int* __restrict__ row_ptr,
        const int* __restrict__ csr_src, unsigned char* __restrict__ flags2, int M) {
    int gtid = blockIdx.x * blockDim.x + threadIdx.x;
    int i = gtid >> 6;
    int lane = threadIdx.x & 63;
    if (i >= M) return;
    int n = plist[i];
    int start = row_ptr[n], end = row_ptr[n + 1];
    for (int e = start + lane; e < end; e += 64) flags2[csr_src[e]] = 1;
}

// ---------- flags1: mark in-neighbors of flagged2 nodes (conv1 needed set) ----------
__global__ __launch_bounds__(128) void flag1_kernel(
        const unsigned char* __restrict__ flags2, const int* __restrict__ row_ptr,
        const int* __restrict__ csr_src, unsigned char* __restrict__ flags1, int N) {
    int gtid = blockIdx.x * blockDim.x + threadIdx.x;
    int n = gtid >> 6;
    int lane = threadIdx.x & 63;
    if (n >= N || !flags2[n]) return;
    int start = row_ptr[n], end = row_ptr[n + 1];
    for (int e = start + lane; e < end; e += 64) flags1[csr_src[e]] = 1;
}

// ---------- layer-1 conv, fused embedding, 8-way chains, flag-masked ----------
// per edge: csr (coalesced) -> zw[s] (one 8B broadcast) -> z_table row (L2).
__global__ __launch_bounds__(128) void conv1_kernel(
        const int2* __restrict__ zw, const float* __restrict__ z_table,
        const unsigned char* __restrict__ flags1,
        unsigned* __restrict__ out_bf,
        const int* __restrict__ row_ptr, const int* __restrict__ csr_src,
        const float* __restrict__ inv_out, const float* __restrict__ inv_in,
        const float* __restrict__ bias, int N) {
    int gtid = blockIdx.x * blockDim.x + threadIdx.x;
    int n = gtid >> 6;       // wave per node
    int lane = threadIdx.x & 63;
    if (n >= N || !flags1[n]) return;

    int start = row_ptr[n];
    int end   = row_ptr[n + 1];

    float ax0 = 0.f, ay0 = 0.f, ax1 = 0.f, ay1 = 0.f;
    float ax2 = 0.f, ay2 = 0.f, ax3 = 0.f, ay3 = 0.f;
    float ax4 = 0.f, ay4 = 0.f, ax5 = 0.f, ay5 = 0.f;
    float ax6 = 0.f, ay6 = 0.f, ax7 = 0.f, ay7 = 0.f;
    int e = start;
    for (; e + 8 <= end; e += 8) {
        int s0 = csr_src[e + 0], s1 = csr_src[e + 1];
        int s2 = csr_src[e + 2], s3 = csr_src[e + 3];
        int s4 = csr_src[e + 4], s5 = csr_src[e + 5];
        int s6 = csr_src[e + 6], s7 = csr_src[e + 7];
        int2 q0 = zw[s0], q1 = zw[s1], q2 = zw[s2], q3 = zw[s3];
        int2 q4 = zw[s4], q5 = zw[s5], q6 = zw[s6], q7 = zw[s7];
        float2 v0 = reinterpret_cast<const float2*>(z_table + (size_t)q0.x * HDIM)[lane];
        float2 v1 = reinterpret_cast<const float2*>(z_table + (size_t)q1.x * HDIM)[lane];
        float2 v2 = reinterpret_cast<const float2*>(z_table + (size_t)q2.x * HDIM)[lane];
        float2 v3 = reinterpret_cast<const float2*>(z_table + (size_t)q3.x * HDIM)[lane];
        float2 v4 = reinterpret_cast<const float2*>(z_table + (size_t)q4.x * HDIM)[lane];
        float2 v5 = reinterpret_cast<const float2*>(z_table + (size_t)q5.x * HDIM)[lane];
        float2 v6 = reinterpret_cast<const float2*>(z_table + (size_t)q6.x * HDIM)[lane];
        float2 v7 = reinterpret_cast<const float2*>(z_table + (size_t)q7.x * HDIM)[lane];
        float w0 = __int_as_float(q0.y), w1 = __int_as_float(q1.y);
        float w2 = __int_as_float(q2.y), w3 = __int_as_float(q3.y);
        float w4 = __int_as_float(q4.y), w5 = __int_as_float(q5.y);
        float w6 = __int_as_float(q6.y), w7 = __int_as_float(q7.y);
        ax0 += w0 * v0.x; ay0 += w0 * v0.y;  ax1 += w1 * v1.x; ay1 += w1 * v1.y;
        ax2 += w2 * v2.x; ay2 += w2 * v2.y;  ax3 += w3 * v3.x; ay3 += w3 * v3.y;
        ax4 += w4 * v4.x; ay4 += w4 * v4.y;  ax5 += w5 * v5.x; ay5 += w5 * v5.y;
        ax6 += w6 * v6.x; ay6 += w6 * v6.y;  ax7 += w7 * v7.x; ay7 += w7 * v7.y;
    }
    for (; e < end; ++e) {
        int s = csr_src[e];
        int2 q = zw[s];
        float w = __int_as_float(q.y);
        float2 v = reinterpret_cast<const float2*>(z_table + (size_t)q.x * HDIM)[lane];
        ax0 += w * v.x; ay0 += w * v.y;
    }
    float accx = ((ax0 + ax1) + (ax2 + ax3)) + ((ax4 + ax5) + (ax6 + ax7));
    float accy = ((ay0 + ay1) + (ay2 + ay3)) + ((ay4 + ay5) + (ay6 + ay7));

    float win = inv_in[n];
    float2 b = reinterpret_cast<const float2*>(bias)[lane];
    float wout = inv_out[n];
    float ox = fmaxf(accx * win + b.x, 0.0f) * wout;
    float oy = fmaxf(accy * win + b.y, 0.0f) * wout;
    out_bf[(size_t)n * 64 + lane] = pack_bf16x2(ox, oy);
}

// ---------- layer-2 conv: bf16 -> bf16, 8-way, flag-masked (~16% of nodes) ----------
__global__ __launch_bounds__(128) void conv2_kernel(
        const unsigned* __restrict__ xs, const unsigned char* __restrict__ flags2,
        unsigned* __restrict__ out_bf,
        const int* __restrict__ row_ptr, const int* __restrict__ csr_src,
        const float* __restrict__ inv_out, const float* __restrict__ inv_in,
        const float* __restrict__ bias, int N) {
    int gtid = blockIdx.x * blockDim.x + threadIdx.x;
    int n = gtid >> 6;       // wave per node
    int lane = threadIdx.x & 63;
    if (n >= N || !flags2[n]) return;

    int start = row_ptr[n];
    int end   = row_ptr[n + 1];

    float ax0 = 0.f, ay0 = 0.f, ax1 = 0.f, ay1 = 0.f;
    float ax2 = 0.f, ay2 = 0.f, ax3 = 0.f, ay3 = 0.f;
    float ax4 = 0.f, ay4 = 0.f, ax5 = 0.f, ay5 = 0.f;
    float ax6 = 0.f, ay6 = 0.f, ax7 = 0.f, ay7 = 0.f;
    int e = start;
    for (; e + 8 <= end; e += 8) {
        int s0 = csr_src[e + 0], s1 = csr_src[e + 1];
        int s2 = csr_src[e + 2], s3 = csr_src[e + 3];
        int s4 = csr_src[e + 4], s5 = csr_src[e + 5];
        int s6 = csr_src[e + 6], s7 = csr_src[e + 7];
        unsigned v0 = xs[(size_t)s0 * 64 + lane];
        unsigned v1 = xs[(size_t)s1 * 64 + lane];
        unsigned v2 = xs[(size_t)s2 * 64 + lane];
        unsigned v3 = xs[(size_t)s3 * 64 + lane];
        unsigned v4 = xs[(size_t)s4 * 64 + lane];
        unsigned v5 = xs[(size_t)s5 * 64 + lane];
        unsigned v6 = xs[(size_t)s6 * 64 + lane];
        unsigned v7 = xs[(size_t)s7 * 64 + lane];
        ax0 += bf16_lo(v0); ay0 += bf16_hi(v0);
        ax1 += bf16_lo(v1); ay1 += bf16_hi(v1);
        ax2 += bf16_lo(v2); ay2 += bf16_hi(v2);
        ax3 += bf16_lo(v3); ay3 += bf16_hi(v3);
        ax4 += bf16_lo(v4); ay4 += bf16_hi(v4);
        ax5 += bf16_lo(v5); ay5 += bf16_hi(v5);
        ax6 += bf16_lo(v6); ay6 += bf16_hi(v6);
        ax7 += bf16_lo(v7); ay7 += bf16_hi(v7);
    }
    if (e + 4 <= end) {
        int s0 = csr_src[e + 0], s1 = csr_src[e + 1];
        int s2 = csr_src[e + 2], s3 = csr_src[e + 3];
        unsigned v0 = xs[(size_t)s0 * 64 + lane];
        unsigned v1 = xs[(size_t)s1 * 64 + lane];
        unsigned v2 = xs[(size_t)s2 * 64 + lane];
        unsigned v3 = xs[(size_t)s3 * 64 + lane];
        ax0 += bf16_lo(v0); ay0 += bf16_hi(v0);
        ax1 += bf16_lo(v1); ay1 += bf16_hi(v1);
        ax2 += bf16_lo(v2); ay2 += bf16_hi(v2);
        ax3 += bf16_lo(v3); ay3 += bf16_hi(v3);
        e += 4;
    }
    for (; e < end; ++e) {
        unsigned v = xs[(size_t)csr_src[e] * 64 + lane];
        ax0 += bf16_lo(v); ay0 += bf16_hi(v);
    }
    float accx = ((ax0 + ax1) + (ax2 + ax3)) + ((ax4 + ax5) + (ax6 + ax7));
    float accy = ((ay0 + ay1) + (ay2 + ay3)) + ((ay4 + ay5) + (ay6 + ay7));

    float win = inv_in[n];
    float2 b = reinterpret_cast<const float2*>(bias)[lane];
    float wout = inv_out[n];
    float ox = fmaxf(accx * win + b.x, 0.0f) * wout;
    float oy = fmaxf(accy * win + b.y, 0.0f) * wout;
    out_bf[(size_t)n * 64 + lane] = pack_bf16x2(ox, oy);
}

// ---------- layer-3 conv, PAIR NODES ONLY (M = 2B rows) ----------
__global__ __launch_bounds__(128) void conv3_kernel(
        const unsigned* __restrict__ xs, const int* __restrict__ plist,
        float* __restrict__ xf,
        const int* __restrict__ row_ptr, const int* __restrict__ csr_src,
        const float* __restrict__ inv_in, const float* __restrict__ bias, int M) {
    int gtid = blockIdx.x * blockDim.x + threadIdx.x;
    int i = gtid >> 6;
    int lane = threadIdx.x & 63;
    if (i >= M) return;
    int n = plist[i];

    int start = row_ptr[n];
    int end   = row_ptr[n + 1];

    float ax0 = 0.f, ay0 = 0.f, ax1 = 0.f, ay1 = 0.f;
    float ax2 = 0.f, ay2 = 0.f, ax3 = 0.f, ay3 = 0.f;
    int e = start;
    for (; e + 4 <= end; e += 4) {
        int s0 = csr_src[e + 0], s1 = csr_src[e + 1];
        int s2 = csr_src[e + 2], s3 = csr_src[e + 3];
        unsigned v0 = xs[(size_t)s0 * 64 + lane];
        unsigned v1 = xs[(size_t)s1 * 64 + lane];
        unsigned v2 = xs[(size_t)s2 * 64 + lane];
        unsigned v3 = xs[(size_t)s3 * 64 + lane];
        ax0 += bf16_lo(v0); ay0 += bf16_hi(v0);
        ax1 += bf16_lo(v1); ay1 += bf16_hi(v1);
        ax2 += bf16_lo(v2); ay2 += bf16_hi(v2);
        ax3 += bf16_lo(v3); ay3 += bf16_hi(v3);
    }
    for (; e < end; ++e) {
        unsigned v = xs[(size_t)csr_src[e] * 64 + lane];
        ax0 += bf16_lo(v); ay0 += bf16_hi(v);
    }
    float accx = (ax0 + ax1) + (ax2 + ax3);
    float accy = (ay0 + ay1) + (ay2 + ay3);

    float win = inv_in[n];
    float2 b = reinterpret_cast<const float2*>(bias)[lane];
    float ox = accx * win + b.x;
    float oy = accy * win + b.y;
    reinterpret_cast<float2*>(xf + (size_t)i * HDIM)[lane] = make_float2(ox, oy);
}

// ---------- center pooling + 2-layer MLP over compact xf ----------
__global__ __launch_bounds__(128) void mlp_kernel(
        const float* __restrict__ xf,
        const float* __restrict__ W1, const float* __restrict__ b1,
        const float* __restrict__ W2, const float* __restrict__ b2,
        float* __restrict__ out, int B) {
    __shared__ float xp[HDIM];
    __shared__ float red[HDIM];
    int p = blockIdx.x;
    int t = threadIdx.x;
    xp[t] = xf[(size_t)p * HDIM + t] * xf[(size_t)(B + p) * HDIM + t];
    __syncthreads();
    float h = b1[t];
    #pragma unroll 8
    for (int k = 0; k < HDIM; ++k) h += xp[k] * W1[k * HDIM + t];
    h = fmaxf(h, 0.0f);
    red[t] = h * W2[t];
    __syncthreads();
    for (int s = 64; s > 0; s >>= 1) {
        if (t < s) red[t] += red[t + s];
        __syncthreads();
    }
    if (t == 0) out[p] = red[0] + b2[0];
}

extern "C" void kernel_launch(void* const* d_in, const int* in_sizes, int n_in,
                              void* d_out, int out_size, void* d_ws, size_t ws_size,
                              hipStream_t stream) {
    const int*   z       = (const int*)d_in[0];
    const int*   src     = (const int*)d_in[1];
    const int*   dst     = (const int*)d_in[2];
    const int*   pairs   = (const int*)d_in[3];
    const float* z_table = (const float*)d_in[4];
    const float* bias[3] = {(const float*)d_in[5], (const float*)d_in[6], (const float*)d_in[7]};
    const float* W1      = (const float*)d_in[8];
    const float* b1      = (const float*)d_in[9];
    const float* W2      = (const float*)d_in[10];
    const float* b2      = (const float*)d_in[11];

    const int N = in_sizes[0];
    const int E = in_sizes[1];
    const int B = in_sizes[3] / 2;
    const int M = 2 * B;                       // pair-node list length
    const int nblk = (N + SCAN_CHUNK - 1) / SCAN_CHUNK;

    char* ws = (char*)d_ws;
    size_t off = 0;
    auto carve = [&](size_t bytes) -> void* {
        void* p = ws + off;
        off = (off + bytes + 255) & ~(size_t)255;
        return p;
    };
    int*      deg_out = (int*)carve((size_t)N * 4);
    int*      deg_in  = (int*)carve((size_t)N * 4);
    float*    inv_out = (float*)carve((size_t)N * 4);
    float*    inv_in  = (float*)carve((size_t)N * 4);
    int*      row_ptr = (int*)carve((size_t)(N + 1) * 4);
    int*      pos     = (int*)carve((size_t)N * 4);
    int*      blk_sum = (int*)carve((size_t)nblk * 4);
    int*      blk_off = (int*)carve((size_t)nblk * 4);
    int*      csr_src = (int*)carve((size_t)E * 4);
    unsigned* xb      = (unsigned*)carve((size_t)N * 64 * 4);   // bf16x2 [N][64]
    unsigned* mbuf    = (unsigned*)carve((size_t)N * 64 * 4);   // bf16x2 [N][64]
    float*    xf      = (float*)carve((size_t)M * HDIM * 4);    // compact pair features
    int2*     zw      = (int2*)carve((size_t)N * 8);            // (z, inv_out) pack
    unsigned char* flags1 = (unsigned char*)carve((size_t)N);
    unsigned char* flags2 = (unsigned char*)carve((size_t)N);

    // radix-partition extras
    const int mean = (E + NBUK - 1) / NBUK;
    const int cap  = (int)((((size_t)mean * 2) + 255) / 256) * 256;   // 2x headroom
    int*  alloc    = (int*)carve((size_t)NBUK * 4);
    int*  alloc2   = (int*)carve((size_t)NBUK * 4);
    int2* staging  = (int2*)carve((size_t)NBUK * (size_t)cap * 8);
    int*  staging2 = (int*)carve((size_t)NBUK * (size_t)cap * 4);
    const bool use_part = (off <= ws_size);

    if (use_part) {
        const int edges_per_block = 1024 * PART_EPT;
        const int pblocks = (E + edges_per_block - 1) / edges_per_block;
        init_alloc_kernel<<<1, NBUK, 0, stream>>>(alloc, alloc2, cap);
        partition_kernel<<<pblocks, 1024, 0, stream>>>(
            src, dst, alloc, alloc2, staging, staging2, E, N, cap);
        hist_in_kernel<<<NBUK, 256, 0, stream>>>(alloc, staging, deg_in, cap, N);
        hist_out_kernel<<<NBUK, 256, 0, stream>>>(alloc2, staging2, deg_out, cap, N);
        inv_kernel<<<(N + 255) / 256, 256, 0, stream>>>(deg_out, deg_in, inv_out, inv_in, N);
        scan_blk_sum<<<nblk, 1024, 0, stream>>>(deg_in, blk_sum, N);
        scan_blk_off<<<1, 128, 0, stream>>>(blk_sum, blk_off, nblk);
        scan_apply<<<nblk, 1024, 0, stream>>>(deg_in, blk_off, row_ptr, pos, N);
        scatter_kernel<<<NBUK, 256, 0, stream>>>(alloc, staging, pos, csr_src, cap);
    } else {
        hipMemsetAsync(deg_out, 0, (size_t)N * 4, stream);
        hipMemsetAsync(deg_in,  0, (size_t)N * 4, stream);
        deg_kernel<<<(E + 255) / 256, 256, 0, stream>>>(src, dst, deg_out, deg_in, E);
        inv_kernel<<<(N + 255) / 256, 256, 0, stream>>>(deg_out, deg_in, inv_out, inv_in, N);
        scan_blk_sum<<<nblk, 1024, 0, stream>>>(deg_in, blk_sum, N);
        scan_blk_off<<<1, 128, 0, stream>>>(blk_sum, blk_off, nblk);
        scan_apply<<<nblk, 1024, 0, stream>>>(deg_in, blk_off, row_ptr, pos, N);
        fill_kernel<<<(E + 255) / 256, 256, 0, stream>>>(src, dst, pos, csr_src, E);
    }

    // common: zw pack + needed-set flags (exact pruning)
    zw_kernel<<<(N + 255) / 256, 256, 0, stream>>>(z, inv_out, zw, N);
    hipMemsetAsync(flags1, 0, (size_t)N, stream);
    hipMemsetAsync(flags2, 0, (size_t)N, stream);
    flag2_kernel<<<((long long)M * 64 + 127) / 128, 128, 0, stream>>>(
        pairs, row_ptr, csr_src, flags2, M);
    flag1_kernel<<<((long long)N * 64 + 127) / 128, 128, 0, stream>>>(
        flags2, row_ptr, csr_src, flags1, N);

    long long threads = (long long)N * 64;
    conv1_kernel<<<(threads + 127) / 128, 128, 0, stream>>>(
        zw, z_table, flags1, xb, row_ptr, csr_src, inv_out, inv_in, bias[0], N);
    conv2_kernel<<<(threads + 127) / 128, 128, 0, stream>>>(
        xb, flags2, mbuf, row_ptr, csr_src, inv_out, inv_in, bias[1], N);
    long long pthreads = (long long)M * 64;
    conv3_kernel<<<(pthreads + 127) / 128, 128, 0, stream>>>(
        mbuf, pairs, xf, row_ptr, csr_src, inv_in, bias[2], M);

    mlp_kernel<<<B, 128, 0, stream>>>(xf, W1, b1, W2, b2, (float*)d_out, B);
}

// Round 13
// 227.049 us; speedup vs baseline: 3.8482x; 1.2018x over previous
//
#include <hip/hip_runtime.h>

#define HDIM 128
#define SCAN_CHUNK 1024
#define NBUK 256          // range buckets for radix partition
#define PART_EPT 2        // edges per thread in partition kernel

// ---------- bf16x2 pack/unpack (RNE) ----------
__device__ inline unsigned pack_bf16x2(float a, float b) {
    unsigned ua = __float_as_uint(a);
    unsigned ub = __float_as_uint(b);
    ua = (ua + 0x7FFFu + ((ua >> 16) & 1u)) >> 16;
    ub = (ub + 0x7FFFu + ((ub >> 16) & 1u)) >> 16;
    return ua | (ub << 16);
}
__device__ inline float bf16_lo(unsigned v) { return __uint_as_float(v << 16); }
__device__ inline float bf16_hi(unsigned v) { return __uint_as_float(v & 0xFFFF0000u); }

// ---------- fallback: degree histogram via global atomics ----------
__global__ void deg_kernel(const int* __restrict__ src, const int* __restrict__ dst,
                           int* __restrict__ deg_out, int* __restrict__ deg_in, int E) {
    int e = blockIdx.x * blockDim.x + threadIdx.x;
    if (e < E) {
        atomicAdd(&deg_out[src[e]], 1);
        atomicAdd(&deg_in[dst[e]], 1);
    }
}

// ---------- inverse-sqrt degree ----------
__global__ void inv_kernel(const int* __restrict__ deg_out, const int* __restrict__ deg_in,
                           float* __restrict__ inv_out, float* __restrict__ inv_in, int N) {
    int n = blockIdx.x * blockDim.x + threadIdx.x;
    if (n < N) {
        float dO = (float)(deg_out[n] > 1 ? deg_out[n] : 1);
        float dI = (float)(deg_in[n]  > 1 ? deg_in[n]  : 1);
        inv_out[n] = 1.0f / sqrtf(dO);
        inv_in[n]  = 1.0f / sqrtf(dI);
    }
}

// ---------- hierarchical scan pass 1 ----------
__global__ __launch_bounds__(1024) void scan_blk_sum(const int* __restrict__ deg,
                                                     int* __restrict__ blk_sum, int n) {
    __shared__ int red[1024];
    int tid = threadIdx.x;
    int i = blockIdx.x * SCAN_CHUNK + tid;
    red[tid] = (i < n) ? deg[i] : 0;
    __syncthreads();
    for (int s = 512; s > 0; s >>= 1) {
        if (tid < s) red[tid] += red[tid + s];
        __syncthreads();
    }
    if (tid == 0) blk_sum[blockIdx.x] = red[0];
}

// ---------- hierarchical scan pass 2 (nblk <= 128) ----------
__global__ __launch_bounds__(128) void scan_blk_off(const int* __restrict__ blk_sum,
                                                    int* __restrict__ blk_off, int nblk) {
    __shared__ int buf[128];
    int tid = threadIdx.x;
    int v = (tid < nblk) ? blk_sum[tid] : 0;
    buf[tid] = v;
    __syncthreads();
    for (int offset = 1; offset < 128; offset <<= 1) {
        int t = (tid >= offset) ? buf[tid - offset] : 0;
        __syncthreads();
        buf[tid] += t;
        __syncthreads();
    }
    if (tid < nblk) blk_off[tid] = buf[tid] - v;   // exclusive
}

// ---------- hierarchical scan pass 3 ----------
__global__ __launch_bounds__(1024) void scan_apply(const int* __restrict__ deg,
                                                   const int* __restrict__ blk_off,
                                                   int* __restrict__ row_ptr,
                                                   int* __restrict__ pos, int n) {
    __shared__ int buf[1024];
    int tid = threadIdx.x;
    int i = blockIdx.x * SCAN_CHUNK + tid;
    int v = (i < n) ? deg[i] : 0;
    buf[tid] = v;
    __syncthreads();
    for (int offset = 1; offset < 1024; offset <<= 1) {
        int t = (tid >= offset) ? buf[tid - offset] : 0;
        __syncthreads();
        buf[tid] += t;
        __syncthreads();
    }
    int base = blk_off[blockIdx.x];
    if (i < n) {
        int incl = base + buf[tid];
        row_ptr[i + 1] = incl;
        pos[i] = incl - v;
    }
    if (i == 0) row_ptr[0] = 0;
}

// ---------- fallback: plain scatter fill ----------
__global__ void fill_kernel(const int* __restrict__ src, const int* __restrict__ dst,
                            int* __restrict__ pos, int* __restrict__ csr_src, int E) {
    int e = blockIdx.x * blockDim.x + threadIdx.x;
    if (e < E) {
        int d = dst[e];
        int idx = atomicAdd(&pos[d], 1);
        csr_src[idx] = src[e];
    }
}

// ---------- radix-partition: init bucket allocators ----------
__global__ void init_alloc_kernel(int* __restrict__ alloc, int* __restrict__ alloc2, int cap) {
    int i = threadIdx.x;        // one block of NBUK threads
    alloc[i]  = i * cap;
    alloc2[i] = i * cap;
}

// ---------- radix partition: dst-bucketed (src,dst) int2 + src-bucketed src int ----------
__global__ __launch_bounds__(1024) void partition_kernel(
        const int* __restrict__ src, const int* __restrict__ dst,
        int* __restrict__ alloc, int* __restrict__ alloc2,
        int2* __restrict__ staging, int* __restrict__ staging2,
        int E, int N, int cap) {
    __shared__ int lcnt[NBUK];
    __shared__ int lbase[NBUK];
    __shared__ int lcnt2[NBUK];
    __shared__ int lbase2[NBUK];
    int tid = threadIdx.x;
    if (tid < NBUK) { lcnt[tid] = 0; lcnt2[tid] = 0; }
    __syncthreads();
    int base_e = blockIdx.x * (1024 * PART_EPT);
    int s[PART_EPT], d[PART_EPT], bk[PART_EPT], rk[PART_EPT], bs[PART_EPT], rs[PART_EPT];
    #pragma unroll
    for (int j = 0; j < PART_EPT; ++j) {
        int e = base_e + j * 1024 + tid;    // coalesced
        if (e < E) {
            s[j] = src[e];
            d[j] = dst[e];
            bk[j] = (int)(((long long)d[j] * NBUK) / N);
            rk[j] = atomicAdd(&lcnt[bk[j]], 1);
            bs[j] = (int)(((long long)s[j] * NBUK) / N);
            rs[j] = atomicAdd(&lcnt2[bs[j]], 1);
        } else {
            bk[j] = -1;
        }
    }
    __syncthreads();
    if (tid < NBUK) {
        int c = lcnt[tid];
        lbase[tid] = (c > 0) ? atomicAdd(&alloc[tid], c) : 0;
        int c2 = lcnt2[tid];
        lbase2[tid] = (c2 > 0) ? atomicAdd(&alloc2[tid], c2) : 0;
    }
    __syncthreads();
    #pragma unroll
    for (int j = 0; j < PART_EPT; ++j) {
        if (bk[j] >= 0) {
            int idx = lbase[bk[j]] + rk[j];
            if (idx < (bk[j] + 1) * cap)    // overflow clamp
                staging[idx] = make_int2(s[j], d[j]);
            int idx2 = lbase2[bs[j]] + rs[j];
            if (idx2 < (bs[j] + 1) * cap)
                staging2[idx2] = s[j];
        }
    }
}

// ---------- per-bucket degree histograms from staged data ----------
__global__ __launch_bounds__(256) void hist_in_kernel(
        const int* __restrict__ alloc, const int2* __restrict__ staging,
        int* __restrict__ deg_in, int cap, int N) {
    __shared__ int h[400];
    int b = blockIdx.x;
    int lo = (b * N + NBUK - 1) / NBUK;
    int hi = ((b + 1) * N + NBUK - 1) / NBUK;
    if (hi > N) hi = N;
    int w = hi - lo;
    for (int t = threadIdx.x; t < w; t += 256) h[t] = 0;
    __syncthreads();
    int base = b * cap;
    int cnt = alloc[b] - base; if (cnt > cap) cnt = cap;
    for (int i = threadIdx.x; i < cnt; i += 256)
        atomicAdd(&h[staging[base + i].y - lo], 1);
    __syncthreads();
    for (int t = threadIdx.x; t < w; t += 256) deg_in[lo + t] = h[t];
}

__global__ __launch_bounds__(256) void hist_out_kernel(
        const int* __restrict__ alloc2, const int* __restrict__ staging2,
        int* __restrict__ deg_out, int cap, int N) {
    __shared__ int h[400];
    int b = blockIdx.x;
    int lo = (b * N + NBUK - 1) / NBUK;
    int hi = ((b + 1) * N + NBUK - 1) / NBUK;
    if (hi > N) hi = N;
    int w = hi - lo;
    for (int t = threadIdx.x; t < w; t += 256) h[t] = 0;
    __syncthreads();
    int base = b * cap;
    int cnt = alloc2[b] - base; if (cnt > cap) cnt = cap;
    for (int i = threadIdx.x; i < cnt; i += 256)
        atomicAdd(&h[staging2[base + i] - lo], 1);
    __syncthreads();
    for (int t = threadIdx.x; t < w; t += 256) deg_out[lo + t] = h[t];
}

// ---------- radix fill phase 2: per-bucket window-local scatter ----------
__global__ __launch_bounds__(256) void scatter_kernel(
        const int* __restrict__ alloc, const int2* __restrict__ staging,
        int* __restrict__ pos, int* __restrict__ csr_src, int cap) {
    int b = blockIdx.x;
    int base = b * cap;
    int cnt = alloc[b] - base;
    if (cnt > cap) cnt = cap;
    for (int i = threadIdx.x; i < cnt; i += 256) {
        int2 sd = staging[base + i];
        int slot = atomicAdd(&pos[sd.y], 1);
        csr_src[slot] = sd.x;
    }
}

// ---------- flags2: mark in-neighbors of pair nodes (conv2 needed set) ----------
__global__ __launch_bounds__(128) void flag2_kernel(
        const int* __restrict__ plist, const int* __restrict__ row_ptr,
        const int* __restrict__ csr_src, unsigned char* __restrict__ flags2, int M) {
    int gtid = blockIdx.x * blockDim.x + threadIdx.x;
    int i = gtid >> 6;
    int lane = threadIdx.x & 63;
    if (i >= M) return;
    int n = plist[i];
    int start = row_ptr[n], end = row_ptr[n + 1];
    for (int e = start + lane; e < end; e += 64) flags2[csr_src[e]] = 1;
}

// ---------- flags1: mark in-neighbors of flagged2 nodes (conv1 needed set) ----------
__global__ __launch_bounds__(128) void flag1_kernel(
        const unsigned char* __restrict__ flags2, const int* __restrict__ row_ptr,
        const int* __restrict__ csr_src, unsigned char* __restrict__ flags1, int N) {
    int gtid = blockIdx.x * blockDim.x + threadIdx.x;
    int n = gtid >> 6;
    int lane = threadIdx.x & 63;
    if (n >= N || !flags2[n]) return;
    int start = row_ptr[n], end = row_ptr[n + 1];
    for (int e = start + lane; e < end; e += 64) flags1[csr_src[e]] = 1;
}

// ---------- embedding gather, pre-scaled + bf16 pack ----------
__global__ void embed_kernel(const int* __restrict__ z, const float* __restrict__ z_table,
                             const float* __restrict__ inv_out,
                             uint2* __restrict__ xs, int N) {
    int t = blockIdx.x * blockDim.x + threadIdx.x;
    int n = t >> 5;          // 32 uint2 per row (H=128 bf16)
    int c = t & 31;
    if (n < N) {
        int zz = z[n];
        float w = inv_out[n];
        float4 v = reinterpret_cast<const float4*>(z_table)[(size_t)zz * 32 + c];
        uint2 p;
        p.x = pack_bf16x2(v.x * w, v.y * w);
        p.y = pack_bf16x2(v.z * w, v.w * w);
        xs[(size_t)n * 32 + c] = p;
    }
}

// ---------- generic bf16->bf16 conv body (8-way, flag-masked) ----------
__device__ inline void conv_bf16_body(
        const unsigned* __restrict__ xs, unsigned* __restrict__ out_bf,
        const int* __restrict__ row_ptr, const int* __restrict__ csr_src,
        const float* __restrict__ inv_out, const float* __restrict__ inv_in,
        const float* __restrict__ bias, int n, int lane) {
    int start = row_ptr[n];
    int end   = row_ptr[n + 1];

    float ax0 = 0.f, ay0 = 0.f, ax1 = 0.f, ay1 = 0.f;
    float ax2 = 0.f, ay2 = 0.f, ax3 = 0.f, ay3 = 0.f;
    float ax4 = 0.f, ay4 = 0.f, ax5 = 0.f, ay5 = 0.f;
    float ax6 = 0.f, ay6 = 0.f, ax7 = 0.f, ay7 = 0.f;
    int e = start;
    for (; e + 8 <= end; e += 8) {
        int s0 = csr_src[e + 0], s1 = csr_src[e + 1];
        int s2 = csr_src[e + 2], s3 = csr_src[e + 3];
        int s4 = csr_src[e + 4], s5 = csr_src[e + 5];
        int s6 = csr_src[e + 6], s7 = csr_src[e + 7];
        unsigned v0 = xs[(size_t)s0 * 64 + lane];
        unsigned v1 = xs[(size_t)s1 * 64 + lane];
        unsigned v2 = xs[(size_t)s2 * 64 + lane];
        unsigned v3 = xs[(size_t)s3 * 64 + lane];
        unsigned v4 = xs[(size_t)s4 * 64 + lane];
        unsigned v5 = xs[(size_t)s5 * 64 + lane];
        unsigned v6 = xs[(size_t)s6 * 64 + lane];
        unsigned v7 = xs[(size_t)s7 * 64 + lane];
        ax0 += bf16_lo(v0); ay0 += bf16_hi(v0);
        ax1 += bf16_lo(v1); ay1 += bf16_hi(v1);
        ax2 += bf16_lo(v2); ay2 += bf16_hi(v2);
        ax3 += bf16_lo(v3); ay3 += bf16_hi(v3);
        ax4 += bf16_lo(v4); ay4 += bf16_hi(v4);
        ax5 += bf16_lo(v5); ay5 += bf16_hi(v5);
        ax6 += bf16_lo(v6); ay6 += bf16_hi(v6);
        ax7 += bf16_lo(v7); ay7 += bf16_hi(v7);
    }
    if (e + 4 <= end) {
        int s0 = csr_src[e + 0], s1 = csr_src[e + 1];
        int s2 = csr_src[e + 2], s3 = csr_src[e + 3];
        unsigned v0 = xs[(size_t)s0 * 64 + lane];
        unsigned v1 = xs[(size_t)s1 * 64 + lane];
        unsigned v2 = xs[(size_t)s2 * 64 + lane];
        unsigned v3 = xs[(size_t)s3 * 64 + lane];
        ax0 += bf16_lo(v0); ay0 += bf16_hi(v0);
        ax1 += bf16_lo(v1); ay1 += bf16_hi(v1);
        ax2 += bf16_lo(v2); ay2 += bf16_hi(v2);
        ax3 += bf16_lo(v3); ay3 += bf16_hi(v3);
        e += 4;
    }
    for (; e < end; ++e) {
        unsigned v = xs[(size_t)csr_src[e] * 64 + lane];
        ax0 += bf16_lo(v); ay0 += bf16_hi(v);
    }
    float accx = ((ax0 + ax1) + (ax2 + ax3)) + ((ax4 + ax5) + (ax6 + ax7));
    float accy = ((ay0 + ay1) + (ay2 + ay3)) + ((ay4 + ay5) + (ay6 + ay7));

    float win = inv_in[n];
    float2 b = reinterpret_cast<const float2*>(bias)[lane];
    float wout = inv_out[n];
    float ox = fmaxf(accx * win + b.x, 0.0f) * wout;
    float oy = fmaxf(accy * win + b.y, 0.0f) * wout;
    out_bf[(size_t)n * 64 + lane] = pack_bf16x2(ox, oy);
}

// ---------- layer-1 conv: gather from pre-scaled bf16 embed buffer, flags1 (~92%) ----------
__global__ __launch_bounds__(128) void conv1_kernel(
        const unsigned* __restrict__ xs, const unsigned char* __restrict__ flags1,
        unsigned* __restrict__ out_bf,
        const int* __restrict__ row_ptr, const int* __restrict__ csr_src,
        const float* __restrict__ inv_out, const float* __restrict__ inv_in,
        const float* __restrict__ bias, int N) {
    int gtid = blockIdx.x * blockDim.x + threadIdx.x;
    int n = gtid >> 6;
    int lane = threadIdx.x & 63;
    if (n >= N || !flags1[n]) return;
    conv_bf16_body(xs, out_bf, row_ptr, csr_src, inv_out, inv_in, bias, n, lane);
}

// ---------- layer-2 conv: flags2-masked (~16% of nodes) ----------
__global__ __launch_bounds__(128) void conv2_kernel(
        const unsigned* __restrict__ xs, const unsigned char* __restrict__ flags2,
        unsigned* __restrict__ out_bf,
        const int* __restrict__ row_ptr, const int* __restrict__ csr_src,
        const float* __restrict__ inv_out, const float* __restrict__ inv_in,
        const float* __restrict__ bias, int N) {
    int gtid = blockIdx.x * blockDim.x + threadIdx.x;
    int n = gtid >> 6;
    int lane = threadIdx.x & 63;
    if (n >= N || !flags2[n]) return;
    conv_bf16_body(xs, out_bf, row_ptr, csr_src, inv_out, inv_in, bias, n, lane);
}

// ---------- layer-3 conv, PAIR NODES ONLY (M = 2B rows) ----------
__global__ __launch_bounds__(128) void conv3_kernel(
        const unsigned* __restrict__ xs, const int* __restrict__ plist,
        float* __restrict__ xf,
        const int* __restrict__ row_ptr, const int* __restrict__ csr_src,
        const float* __restrict__ inv_in, const float* __restrict__ bias, int M) {
    int gtid = blockIdx.x * blockDim.x + threadIdx.x;
    int i = gtid >> 6;
    int lane = threadIdx.x & 63;
    if (i >= M) return;
    int n = plist[i];

    int start = row_ptr[n];
    int end   = row_ptr[n + 1];

    float ax0 = 0.f, ay0 = 0.f, ax1 = 0.f, ay1 = 0.f;
    float ax2 = 0.f, ay2 = 0.f, ax3 = 0.f, ay3 = 0.f;
    int e = start;
    for (; e + 4 <= end; e += 4) {
        int s0 = csr_src[e + 0], s1 = csr_src[e + 1];
        int s2 = csr_src[e + 2], s3 = csr_src[e + 3];
        unsigned v0 = xs[(size_t)s0 * 64 + lane];
        unsigned v1 = xs[(size_t)s1 * 64 + lane];
        unsigned v2 = xs[(size_t)s2 * 64 + lane];
        unsigned v3 = xs[(size_t)s3 * 64 + lane];
        ax0 += bf16_lo(v0); ay0 += bf16_hi(v0);
        ax1 += bf16_lo(v1); ay1 += bf16_hi(v1);
        ax2 += bf16_lo(v2); ay2 += bf16_hi(v2);
        ax3 += bf16_lo(v3); ay3 += bf16_hi(v3);
    }
    for (; e < end; ++e) {
        unsigned v = xs[(size_t)csr_src[e] * 64 + lane];
        ax0 += bf16_lo(v); ay0 += bf16_hi(v);
    }
    float accx = (ax0 + ax1) + (ax2 + ax3);
    float accy = (ay0 + ay1) + (ay2 + ay3);

    float win = inv_in[n];
    float2 b = reinterpret_cast<const float2*>(bias)[lane];
    float ox = accx * win + b.x;
    float oy = accy * win + b.y;
    reinterpret_cast<float2*>(xf + (size_t)i * HDIM)[lane] = make_float2(ox, oy);
}

// ---------- center pooling + 2-layer MLP over compact xf ----------
__global__ __launch_bounds__(128) void mlp_kernel(
        const float* __restrict__ xf,
        const float* __restrict__ W1, const float* __restrict__ b1,
        const float* __restrict__ W2, const float* __restrict__ b2,
        float* __restrict__ out, int B) {
    __shared__ float xp[HDIM];
    __shared__ float red[HDIM];
    int p = blockIdx.x;
    int t = threadIdx.x;
    xp[t] = xf[(size_t)p * HDIM + t] * xf[(size_t)(B + p) * HDIM + t];
    __syncthreads();
    float h = b1[t];
    #pragma unroll 8
    for (int k = 0; k < HDIM; ++k) h += xp[k] * W1[k * HDIM + t];
    h = fmaxf(h, 0.0f);
    red[t] = h * W2[t];
    __syncthreads();
    for (int s = 64; s > 0; s >>= 1) {
        if (t < s) red[t] += red[t + s];
        __syncthreads();
    }
    if (t == 0) out[p] = red[0] + b2[0];
}

extern "C" void kernel_launch(void* const* d_in, const int* in_sizes, int n_in,
                              void* d_out, int out_size, void* d_ws, size_t ws_size,
                              hipStream_t stream) {
    const int*   z       = (const int*)d_in[0];
    const int*   src     = (const int*)d_in[1];
    const int*   dst     = (const int*)d_in[2];
    const int*   pairs   = (const int*)d_in[3];
    const float* z_table = (const float*)d_in[4];
    const float* bias[3] = {(const float*)d_in[5], (const float*)d_in[6], (const float*)d_in[7]};
    const float* W1      = (const float*)d_in[8];
    const float* b1      = (const float*)d_in[9];
    const float* W2      = (const float*)d_in[10];
    const float* b2      = (const float*)d_in[11];

    const int N = in_sizes[0];
    const int E = in_sizes[1];
    const int B = in_sizes[3] / 2;
    const int M = 2 * B;                       // pair-node list length
    const int nblk = (N + SCAN_CHUNK - 1) / SCAN_CHUNK;

    char* ws = (char*)d_ws;
    size_t off = 0;
    auto carve = [&](size_t bytes) -> void* {
        void* p = ws + off;
        off = (off + bytes + 255) & ~(size_t)255;
        return p;
    };
    int*      deg_out = (int*)carve((size_t)N * 4);
    int*      deg_in  = (int*)carve((size_t)N * 4);
    float*    inv_out = (float*)carve((size_t)N * 4);
    float*    inv_in  = (float*)carve((size_t)N * 4);
    int*      row_ptr = (int*)carve((size_t)(N + 1) * 4);
    int*      pos     = (int*)carve((size_t)N * 4);
    int*      blk_sum = (int*)carve((size_t)nblk * 4);
    int*      blk_off = (int*)carve((size_t)nblk * 4);
    int*      csr_src = (int*)carve((size_t)E * 4);
    unsigned* xe      = (unsigned*)carve((size_t)N * 64 * 4);   // embed out, bf16x2
    unsigned* xb      = (unsigned*)carve((size_t)N * 64 * 4);   // conv1 out, bf16x2
    unsigned* mbuf    = (unsigned*)carve((size_t)N * 64 * 4);   // conv2 out, bf16x2
    float*    xf      = (float*)carve((size_t)M * HDIM * 4);    // compact pair features
    unsigned char* flags1 = (unsigned char*)carve((size_t)N);
    unsigned char* flags2 = (unsigned char*)carve((size_t)N);

    // radix-partition extras
    const int mean = (E + NBUK - 1) / NBUK;
    const int cap  = (int)((((size_t)mean * 2) + 255) / 256) * 256;   // 2x headroom
    int*  alloc    = (int*)carve((size_t)NBUK * 4);
    int*  alloc2   = (int*)carve((size_t)NBUK * 4);
    int2* staging  = (int2*)carve((size_t)NBUK * (size_t)cap * 8);
    int*  staging2 = (int*)carve((size_t)NBUK * (size_t)cap * 4);
    const bool use_part = (off <= ws_size);

    if (use_part) {
        const int edges_per_block = 1024 * PART_EPT;
        const int pblocks = (E + edges_per_block - 1) / edges_per_block;
        init_alloc_kernel<<<1, NBUK, 0, stream>>>(alloc, alloc2, cap);
        partition_kernel<<<pblocks, 1024, 0, stream>>>(
            src, dst, alloc, alloc2, staging, staging2, E, N, cap);
        hist_in_kernel<<<NBUK, 256, 0, stream>>>(alloc, staging, deg_in, cap, N);
        hist_out_kernel<<<NBUK, 256, 0, stream>>>(alloc2, staging2, deg_out, cap, N);
        inv_kernel<<<(N + 255) / 256, 256, 0, stream>>>(deg_out, deg_in, inv_out, inv_in, N);
        scan_blk_sum<<<nblk, 1024, 0, stream>>>(deg_in, blk_sum, N);
        scan_blk_off<<<1, 128, 0, stream>>>(blk_sum, blk_off, nblk);
        scan_apply<<<nblk, 1024, 0, stream>>>(deg_in, blk_off, row_ptr, pos, N);
        scatter_kernel<<<NBUK, 256, 0, stream>>>(alloc, staging, pos, csr_src, cap);
    } else {
        hipMemsetAsync(deg_out, 0, (size_t)N * 4, stream);
        hipMemsetAsync(deg_in,  0, (size_t)N * 4, stream);
        deg_kernel<<<(E + 255) / 256, 256, 0, stream>>>(src, dst, deg_out, deg_in, E);
        inv_kernel<<<(N + 255) / 256, 256, 0, stream>>>(deg_out, deg_in, inv_out, inv_in, N);
        scan_blk_sum<<<nblk, 1024, 0, stream>>>(deg_in, blk_sum, N);
        scan_blk_off<<<1, 128, 0, stream>>>(blk_sum, blk_off, nblk);
        scan_apply<<<nblk, 1024, 0, stream>>>(deg_in, blk_off, row_ptr, pos, N);
        fill_kernel<<<(E + 255) / 256, 256, 0, stream>>>(src, dst, pos, csr_src, E);
    }

    // needed-set flags (exact pruning) + embed
    hipMemsetAsync(flags1, 0, (size_t)N, stream);
    hipMemsetAsync(flags2, 0, (size_t)N, stream);
    flag2_kernel<<<((long long)M * 64 + 127) / 128, 128, 0, stream>>>(
        pairs, row_ptr, csr_src, flags2, M);
    flag1_kernel<<<((long long)N * 64 + 127) / 128, 128, 0, stream>>>(
        flags2, row_ptr, csr_src, flags1, N);
    embed_kernel<<<((size_t)N * 32 + 255) / 256, 256, 0, stream>>>(
        z, z_table, inv_out, (uint2*)xe, N);

    long long threads = (long long)N * 64;
    conv1_kernel<<<(threads + 127) / 128, 128, 0, stream>>>(
        xe, flags1, xb, row_ptr, csr_src, inv_out, inv_in, bias[0], N);
    conv2_kernel<<<(threads + 127) / 128, 128, 0, stream>>>(
        xb, flags2, mbuf, row_ptr, csr_src, inv_out, inv_in, bias[1], N);
    long long pthreads = (long long)M * 64;
    conv3_kernel<<<(pthreads + 127) / 128, 128, 0, stream>>>(
        mbuf, pairs, xf, row_ptr, csr_src, inv_in, bias[2], M);

    mlp_kernel<<<B, 128, 0, stream>>>(xf, W1, b1, W2, b2, (float*)d_out, B);
}

// Round 14
// 226.174 us; speedup vs baseline: 3.8631x; 1.0039x over previous
//
#include <hip/hip_runtime.h>

#define HDIM 128
#define SCAN_CHUNK 1024
#define NBUK 256          // range buckets for radix partition
#define PART_EPT 2        // edges per thread in partition kernel
#define SCHUNK 8          // scatter chunks per bucket (8*256 grid, same-XCD per bucket)

// ---------- bf16x2 pack/unpack (RNE) ----------
__device__ inline unsigned pack_bf16x2(float a, float b) {
    unsigned ua = __float_as_uint(a);
    unsigned ub = __float_as_uint(b);
    ua = (ua + 0x7FFFu + ((ua >> 16) & 1u)) >> 16;
    ub = (ub + 0x7FFFu + ((ub >> 16) & 1u)) >> 16;
    return ua | (ub << 16);
}
__device__ inline float bf16_lo(unsigned v) { return __uint_as_float(v << 16); }
__device__ inline float bf16_hi(unsigned v) { return __uint_as_float(v & 0xFFFF0000u); }

// ---------- fallback: degree histogram via global atomics ----------
__global__ void deg_kernel(const int* __restrict__ src, const int* __restrict__ dst,
                           int* __restrict__ deg_out, int* __restrict__ deg_in, int E) {
    int e = blockIdx.x * blockDim.x + threadIdx.x;
    if (e < E) {
        atomicAdd(&deg_out[src[e]], 1);
        atomicAdd(&deg_in[dst[e]], 1);
    }
}

// ---------- fallback: inverse-sqrt degree (both) ----------
__global__ void inv_kernel(const int* __restrict__ deg_out, const int* __restrict__ deg_in,
                           float* __restrict__ inv_out, float* __restrict__ inv_in, int N) {
    int n = blockIdx.x * blockDim.x + threadIdx.x;
    if (n < N) {
        float dO = (float)(deg_out[n] > 1 ? deg_out[n] : 1);
        float dI = (float)(deg_in[n]  > 1 ? deg_in[n]  : 1);
        inv_out[n] = 1.0f / sqrtf(dO);
        inv_in[n]  = 1.0f / sqrtf(dI);
    }
}

// ---------- hierarchical scan pass 1 ----------
__global__ __launch_bounds__(1024) void scan_blk_sum(const int* __restrict__ deg,
                                                     int* __restrict__ blk_sum, int n) {
    __shared__ int red[1024];
    int tid = threadIdx.x;
    int i = blockIdx.x * SCAN_CHUNK + tid;
    red[tid] = (i < n) ? deg[i] : 0;
    __syncthreads();
    for (int s = 512; s > 0; s >>= 1) {
        if (tid < s) red[tid] += red[tid + s];
        __syncthreads();
    }
    if (tid == 0) blk_sum[blockIdx.x] = red[0];
}

// ---------- hierarchical scan pass 2 (nblk <= 128) ----------
__global__ __launch_bounds__(128) void scan_blk_off(const int* __restrict__ blk_sum,
                                                    int* __restrict__ blk_off, int nblk) {
    __shared__ int buf[128];
    int tid = threadIdx.x;
    int v = (tid < nblk) ? blk_sum[tid] : 0;
    buf[tid] = v;
    __syncthreads();
    for (int offset = 1; offset < 128; offset <<= 1) {
        int t = (tid >= offset) ? buf[tid - offset] : 0;
        __syncthreads();
        buf[tid] += t;
        __syncthreads();
    }
    if (tid < nblk) blk_off[tid] = buf[tid] - v;   // exclusive
}

// ---------- hierarchical scan pass 3 (+ fused inv_in) ----------
__global__ __launch_bounds__(1024) void scan_apply(const int* __restrict__ deg,
                                                   const int* __restrict__ blk_off,
                                                   int* __restrict__ row_ptr,
                                                   int* __restrict__ pos,
                                                   float* __restrict__ inv_in, int n) {
    __shared__ int buf[1024];
    int tid = threadIdx.x;
    int i = blockIdx.x * SCAN_CHUNK + tid;
    int v = (i < n) ? deg[i] : 0;
    buf[tid] = v;
    __syncthreads();
    for (int offset = 1; offset < 1024; offset <<= 1) {
        int t = (tid >= offset) ? buf[tid - offset] : 0;
        __syncthreads();
        buf[tid] += t;
        __syncthreads();
    }
    int base = blk_off[blockIdx.x];
    if (i < n) {
        int incl = base + buf[tid];
        row_ptr[i + 1] = incl;
        pos[i] = incl - v;
        inv_in[i] = 1.0f / sqrtf((float)(v > 1 ? v : 1));
    }
    if (i == 0) row_ptr[0] = 0;
}

// ---------- fallback: plain scatter fill ----------
__global__ void fill_kernel(const int* __restrict__ src, const int* __restrict__ dst,
                            int* __restrict__ pos, int* __restrict__ csr_src, int E) {
    int e = blockIdx.x * blockDim.x + threadIdx.x;
    if (e < E) {
        int d = dst[e];
        int idx = atomicAdd(&pos[d], 1);
        csr_src[idx] = src[e];
    }
}

// ---------- radix-partition: init bucket allocators ----------
__global__ void init_alloc_kernel(int* __restrict__ alloc, int* __restrict__ alloc2, int cap) {
    int i = threadIdx.x;        // one block of NBUK threads
    alloc[i]  = i * cap;
    alloc2[i] = i * cap;
}

// ---------- radix partition, PACKED staging ----------
// staging[idx]  = src | (dst - lo(bk)) << 23   (dst-bucketed; local dst < 512)
// staging2[idx] = (ushort)(src - lo(bs))       (src-bucketed; for deg_out hist)
__global__ __launch_bounds__(1024) void partition_kernel(
        const int* __restrict__ src, const int* __restrict__ dst,
        int* __restrict__ alloc, int* __restrict__ alloc2,
        unsigned* __restrict__ staging, unsigned short* __restrict__ staging2,
        int E, int N, int cap) {
    __shared__ int lcnt[NBUK];
    __shared__ int lbase[NBUK];
    __shared__ int lcnt2[NBUK];
    __shared__ int lbase2[NBUK];
    int tid = threadIdx.x;
    if (tid < NBUK) { lcnt[tid] = 0; lcnt2[tid] = 0; }
    __syncthreads();
    int base_e = blockIdx.x * (1024 * PART_EPT);
    unsigned pk[PART_EPT]; unsigned short pk2[PART_EPT];
    int bk[PART_EPT], rk[PART_EPT], bs[PART_EPT], rs[PART_EPT];
    #pragma unroll
    for (int j = 0; j < PART_EPT; ++j) {
        int e = base_e + j * 1024 + tid;    // coalesced
        if (e < E) {
            int s = src[e];
            int d = dst[e];
            bk[j] = (int)(((long long)d * NBUK) / N);
            int lo_d = (bk[j] * N + NBUK - 1) / NBUK;
            pk[j] = (unsigned)s | ((unsigned)(d - lo_d) << 23);
            rk[j] = atomicAdd(&lcnt[bk[j]], 1);
            bs[j] = (int)(((long long)s * NBUK) / N);
            int lo_s = (bs[j] * N + NBUK - 1) / NBUK;
            pk2[j] = (unsigned short)(s - lo_s);
            rs[j] = atomicAdd(&lcnt2[bs[j]], 1);
        } else {
            bk[j] = -1;
        }
    }
    __syncthreads();
    if (tid < NBUK) {
        int c = lcnt[tid];
        lbase[tid] = (c > 0) ? atomicAdd(&alloc[tid], c) : 0;
        int c2 = lcnt2[tid];
        lbase2[tid] = (c2 > 0) ? atomicAdd(&alloc2[tid], c2) : 0;
    }
    __syncthreads();
    #pragma unroll
    for (int j = 0; j < PART_EPT; ++j) {
        if (bk[j] >= 0) {
            int idx = lbase[bk[j]] + rk[j];
            if (idx < (bk[j] + 1) * cap)    // overflow clamp
                staging[idx] = pk[j];
            int idx2 = lbase2[bs[j]] + rs[j];
            if (idx2 < (bs[j] + 1) * cap)
                staging2[idx2] = pk2[j];
        }
    }
}

// ---------- per-bucket in-degree histogram (packed dst) ----------
__global__ __launch_bounds__(256) void hist_in_kernel(
        const int* __restrict__ alloc, const unsigned* __restrict__ staging,
        int* __restrict__ deg_in, int cap, int N) {
    __shared__ int h[512];
    int b = blockIdx.x;
    int lo = (b * N + NBUK - 1) / NBUK;
    int hi = ((b + 1) * N + NBUK - 1) / NBUK;
    if (hi > N) hi = N;
    int w = hi - lo;
    for (int t = threadIdx.x; t < w; t += 256) h[t] = 0;
    __syncthreads();
    int base = b * cap;
    int cnt = alloc[b] - base; if (cnt > cap) cnt = cap;
    for (int i = threadIdx.x; i < cnt; i += 256)
        atomicAdd(&h[staging[base + i] >> 23], 1);
    __syncthreads();
    for (int t = threadIdx.x; t < w; t += 256) deg_in[lo + t] = h[t];
}

// ---------- per-bucket out-degree histogram (ushort local src) + fused inv_out ----------
__global__ __launch_bounds__(256) void hist_out_kernel(
        const int* __restrict__ alloc2, const unsigned short* __restrict__ staging2,
        float* __restrict__ inv_out, int cap, int N) {
    __shared__ int h[512];
    int b = blockIdx.x;
    int lo = (b * N + NBUK - 1) / NBUK;
    int hi = ((b + 1) * N + NBUK - 1) / NBUK;
    if (hi > N) hi = N;
    int w = hi - lo;
    for (int t = threadIdx.x; t < w; t += 256) h[t] = 0;
    __syncthreads();
    int base = b * cap;
    int cnt = alloc2[b] - base; if (cnt > cap) cnt = cap;
    for (int i = threadIdx.x; i < cnt; i += 256)
        atomicAdd(&h[staging2[base + i]], 1);
    __syncthreads();
    for (int t = threadIdx.x; t < w; t += 256) {
        int v = h[t];
        inv_out[lo + t] = 1.0f / sqrtf((float)(v > 1 ? v : 1));
    }
}

// ---------- radix fill phase 2: chunked per-bucket scatter ----------
// bucket = blockIdx & 255 -> all SCHUNK chunks of a bucket hit the same XCD
// (256 % 8 == 0), preserving pos/csr window locality at 8x the parallelism.
__global__ __launch_bounds__(256) void scatter_kernel(
        const int* __restrict__ alloc, const unsigned* __restrict__ staging,
        int* __restrict__ pos, int* __restrict__ csr_src, int cap, int N) {
    int b = blockIdx.x & (NBUK - 1);
    int chunk = blockIdx.x >> 8;
    int lo = (b * N + NBUK - 1) / NBUK;
    int base = b * cap;
    int cnt = alloc[b] - base;
    if (cnt > cap) cnt = cap;
    int per = (cnt + SCHUNK - 1) / SCHUNK;
    int i0 = chunk * per;
    int i1 = i0 + per; if (i1 > cnt) i1 = cnt;
    for (int i = i0 + threadIdx.x; i < i1; i += 256) {
        unsigned p = staging[base + i];
        int d = lo + (int)(p >> 23);
        int s = (int)(p & 0x7FFFFFu);
        int slot = atomicAdd(&pos[d], 1);
        csr_src[slot] = s;
    }
}

// ---------- flags2: mark in-neighbors of pair nodes (conv2 needed set) ----------
__global__ __launch_bounds__(128) void flag2_kernel(
        const int* __restrict__ plist, const int* __restrict__ row_ptr,
        const int* __restrict__ csr_src, unsigned char* __restrict__ flags2, int M) {
    int gtid = blockIdx.x * blockDim.x + threadIdx.x;
    int i = gtid >> 6;
    int lane = threadIdx.x & 63;
    if (i >= M) return;
    int n = plist[i];
    int start = row_ptr[n], end = row_ptr[n + 1];
    for (int e = start + lane; e < end; e += 64) flags2[csr_src[e]] = 1;
}

// ---------- flags1: mark in-neighbors of flagged2 nodes (conv1 needed set) ----------
__global__ __launch_bounds__(128) void flag1_kernel(
        const unsigned char* __restrict__ flags2, const int* __restrict__ row_ptr,
        const int* __restrict__ csr_src, unsigned char* __restrict__ flags1, int N) {
    int gtid = blockIdx.x * blockDim.x + threadIdx.x;
    int n = gtid >> 6;
    int lane = threadIdx.x & 63;
    if (n >= N || !flags2[n]) return;
    int start = row_ptr[n], end = row_ptr[n + 1];
    for (int e = start + lane; e < end; e += 64) flags1[csr_src[e]] = 1;
}

// ---------- embedding gather, pre-scaled + bf16 pack ----------
__global__ void embed_kernel(const int* __restrict__ z, const float* __restrict__ z_table,
                             const float* __restrict__ inv_out,
                             uint2* __restrict__ xs, int N) {
    int t = blockIdx.x * blockDim.x + threadIdx.x;
    int n = t >> 5;          // 32 uint2 per row (H=128 bf16)
    int c = t & 31;
    if (n < N) {
        int zz = z[n];
        float w = inv_out[n];
        float4 v = reinterpret_cast<const float4*>(z_table)[(size_t)zz * 32 + c];
        uint2 p;
        p.x = pack_bf16x2(v.x * w, v.y * w);
        p.y = pack_bf16x2(v.z * w, v.w * w);
        xs[(size_t)n * 32 + c] = p;
    }
}

// ---------- generic bf16->bf16 conv body (8-way, flag-masked) ----------
__device__ inline void conv_bf16_body(
        const unsigned* __restrict__ xs, unsigned* __restrict__ out_bf,
        const int* __restrict__ row_ptr, const int* __restrict__ csr_src,
        const float* __restrict__ inv_out, const float* __restrict__ inv_in,
        const float* __restrict__ bias, int n, int lane) {
    int start = row_ptr[n];
    int end   = row_ptr[n + 1];

    float ax0 = 0.f, ay0 = 0.f, ax1 = 0.f, ay1 = 0.f;
    float ax2 = 0.f, ay2 = 0.f, ax3 = 0.f, ay3 = 0.f;
    float ax4 = 0.f, ay4 = 0.f, ax5 = 0.f, ay5 = 0.f;
    float ax6 = 0.f, ay6 = 0.f, ax7 = 0.f, ay7 = 0.f;
    int e = start;
    for (; e + 8 <= end; e += 8) {
        int s0 = csr_src[e + 0], s1 = csr_src[e + 1];
        int s2 = csr_src[e + 2], s3 = csr_src[e + 3];
        int s4 = csr_src[e + 4], s5 = csr_src[e + 5];
        int s6 = csr_src[e + 6], s7 = csr_src[e + 7];
        unsigned v0 = xs[(size_t)s0 * 64 + lane];
        unsigned v1 = xs[(size_t)s1 * 64 + lane];
        unsigned v2 = xs[(size_t)s2 * 64 + lane];
        unsigned v3 = xs[(size_t)s3 * 64 + lane];
        unsigned v4 = xs[(size_t)s4 * 64 + lane];
        unsigned v5 = xs[(size_t)s5 * 64 + lane];
        unsigned v6 = xs[(size_t)s6 * 64 + lane];
        unsigned v7 = xs[(size_t)s7 * 64 + lane];
        ax0 += bf16_lo(v0); ay0 += bf16_hi(v0);
        ax1 += bf16_lo(v1); ay1 += bf16_hi(v1);
        ax2 += bf16_lo(v2); ay2 += bf16_hi(v2);
        ax3 += bf16_lo(v3); ay3 += bf16_hi(v3);
        ax4 += bf16_lo(v4); ay4 += bf16_hi(v4);
        ax5 += bf16_lo(v5); ay5 += bf16_hi(v5);
        ax6 += bf16_lo(v6); ay6 += bf16_hi(v6);
        ax7 += bf16_lo(v7); ay7 += bf16_hi(v7);
    }
    if (e + 4 <= end) {
        int s0 = csr_src[e + 0], s1 = csr_src[e + 1];
        int s2 = csr_src[e + 2], s3 = csr_src[e + 3];
        unsigned v0 = xs[(size_t)s0 * 64 + lane];
        unsigned v1 = xs[(size_t)s1 * 64 + lane];
        unsigned v2 = xs[(size_t)s2 * 64 + lane];
        unsigned v3 = xs[(size_t)s3 * 64 + lane];
        ax0 += bf16_lo(v0); ay0 += bf16_hi(v0);
        ax1 += bf16_lo(v1); ay1 += bf16_hi(v1);
        ax2 += bf16_lo(v2); ay2 += bf16_hi(v2);
        ax3 += bf16_lo(v3); ay3 += bf16_hi(v3);
        e += 4;
    }
    for (; e < end; ++e) {
        unsigned v = xs[(size_t)csr_src[e] * 64 + lane];
        ax0 += bf16_lo(v); ay0 += bf16_hi(v);
    }
    float accx = ((ax0 + ax1) + (ax2 + ax3)) + ((ax4 + ax5) + (ax6 + ax7));
    float accy = ((ay0 + ay1) + (ay2 + ay3)) + ((ay4 + ay5) + (ay6 + ay7));

    float win = inv_in[n];
    float2 b = reinterpret_cast<const float2*>(bias)[lane];
    float wout = inv_out[n];
    float ox = fmaxf(accx * win + b.x, 0.0f) * wout;
    float oy = fmaxf(accy * win + b.y, 0.0f) * wout;
    out_bf[(size_t)n * 64 + lane] = pack_bf16x2(ox, oy);
}

// ---------- layer-1 conv: gather from pre-scaled bf16 embed buffer, flags1 (~92%) ----------
__global__ __launch_bounds__(128) void conv1_kernel(
        const unsigned* __restrict__ xs, const unsigned char* __restrict__ flags1,
        unsigned* __restrict__ out_bf,
        const int* __restrict__ row_ptr, const int* __restrict__ csr_src,
        const float* __restrict__ inv_out, const float* __restrict__ inv_in,
        const float* __restrict__ bias, int N) {
    int gtid = blockIdx.x * blockDim.x + threadIdx.x;
    int n = gtid >> 6;
    int lane = threadIdx.x & 63;
    if (n >= N || !flags1[n]) return;
    conv_bf16_body(xs, out_bf, row_ptr, csr_src, inv_out, inv_in, bias, n, lane);
}

// ---------- layer-2 conv: flags2-masked (~16% of nodes) ----------
__global__ __launch_bounds__(128) void conv2_kernel(
        const unsigned* __restrict__ xs, const unsigned char* __restrict__ flags2,
        unsigned* __restrict__ out_bf,
        const int* __restrict__ row_ptr, const int* __restrict__ csr_src,
        const float* __restrict__ inv_out, const float* __restrict__ inv_in,
        const float* __restrict__ bias, int N) {
    int gtid = blockIdx.x * blockDim.x + threadIdx.x;
    int n = gtid >> 6;
    int lane = threadIdx.x & 63;
    if (n >= N || !flags2[n]) return;
    conv_bf16_body(xs, out_bf, row_ptr, csr_src, inv_out, inv_in, bias, n, lane);
}

// ---------- layer-3 conv, PAIR NODES ONLY (M = 2B rows) ----------
__global__ __launch_bounds__(128) void conv3_kernel(
        const unsigned* __restrict__ xs, const int* __restrict__ plist,
        float* __restrict__ xf,
        const int* __restrict__ row_ptr, const int* __restrict__ csr_src,
        const float* __restrict__ inv_in, const float* __restrict__ bias, int M) {
    int gtid = blockIdx.x * blockDim.x + threadIdx.x;
    int i = gtid >> 6;
    int lane = threadIdx.x & 63;
    if (i >= M) return;
    int n = plist[i];

    int start = row_ptr[n];
    int end   = row_ptr[n + 1];

    float ax0 = 0.f, ay0 = 0.f, ax1 = 0.f, ay1 = 0.f;
    float ax2 = 0.f, ay2 = 0.f, ax3 = 0.f, ay3 = 0.f;
    int e = start;
    for (; e + 4 <= end; e += 4) {
        int s0 = csr_src[e + 0], s1 = csr_src[e + 1];
        int s2 = csr_src[e + 2], s3 = csr_src[e + 3];
        unsigned v0 = xs[(size_t)s0 * 64 + lane];
        unsigned v1 = xs[(size_t)s1 * 64 + lane];
        unsigned v2 = xs[(size_t)s2 * 64 + lane];
        unsigned v3 = xs[(size_t)s3 * 64 + lane];
        ax0 += bf16_lo(v0); ay0 += bf16_hi(v0);
        ax1 += bf16_lo(v1); ay1 += bf16_hi(v1);
        ax2 += bf16_lo(v2); ay2 += bf16_hi(v2);
        ax3 += bf16_lo(v3); ay3 += bf16_hi(v3);
    }
    for (; e < end; ++e) {
        unsigned v = xs[(size_t)csr_src[e] * 64 + lane];
        ax0 += bf16_lo(v); ay0 += bf16_hi(v);
    }
    float accx = (ax0 + ax1) + (ax2 + ax3);
    float accy = (ay0 + ay1) + (ay2 + ay3);

    float win = inv_in[n];
    float2 b = reinterpret_cast<const float2*>(bias)[lane];
    float ox = accx * win + b.x;
    float oy = accy * win + b.y;
    reinterpret_cast<float2*>(xf + (size_t)i * HDIM)[lane] = make_float2(ox, oy);
}

// ---------- center pooling + 2-layer MLP over compact xf ----------
__global__ __launch_bounds__(128) void mlp_kernel(
        const float* __restrict__ xf,
        const float* __restrict__ W1, const float* __restrict__ b1,
        const float* __restrict__ W2, const float* __restrict__ b2,
        float* __restrict__ out, int B) {
    __shared__ float xp[HDIM];
    __shared__ float red[HDIM];
    int p = blockIdx.x;
    int t = threadIdx.x;
    xp[t] = xf[(size_t)p * HDIM + t] * xf[(size_t)(B + p) * HDIM + t];
    __syncthreads();
    float h = b1[t];
    #pragma unroll 8
    for (int k = 0; k < HDIM; ++k) h += xp[k] * W1[k * HDIM + t];
    h = fmaxf(h, 0.0f);
    red[t] = h * W2[t];
    __syncthreads();
    for (int s = 64; s > 0; s >>= 1) {
        if (t < s) red[t] += red[t + s];
        __syncthreads();
    }
    if (t == 0) out[p] = red[0] + b2[0];
}

extern "C" void kernel_launch(void* const* d_in, const int* in_sizes, int n_in,
                              void* d_out, int out_size, void* d_ws, size_t ws_size,
                              hipStream_t stream) {
    const int*   z       = (const int*)d_in[0];
    const int*   src     = (const int*)d_in[1];
    const int*   dst     = (const int*)d_in[2];
    const int*   pairs   = (const int*)d_in[3];
    const float* z_table = (const float*)d_in[4];
    const float* bias[3] = {(const float*)d_in[5], (const float*)d_in[6], (const float*)d_in[7]};
    const float* W1      = (const float*)d_in[8];
    const float* b1      = (const float*)d_in[9];
    const float* W2      = (const float*)d_in[10];
    const float* b2      = (const float*)d_in[11];

    const int N = in_sizes[0];
    const int E = in_sizes[1];
    const int B = in_sizes[3] / 2;
    const int M = 2 * B;                       // pair-node list length
    const int nblk = (N + SCAN_CHUNK - 1) / SCAN_CHUNK;
    const int window = (N + NBUK - 1) / NBUK;  // per-bucket node window

    char* ws = (char*)d_ws;
    size_t off = 0;
    auto carve = [&](size_t bytes) -> void* {
        void* p = ws + off;
        off = (off + bytes + 255) & ~(size_t)255;
        return p;
    };
    int*      deg_out = (int*)carve((size_t)N * 4);   // fallback only
    int*      deg_in  = (int*)carve((size_t)N * 4);
    float*    inv_out = (float*)carve((size_t)N * 4);
    float*    inv_in  = (float*)carve((size_t)N * 4);
    int*      row_ptr = (int*)carve((size_t)(N + 1) * 4);
    int*      pos     = (int*)carve((size_t)N * 4);
    int*      blk_sum = (int*)carve((size_t)nblk * 4);
    int*      blk_off = (int*)carve((size_t)nblk * 4);
    int*      csr_src = (int*)carve((size_t)E * 4);
    unsigned* xe      = (unsigned*)carve((size_t)N * 64 * 4);   // embed out, bf16x2
    unsigned* xb      = (unsigned*)carve((size_t)N * 64 * 4);   // conv1 out, bf16x2
    unsigned* mbuf    = (unsigned*)carve((size_t)N * 64 * 4);   // conv2 out, bf16x2
    float*    xf      = (float*)carve((size_t)M * HDIM * 4);    // compact pair features
    unsigned char* flags1 = (unsigned char*)carve((size_t)N);
    unsigned char* flags2 = (unsigned char*)carve((size_t)N);

    // radix-partition extras (packed staging)
    const int mean = (E + NBUK - 1) / NBUK;
    const int cap  = (int)((((size_t)mean * 2) + 255) / 256) * 256;   // 2x headroom
    int*            alloc    = (int*)carve((size_t)NBUK * 4);
    int*            alloc2   = (int*)carve((size_t)NBUK * 4);
    unsigned*       staging  = (unsigned*)carve((size_t)NBUK * (size_t)cap * 4);
    unsigned short* staging2 = (unsigned short*)carve((size_t)NBUK * (size_t)cap * 2);
    const bool pack_ok  = (N < (1 << 23)) && (window <= 512);
    const bool use_part = pack_ok && (off <= ws_size);

    if (use_part) {
        const int edges_per_block = 1024 * PART_EPT;
        const int pblocks = (E + edges_per_block - 1) / edges_per_block;
        init_alloc_kernel<<<1, NBUK, 0, stream>>>(alloc, alloc2, cap);
        partition_kernel<<<pblocks, 1024, 0, stream>>>(
            src, dst, alloc, alloc2, staging, staging2, E, N, cap);
        hist_in_kernel<<<NBUK, 256, 0, stream>>>(alloc, staging, deg_in, cap, N);
        hist_out_kernel<<<NBUK, 256, 0, stream>>>(alloc2, staging2, inv_out, cap, N);
        scan_blk_sum<<<nblk, 1024, 0, stream>>>(deg_in, blk_sum, N);
        scan_blk_off<<<1, 128, 0, stream>>>(blk_sum, blk_off, nblk);
        scan_apply<<<nblk, 1024, 0, stream>>>(deg_in, blk_off, row_ptr, pos, inv_in, N);
        scatter_kernel<<<NBUK * SCHUNK, 256, 0, stream>>>(alloc, staging, pos, csr_src, cap, N);
    } else {
        hipMemsetAsync(deg_out, 0, (size_t)N * 4, stream);
        hipMemsetAsync(deg_in,  0, (size_t)N * 4, stream);
        deg_kernel<<<(E + 255) / 256, 256, 0, stream>>>(src, dst, deg_out, deg_in, E);
        inv_kernel<<<(N + 255) / 256, 256, 0, stream>>>(deg_out, deg_in, inv_out, inv_in, N);
        scan_blk_sum<<<nblk, 1024, 0, stream>>>(deg_in, blk_sum, N);
        scan_blk_off<<<1, 128, 0, stream>>>(blk_sum, blk_off, nblk);
        scan_apply<<<nblk, 1024, 0, stream>>>(deg_in, blk_off, row_ptr, pos, inv_in, N);
        fill_kernel<<<(E + 255) / 256, 256, 0, stream>>>(src, dst, pos, csr_src, E);
    }

    // needed-set flags (exact pruning) + embed
    hipMemsetAsync(flags1, 0, (size_t)N, stream);
    hipMemsetAsync(flags2, 0, (size_t)N, stream);
    flag2_kernel<<<((long long)M * 64 + 127) / 128, 128, 0, stream>>>(
        pairs, row_ptr, csr_src, flags2, M);
    flag1_kernel<<<((long long)N * 64 + 127) / 128, 128, 0, stream>>>(
        flags2, row_ptr, csr_src, flags1, N);
    embed_kernel<<<((size_t)N * 32 + 255) / 256, 256, 0, stream>>>(
        z, z_table, inv_out, (uint2*)xe, N);

    long long threads = (long long)N * 64;
    conv1_kernel<<<(threads + 127) / 128, 128, 0, stream>>>(
        xe, flags1, xb, row_ptr, csr_src, inv_out, inv_in, bias[0], N);
    conv2_kernel<<<(threads + 127) / 128, 128, 0, stream>>>(
        xb, flags2, mbuf, row_ptr, csr_src, inv_out, inv_in, bias[1], N);
    long long pthreads = (long long)M * 64;
    conv3_kernel<<<(pthreads + 127) / 128, 128, 0, stream>>>(
        mbuf, pairs, xf, row_ptr, csr_src, inv_in, bias[2], M);

    mlp_kernel<<<B, 128, 0, stream>>>(xf, W1, b1, W2, b2, (float*)d_out, B);
}

// Round 15
// 205.358 us; speedup vs baseline: 4.2547x; 1.1014x over previous
//
#include <hip/hip_runtime.h>

#define HDIM 128
#define SCAN_CHUNK 1024
#define NBUK 256          // range buckets for radix partition
#define PART_EPT 2        // edges per thread in partition kernel
#define SCHUNK 8          // scatter chunks per bucket

// ---------- bf16x2 pack/unpack (RNE) ----------
__device__ inline unsigned pack_bf16x2(float a, float b) {
    unsigned ua = __float_as_uint(a);
    unsigned ub = __float_as_uint(b);
    ua = (ua + 0x7FFFu + ((ua >> 16) & 1u)) >> 16;
    ub = (ub + 0x7FFFu + ((ub >> 16) & 1u)) >> 16;
    return ua | (ub << 16);
}
__device__ inline float bf16_lo(unsigned v) { return __uint_as_float(v << 16); }
__device__ inline float bf16_hi(unsigned v) { return __uint_as_float(v & 0xFFFF0000u); }

// ================= fallback path (used only if ws too small) =================
__global__ void deg_kernel(const int* __restrict__ src, const int* __restrict__ dst,
                           int* __restrict__ deg_out, int* __restrict__ deg_in, int E) {
    int e = blockIdx.x * blockDim.x + threadIdx.x;
    if (e < E) {
        atomicAdd(&deg_out[src[e]], 1);
        atomicAdd(&deg_in[dst[e]], 1);
    }
}

__global__ void inv_kernel(const int* __restrict__ deg_out, const int* __restrict__ deg_in,
                           float* __restrict__ inv_out, float* __restrict__ inv_in, int N) {
    int n = blockIdx.x * blockDim.x + threadIdx.x;
    if (n < N) {
        float dO = (float)(deg_out[n] > 1 ? deg_out[n] : 1);
        float dI = (float)(deg_in[n]  > 1 ? deg_in[n]  : 1);
        inv_out[n] = 1.0f / sqrtf(dO);
        inv_in[n]  = 1.0f / sqrtf(dI);
    }
}

__global__ __launch_bounds__(1024) void scan_blk_sum(const int* __restrict__ deg,
                                                     int* __restrict__ blk_sum, int n) {
    __shared__ int red[1024];
    int tid = threadIdx.x;
    int i = blockIdx.x * SCAN_CHUNK + tid;
    red[tid] = (i < n) ? deg[i] : 0;
    __syncthreads();
    for (int s = 512; s > 0; s >>= 1) {
        if (tid < s) red[tid] += red[tid + s];
        __syncthreads();
    }
    if (tid == 0) blk_sum[blockIdx.x] = red[0];
}

__global__ __launch_bounds__(128) void scan_blk_off(const int* __restrict__ blk_sum,
                                                    int* __restrict__ blk_off, int nblk) {
    __shared__ int buf[128];
    int tid = threadIdx.x;
    int v = (tid < nblk) ? blk_sum[tid] : 0;
    buf[tid] = v;
    __syncthreads();
    for (int offset = 1; offset < 128; offset <<= 1) {
        int t = (tid >= offset) ? buf[tid - offset] : 0;
        __syncthreads();
        buf[tid] += t;
        __syncthreads();
    }
    if (tid < nblk) blk_off[tid] = buf[tid] - v;   // exclusive
}

__global__ __launch_bounds__(1024) void scan_apply(const int* __restrict__ deg,
                                                   const int* __restrict__ blk_off,
                                                   int* __restrict__ row_ptr,
                                                   int* __restrict__ pos,
                                                   float* __restrict__ inv_in, int n) {
    __shared__ int buf[1024];
    int tid = threadIdx.x;
    int i = blockIdx.x * SCAN_CHUNK + tid;
    int v = (i < n) ? deg[i] : 0;
    buf[tid] = v;
    __syncthreads();
    for (int offset = 1; offset < 1024; offset <<= 1) {
        int t = (tid >= offset) ? buf[tid - offset] : 0;
        __syncthreads();
        buf[tid] += t;
        __syncthreads();
    }
    int base = blk_off[blockIdx.x];
    if (i < n) {
        int incl = base + buf[tid];
        row_ptr[i + 1] = incl;
        pos[i] = incl - v;
        inv_in[i] = 1.0f / sqrtf((float)(v > 1 ? v : 1));
    }
    if (i == 0) row_ptr[0] = 0;
}

__global__ void fill_kernel(const int* __restrict__ src, const int* __restrict__ dst,
                            int* __restrict__ pos, int* __restrict__ csr_src, int E) {
    int e = blockIdx.x * blockDim.x + threadIdx.x;
    if (e < E) {
        int d = dst[e];
        int idx = atomicAdd(&pos[d], 1);
        csr_src[idx] = src[e];
    }
}

// ================= fast path =================
__global__ void init_alloc_kernel(int* __restrict__ alloc, int* __restrict__ alloc2, int cap) {
    int i = threadIdx.x;        // one block of NBUK threads
    alloc[i]  = i * cap;
    alloc2[i] = i * cap;
}

// radix partition, PACKED staging:
// staging[idx]  = src | (dst - lo(bk)) << 23   (dst-bucketed; local dst < 512)
// staging2[idx] = (ushort)(src - lo(bs))       (src-bucketed; for out-degree)
__global__ __launch_bounds__(1024) void partition_kernel(
        const int* __restrict__ src, const int* __restrict__ dst,
        int* __restrict__ alloc, int* __restrict__ alloc2,
        unsigned* __restrict__ staging, unsigned short* __restrict__ staging2,
        int E, int N, int cap) {
    __shared__ int lcnt[NBUK];
    __shared__ int lbase[NBUK];
    __shared__ int lcnt2[NBUK];
    __shared__ int lbase2[NBUK];
    int tid = threadIdx.x;
    if (tid < NBUK) { lcnt[tid] = 0; lcnt2[tid] = 0; }
    __syncthreads();
    int base_e = blockIdx.x * (1024 * PART_EPT);
    unsigned pk[PART_EPT]; unsigned short pk2[PART_EPT];
    int bk[PART_EPT], rk[PART_EPT], bs[PART_EPT], rs[PART_EPT];
    #pragma unroll
    for (int j = 0; j < PART_EPT; ++j) {
        int e = base_e + j * 1024 + tid;    // coalesced
        if (e < E) {
            int s = src[e];
            int d = dst[e];
            bk[j] = (int)(((long long)d * NBUK) / N);
            int lo_d = (bk[j] * N + NBUK - 1) / NBUK;
            pk[j] = (unsigned)s | ((unsigned)(d - lo_d) << 23);
            rk[j] = atomicAdd(&lcnt[bk[j]], 1);
            bs[j] = (int)(((long long)s * NBUK) / N);
            int lo_s = (bs[j] * N + NBUK - 1) / NBUK;
            pk2[j] = (unsigned short)(s - lo_s);
            rs[j] = atomicAdd(&lcnt2[bs[j]], 1);
        } else {
            bk[j] = -1;
        }
    }
    __syncthreads();
    if (tid < NBUK) {
        int c = lcnt[tid];
        lbase[tid] = (c > 0) ? atomicAdd(&alloc[tid], c) : 0;
        int c2 = lcnt2[tid];
        lbase2[tid] = (c2 > 0) ? atomicAdd(&alloc2[tid], c2) : 0;
    }
    __syncthreads();
    #pragma unroll
    for (int j = 0; j < PART_EPT; ++j) {
        if (bk[j] >= 0) {
            int idx = lbase[bk[j]] + rk[j];
            if (idx < (bk[j] + 1) * cap)    // overflow clamp
                staging[idx] = pk[j];
            int idx2 = lbase2[bs[j]] + rs[j];
            if (idx2 < (bs[j] + 1) * cap)
                staging2[idx2] = pk2[j];
        }
    }
}

// exclusive prefix over per-bucket stored counts -> bucket_base (1 block)
__global__ __launch_bounds__(NBUK) void bucket_off_kernel(
        const int* __restrict__ alloc, int* __restrict__ bucket_base, int cap) {
    __shared__ int buf[NBUK];
    int tid = threadIdx.x;
    int cnt = alloc[tid] - tid * cap;
    if (cnt > cap) cnt = cap;
    buf[tid] = cnt;
    __syncthreads();
    for (int offset = 1; offset < NBUK; offset <<= 1) {
        int t = (tid >= offset) ? buf[tid - offset] : 0;
        __syncthreads();
        buf[tid] += t;
        __syncthreads();
    }
    bucket_base[tid] = buf[tid] - cnt;   // exclusive
}

// FUSED per-bucket: dst-hist + src-hist + within-bucket scan ->
// row_ptr, pos, inv_in, inv_out for the bucket's node window (<=512).
__global__ __launch_bounds__(512) void hist_scan_kernel(
        const int* __restrict__ alloc, const int* __restrict__ alloc2,
        const unsigned* __restrict__ staging, const unsigned short* __restrict__ staging2,
        const int* __restrict__ bucket_base,
        int* __restrict__ row_ptr, int* __restrict__ pos,
        float* __restrict__ inv_in, float* __restrict__ inv_out,
        int cap, int N) {
    __shared__ int h[512];
    __shared__ int h2[512];
    int b = blockIdx.x;
    int t = threadIdx.x;
    int lo = (b * N + NBUK - 1) / NBUK;
    int hi = ((b + 1) * N + NBUK - 1) / NBUK;
    if (hi > N) hi = N;
    int w = hi - lo;
    h[t] = 0; h2[t] = 0;
    __syncthreads();
    int base = b * cap;
    int cnt  = alloc[b]  - base; if (cnt  > cap) cnt  = cap;
    int cnt2 = alloc2[b] - base; if (cnt2 > cap) cnt2 = cap;
    for (int i = t; i < cnt; i += 512)
        atomicAdd(&h[staging[base + i] >> 23], 1);
    for (int i = t; i < cnt2; i += 512)
        atomicAdd(&h2[staging2[base + i]], 1);
    __syncthreads();
    // out-degree -> inv_out
    if (t < w) {
        int v2 = h2[t];
        inv_out[lo + t] = 1.0f / sqrtf((float)(v2 > 1 ? v2 : 1));
    }
    // in-degree: save, then inclusive scan h in-place (Hillis-Steele, 512)
    int v = h[t];
    __syncthreads();
    for (int offset = 1; offset < 512; offset <<= 1) {
        int tmp = (t >= offset) ? h[t - offset] : 0;
        __syncthreads();
        h[t] += tmp;
        __syncthreads();
    }
    int gbase = bucket_base[b];
    if (t < w) {
        int incl = gbase + h[t];
        row_ptr[lo + t + 1] = incl;
        pos[lo + t] = incl - v;
        inv_in[lo + t] = 1.0f / sqrtf((float)(v > 1 ? v : 1));
    }
    if (b == 0 && t == 0) row_ptr[0] = 0;
}

// chunked per-bucket scatter (bucket = blockIdx & 255 -> same XCD per bucket)
__global__ __launch_bounds__(256) void scatter_kernel(
        const int* __restrict__ alloc, const unsigned* __restrict__ staging,
        int* __restrict__ pos, int* __restrict__ csr_src, int cap, int N) {
    int b = blockIdx.x & (NBUK - 1);
    int chunk = blockIdx.x >> 8;
    int lo = (b * N + NBUK - 1) / NBUK;
    int base = b * cap;
    int cnt = alloc[b] - base;
    if (cnt > cap) cnt = cap;
    int per = (cnt + SCHUNK - 1) / SCHUNK;
    int i0 = chunk * per;
    int i1 = i0 + per; if (i1 > cnt) i1 = cnt;
    for (int i = i0 + threadIdx.x; i < i1; i += 256) {
        unsigned p = staging[base + i];
        int d = lo + (int)(p >> 23);
        int s = (int)(p & 0x7FFFFFu);
        int slot = atomicAdd(&pos[d], 1);
        csr_src[slot] = s;
    }
}

// ---------- needed-set flags (exact pruning; idempotent byte stores) ----------
__global__ __launch_bounds__(128) void flag2_kernel(
        const int* __restrict__ plist, const int* __restrict__ row_ptr,
        const int* __restrict__ csr_src, unsigned char* __restrict__ flags2, int M) {
    int gtid = blockIdx.x * blockDim.x + threadIdx.x;
    int i = gtid >> 6;
    int lane = threadIdx.x & 63;
    if (i >= M) return;
    int n = plist[i];
    int start = row_ptr[n], end = row_ptr[n + 1];
    for (int e = start + lane; e < end; e += 64) flags2[csr_src[e]] = 1;
}

__global__ __launch_bounds__(128) void flag1_kernel(
        const unsigned char* __restrict__ flags2, const int* __restrict__ row_ptr,
        const int* __restrict__ csr_src, unsigned char* __restrict__ flags1, int N) {
    int gtid = blockIdx.x * blockDim.x + threadIdx.x;
    int n = gtid >> 6;
    int lane = threadIdx.x & 63;
    if (n >= N || !flags2[n]) return;
    int start = row_ptr[n], end = row_ptr[n + 1];
    for (int e = start + lane; e < end; e += 64) flags1[csr_src[e]] = 1;
}

// ---------- embedding gather, pre-scaled + bf16 pack ----------
__global__ void embed_kernel(const int* __restrict__ z, const float* __restrict__ z_table,
                             const float* __restrict__ inv_out,
                             uint2* __restrict__ xs, int N) {
    int t = blockIdx.x * blockDim.x + threadIdx.x;
    int n = t >> 5;          // 32 uint2 per row (H=128 bf16)
    int c = t & 31;
    if (n < N) {
        int zz = z[n];
        float w = inv_out[n];
        float4 v = reinterpret_cast<const float4*>(z_table)[(size_t)zz * 32 + c];
        uint2 p;
        p.x = pack_bf16x2(v.x * w, v.y * w);
        p.y = pack_bf16x2(v.z * w, v.w * w);
        xs[(size_t)n * 32 + c] = p;
    }
}

// ---------- generic bf16->bf16 conv body (8-way, flag-masked) ----------
__device__ inline void conv_bf16_body(
        const unsigned* __restrict__ xs, unsigned* __restrict__ out_bf,
        const int* __restrict__ row_ptr, const int* __restrict__ csr_src,
        const float* __restrict__ inv_out, const float* __restrict__ inv_in,
        const float* __restrict__ bias, int n, int lane) {
    int start = row_ptr[n];
    int end   = row_ptr[n + 1];

    float ax0 = 0.f, ay0 = 0.f, ax1 = 0.f, ay1 = 0.f;
    float ax2 = 0.f, ay2 = 0.f, ax3 = 0.f, ay3 = 0.f;
    float ax4 = 0.f, ay4 = 0.f, ax5 = 0.f, ay5 = 0.f;
    float ax6 = 0.f, ay6 = 0.f, ax7 = 0.f, ay7 = 0.f;
    int e = start;
    for (; e + 8 <= end; e += 8) {
        int s0 = csr_src[e + 0], s1 = csr_src[e + 1];
        int s2 = csr_src[e + 2], s3 = csr_src[e + 3];
        int s4 = csr_src[e + 4], s5 = csr_src[e + 5];
        int s6 = csr_src[e + 6], s7 = csr_src[e + 7];
        unsigned v0 = xs[(size_t)s0 * 64 + lane];
        unsigned v1 = xs[(size_t)s1 * 64 + lane];
        unsigned v2 = xs[(size_t)s2 * 64 + lane];
        unsigned v3 = xs[(size_t)s3 * 64 + lane];
        unsigned v4 = xs[(size_t)s4 * 64 + lane];
        unsigned v5 = xs[(size_t)s5 * 64 + lane];
        unsigned v6 = xs[(size_t)s6 * 64 + lane];
        unsigned v7 = xs[(size_t)s7 * 64 + lane];
        ax0 += bf16_lo(v0); ay0 += bf16_hi(v0);
        ax1 += bf16_lo(v1); ay1 += bf16_hi(v1);
        ax2 += bf16_lo(v2); ay2 += bf16_hi(v2);
        ax3 += bf16_lo(v3); ay3 += bf16_hi(v3);
        ax4 += bf16_lo(v4); ay4 += bf16_hi(v4);
        ax5 += bf16_lo(v5); ay5 += bf16_hi(v5);
        ax6 += bf16_lo(v6); ay6 += bf16_hi(v6);
        ax7 += bf16_lo(v7); ay7 += bf16_hi(v7);
    }
    if (e + 4 <= end) {
        int s0 = csr_src[e + 0], s1 = csr_src[e + 1];
        int s2 = csr_src[e + 2], s3 = csr_src[e + 3];
        unsigned v0 = xs[(size_t)s0 * 64 + lane];
        unsigned v1 = xs[(size_t)s1 * 64 + lane];
        unsigned v2 = xs[(size_t)s2 * 64 + lane];
        unsigned v3 = xs[(size_t)s3 * 64 + lane];
        ax0 += bf16_lo(v0); ay0 += bf16_hi(v0);
        ax1 += bf16_lo(v1); ay1 += bf16_hi(v1);
        ax2 += bf16_lo(v2); ay2 += bf16_hi(v2);
        ax3 += bf16_lo(v3); ay3 += bf16_hi(v3);
        e += 4;
    }
    for (; e < end; ++e) {
        unsigned v = xs[(size_t)csr_src[e] * 64 + lane];
        ax0 += bf16_lo(v); ay0 += bf16_hi(v);
    }
    float accx = ((ax0 + ax1) + (ax2 + ax3)) + ((ax4 + ax5) + (ax6 + ax7));
    float accy = ((ay0 + ay1) + (ay2 + ay3)) + ((ay4 + ay5) + (ay6 + ay7));

    float win = inv_in[n];
    float2 b = reinterpret_cast<const float2*>(bias)[lane];
    float wout = inv_out[n];
    float ox = fmaxf(accx * win + b.x, 0.0f) * wout;
    float oy = fmaxf(accy * win + b.y, 0.0f) * wout;
    out_bf[(size_t)n * 64 + lane] = pack_bf16x2(ox, oy);
}

__global__ __launch_bounds__(128) void conv1_kernel(
        const unsigned* __restrict__ xs, const unsigned char* __restrict__ flags1,
        unsigned* __restrict__ out_bf,
        const int* __restrict__ row_ptr, const int* __restrict__ csr_src,
        const float* __restrict__ inv_out, const float* __restrict__ inv_in,
        const float* __restrict__ bias, int N) {
    int gtid = blockIdx.x * blockDim.x + threadIdx.x;
    int n = gtid >> 6;
    int lane = threadIdx.x & 63;
    if (n >= N || !flags1[n]) return;
    conv_bf16_body(xs, out_bf, row_ptr, csr_src, inv_out, inv_in, bias, n, lane);
}

__global__ __launch_bounds__(128) void conv2_kernel(
        const unsigned* __restrict__ xs, const unsigned char* __restrict__ flags2,
        unsigned* __restrict__ out_bf,
        const int* __restrict__ row_ptr, const int* __restrict__ csr_src,
        const float* __restrict__ inv_out, const float* __restrict__ inv_in,
        const float* __restrict__ bias, int N) {
    int gtid = blockIdx.x * blockDim.x + threadIdx.x;
    int n = gtid >> 6;
    int lane = threadIdx.x & 63;
    if (n >= N || !flags2[n]) return;
    conv_bf16_body(xs, out_bf, row_ptr, csr_src, inv_out, inv_in, bias, n, lane);
}

// ---------- FUSED conv3 (both pair nodes) + center pooling + MLP, one block/pair ----------
__global__ __launch_bounds__(128) void conv3mlp_kernel(
        const unsigned* __restrict__ xs, const int* __restrict__ pairs,
        const int* __restrict__ row_ptr, const int* __restrict__ csr_src,
        const float* __restrict__ inv_in, const float* __restrict__ bias2,
        const float* __restrict__ W1, const float* __restrict__ b1,
        const float* __restrict__ W2, const float* __restrict__ b2,
        float* __restrict__ out, int B) {
    __shared__ float2 xr[2][64];     // conv3 outputs for the two pair nodes
    __shared__ float xp[HDIM];
    __shared__ float red[HDIM];
    int p = blockIdx.x;
    int t = threadIdx.x;
    int wv = t >> 6;                 // 0: pairs[p], 1: pairs[B+p]
    int lane = t & 63;
    int n = pairs[p + wv * B];

    int start = row_ptr[n];
    int end   = row_ptr[n + 1];
    float ax0 = 0.f, ay0 = 0.f, ax1 = 0.f, ay1 = 0.f;
    float ax2 = 0.f, ay2 = 0.f, ax3 = 0.f, ay3 = 0.f;
    int e = start;
    for (; e + 4 <= end; e += 4) {
        int s0 = csr_src[e + 0], s1 = csr_src[e + 1];
        int s2 = csr_src[e + 2], s3 = csr_src[e + 3];
        unsigned v0 = xs[(size_t)s0 * 64 + lane];
        unsigned v1 = xs[(size_t)s1 * 64 + lane];
        unsigned v2 = xs[(size_t)s2 * 64 + lane];
        unsigned v3 = xs[(size_t)s3 * 64 + lane];
        ax0 += bf16_lo(v0); ay0 += bf16_hi(v0);
        ax1 += bf16_lo(v1); ay1 += bf16_hi(v1);
        ax2 += bf16_lo(v2); ay2 += bf16_hi(v2);
        ax3 += bf16_lo(v3); ay3 += bf16_hi(v3);
    }
    for (; e < end; ++e) {
        unsigned v = xs[(size_t)csr_src[e] * 64 + lane];
        ax0 += bf16_lo(v); ay0 += bf16_hi(v);
    }
    float accx = (ax0 + ax1) + (ax2 + ax3);
    float accy = (ay0 + ay1) + (ay2 + ay3);

    float win = inv_in[n];
    float2 bb = reinterpret_cast<const float2*>(bias2)[lane];
    xr[wv][lane] = make_float2(accx * win + bb.x, accy * win + bb.y);
    __syncthreads();

    // center pooling: xp[t] = xa[t] * xb[t]
    const float* xa = (const float*)xr[0];
    const float* xbv = (const float*)xr[1];
    xp[t] = xa[t] * xbv[t];
    __syncthreads();

    float h = b1[t];
    #pragma unroll 8
    for (int k = 0; k < HDIM; ++k) h += xp[k] * W1[k * HDIM + t];
    h = fmaxf(h, 0.0f);
    red[t] = h * W2[t];
    __syncthreads();
    for (int s = 64; s > 0; s >>= 1) {
        if (t < s) red[t] += red[t + s];
        __syncthreads();
    }
    if (t == 0) out[p] = red[0] + b2[0];
}

extern "C" void kernel_launch(void* const* d_in, const int* in_sizes, int n_in,
                              void* d_out, int out_size, void* d_ws, size_t ws_size,
                              hipStream_t stream) {
    const int*   z       = (const int*)d_in[0];
    const int*   src     = (const int*)d_in[1];
    const int*   dst     = (const int*)d_in[2];
    const int*   pairs   = (const int*)d_in[3];
    const float* z_table = (const float*)d_in[4];
    const float* bias[3] = {(const float*)d_in[5], (const float*)d_in[6], (const float*)d_in[7]};
    const float* W1      = (const float*)d_in[8];
    const float* b1      = (const float*)d_in[9];
    const float* W2      = (const float*)d_in[10];
    const float* b2      = (const float*)d_in[11];

    const int N = in_sizes[0];
    const int E = in_sizes[1];
    const int B = in_sizes[3] / 2;
    const int M = 2 * B;
    const int nblk = (N + SCAN_CHUNK - 1) / SCAN_CHUNK;
    const int window = (N + NBUK - 1) / NBUK;

    char* ws = (char*)d_ws;
    size_t off = 0;
    auto carve = [&](size_t bytes) -> void* {
        void* p = ws + off;
        off = (off + bytes + 255) & ~(size_t)255;
        return p;
    };
    int*      deg_out = (int*)carve((size_t)N * 4);   // fallback only
    int*      deg_in  = (int*)carve((size_t)N * 4);   // fallback only
    float*    inv_out = (float*)carve((size_t)N * 4);
    float*    inv_in  = (float*)carve((size_t)N * 4);
    int*      row_ptr = (int*)carve((size_t)(N + 1) * 4);
    int*      pos     = (int*)carve((size_t)N * 4);
    int*      blk_sum = (int*)carve((size_t)nblk * 4);   // fallback only
    int*      blk_off = (int*)carve((size_t)nblk * 4);   // fallback only
    int*      csr_src = (int*)carve((size_t)E * 4);
    unsigned* xe      = (unsigned*)carve((size_t)N * 64 * 4);   // embed out, bf16x2
    unsigned* xb      = (unsigned*)carve((size_t)N * 64 * 4);   // conv1 out, bf16x2
    unsigned* mbuf    = (unsigned*)carve((size_t)N * 64 * 4);   // conv2 out, bf16x2
    unsigned char* flags1 = (unsigned char*)carve((size_t)N * 2);  // [flags1 | flags2]
    unsigned char* flags2 = flags1 + N;

    // radix-partition extras (packed staging)
    const int mean = (E + NBUK - 1) / NBUK;
    const int cap  = (int)((((size_t)mean * 2) + 255) / 256) * 256;   // 2x headroom
    int*            alloc       = (int*)carve((size_t)NBUK * 4);
    int*            alloc2      = (int*)carve((size_t)NBUK * 4);
    int*            bucket_base = (int*)carve((size_t)NBUK * 4);
    unsigned*       staging     = (unsigned*)carve((size_t)NBUK * (size_t)cap * 4);
    unsigned short* staging2    = (unsigned short*)carve((size_t)NBUK * (size_t)cap * 2);
    const bool pack_ok  = (N < (1 << 23)) && (window <= 512);
    const bool use_part = pack_ok && (off <= ws_size);

    if (use_part) {
        const int edges_per_block = 1024 * PART_EPT;
        const int pblocks = (E + edges_per_block - 1) / edges_per_block;
        init_alloc_kernel<<<1, NBUK, 0, stream>>>(alloc, alloc2, cap);
        partition_kernel<<<pblocks, 1024, 0, stream>>>(
            src, dst, alloc, alloc2, staging, staging2, E, N, cap);
        bucket_off_kernel<<<1, NBUK, 0, stream>>>(alloc, bucket_base, cap);
        hist_scan_kernel<<<NBUK, 512, 0, stream>>>(
            alloc, alloc2, staging, staging2, bucket_base,
            row_ptr, pos, inv_in, inv_out, cap, N);
        scatter_kernel<<<NBUK * SCHUNK, 256, 0, stream>>>(alloc, staging, pos, csr_src, cap, N);
    } else {
        hipMemsetAsync(deg_out, 0, (size_t)N * 4, stream);
        hipMemsetAsync(deg_in,  0, (size_t)N * 4, stream);
        deg_kernel<<<(E + 255) / 256, 256, 0, stream>>>(src, dst, deg_out, deg_in, E);
        inv_kernel<<<(N + 255) / 256, 256, 0, stream>>>(deg_out, deg_in, inv_out, inv_in, N);
        scan_blk_sum<<<nblk, 1024, 0, stream>>>(deg_in, blk_sum, N);
        scan_blk_off<<<1, 128, 0, stream>>>(blk_sum, blk_off, nblk);
        scan_apply<<<nblk, 1024, 0, stream>>>(deg_in, blk_off, row_ptr, pos, inv_in, N);
        fill_kernel<<<(E + 255) / 256, 256, 0, stream>>>(src, dst, pos, csr_src, E);
    }

    // needed-set flags (one memset for both) + embed
    hipMemsetAsync(flags1, 0, (size_t)N * 2, stream);
    flag2_kernel<<<((long long)M * 64 + 127) / 128, 128, 0, stream>>>(
        pairs, row_ptr, csr_src, flags2, M);
    flag1_kernel<<<((long long)N * 64 + 127) / 128, 128, 0, stream>>>(
        flags2, row_ptr, csr_src, flags1, N);
    embed_kernel<<<((size_t)N * 32 + 255) / 256, 256, 0, stream>>>(
        z, z_table, inv_out, (uint2*)xe, N);

    long long threads = (long long)N * 64;
    conv1_kernel<<<(threads + 127) / 128, 128, 0, stream>>>(
        xe, flags1, xb, row_ptr, csr_src, inv_out, inv_in, bias[0], N);
    conv2_kernel<<<(threads + 127) / 128, 128, 0, stream>>>(
        xb, flags2, mbuf, row_ptr, csr_src, inv_out, inv_in, bias[1], N);
    conv3mlp_kernel<<<B, 128, 0, stream>>>(
        mbuf, pairs, row_ptr, csr_src, inv_in, bias[2],
        W1, b1, W2, b2, (float*)d_out, B);
}

// Round 16
// 176.343 us; speedup vs baseline: 4.9547x; 1.1645x over previous
//
#include <hip/hip_runtime.h>

#define HDIM 128
#define SCAN_CHUNK 1024
#define NBUK 256          // range buckets for radix partition
#define PART_EPT 2        // edges per thread in partition kernel

// ---------- bf16x2 pack/unpack (RNE) ----------
__device__ inline unsigned pack_bf16x2(float a, float b) {
    unsigned ua = __float_as_uint(a);
    unsigned ub = __float_as_uint(b);
    ua = (ua + 0x7FFFu + ((ua >> 16) & 1u)) >> 16;
    ub = (ub + 0x7FFFu + ((ub >> 16) & 1u)) >> 16;
    return ua | (ub << 16);
}
__device__ inline float bf16_lo(unsigned v) { return __uint_as_float(v << 16); }
__device__ inline float bf16_hi(unsigned v) { return __uint_as_float(v & 0xFFFF0000u); }

// ================= fallback path (used only if ws too small) =================
__global__ void deg_kernel(const int* __restrict__ src, const int* __restrict__ dst,
                           int* __restrict__ deg_out, int* __restrict__ deg_in, int E) {
    int e = blockIdx.x * blockDim.x + threadIdx.x;
    if (e < E) {
        atomicAdd(&deg_out[src[e]], 1);
        atomicAdd(&deg_in[dst[e]], 1);
    }
}

__global__ void inv_kernel(const int* __restrict__ deg_out, const int* __restrict__ deg_in,
                           float* __restrict__ inv_out, float* __restrict__ inv_in, int N) {
    int n = blockIdx.x * blockDim.x + threadIdx.x;
    if (n < N) {
        float dO = (float)(deg_out[n] > 1 ? deg_out[n] : 1);
        float dI = (float)(deg_in[n]  > 1 ? deg_in[n]  : 1);
        inv_out[n] = 1.0f / sqrtf(dO);
        inv_in[n]  = 1.0f / sqrtf(dI);
    }
}

__global__ __launch_bounds__(1024) void scan_blk_sum(const int* __restrict__ deg,
                                                     int* __restrict__ blk_sum, int n) {
    __shared__ int red[1024];
    int tid = threadIdx.x;
    int i = blockIdx.x * SCAN_CHUNK + tid;
    red[tid] = (i < n) ? deg[i] : 0;
    __syncthreads();
    for (int s = 512; s > 0; s >>= 1) {
        if (tid < s) red[tid] += red[tid + s];
        __syncthreads();
    }
    if (tid == 0) blk_sum[blockIdx.x] = red[0];
}

__global__ __launch_bounds__(128) void scan_blk_off(const int* __restrict__ blk_sum,
                                                    int* __restrict__ blk_off, int nblk) {
    __shared__ int buf[128];
    int tid = threadIdx.x;
    int v = (tid < nblk) ? blk_sum[tid] : 0;
    buf[tid] = v;
    __syncthreads();
    for (int offset = 1; offset < 128; offset <<= 1) {
        int t = (tid >= offset) ? buf[tid - offset] : 0;
        __syncthreads();
        buf[tid] += t;
        __syncthreads();
    }
    if (tid < nblk) blk_off[tid] = buf[tid] - v;   // exclusive
}

__global__ __launch_bounds__(1024) void scan_apply(const int* __restrict__ deg,
                                                   const int* __restrict__ blk_off,
                                                   int* __restrict__ row_ptr,
                                                   int* __restrict__ pos,
                                                   float* __restrict__ inv_in, int n) {
    __shared__ int buf[1024];
    int tid = threadIdx.x;
    int i = blockIdx.x * SCAN_CHUNK + tid;
    int v = (i < n) ? deg[i] : 0;
    buf[tid] = v;
    __syncthreads();
    for (int offset = 1; offset < 1024; offset <<= 1) {
        int t = (tid >= offset) ? buf[tid - offset] : 0;
        __syncthreads();
        buf[tid] += t;
        __syncthreads();
    }
    int base = blk_off[blockIdx.x];
    if (i < n) {
        int incl = base + buf[tid];
        row_ptr[i + 1] = incl;
        pos[i] = incl - v;
        inv_in[i] = 1.0f / sqrtf((float)(v > 1 ? v : 1));
    }
    if (i == 0) row_ptr[0] = 0;
}

__global__ void fill_kernel(const int* __restrict__ src, const int* __restrict__ dst,
                            int* __restrict__ pos, int* __restrict__ csr_src, int E) {
    int e = blockIdx.x * blockDim.x + threadIdx.x;
    if (e < E) {
        int d = dst[e];
        int idx = atomicAdd(&pos[d], 1);
        csr_src[idx] = src[e];
    }
}

// ================= fast path =================
// radix partition, PACKED staging; allocators are zero-initialized counters:
// store position = b*cap + (running count). Guarded at cap (2x headroom).
// staging[.]  = src | (dst - lo(bk)) << 23    (dst-bucketed; local dst < 512)
// staging2[.] = (ushort)(src - lo(bs))        (src-bucketed; for out-degree)
__global__ __launch_bounds__(1024) void partition_kernel(
        const int* __restrict__ src, const int* __restrict__ dst,
        int* __restrict__ cnt, int* __restrict__ cnt2,
        unsigned* __restrict__ staging, unsigned short* __restrict__ staging2,
        int E, int N, int cap) {
    __shared__ int lcnt[NBUK];
    __shared__ int lbase[NBUK];
    __shared__ int lcnt2[NBUK];
    __shared__ int lbase2[NBUK];
    int tid = threadIdx.x;
    if (tid < NBUK) { lcnt[tid] = 0; lcnt2[tid] = 0; }
    __syncthreads();
    int base_e = blockIdx.x * (1024 * PART_EPT);
    unsigned pk[PART_EPT]; unsigned short pk2[PART_EPT];
    int bk[PART_EPT], rk[PART_EPT], bs[PART_EPT], rs[PART_EPT];
    #pragma unroll
    for (int j = 0; j < PART_EPT; ++j) {
        int e = base_e + j * 1024 + tid;    // coalesced
        if (e < E) {
            int s = src[e];
            int d = dst[e];
            bk[j] = (int)(((long long)d * NBUK) / N);
            int lo_d = (bk[j] * N + NBUK - 1) / NBUK;
            pk[j] = (unsigned)s | ((unsigned)(d - lo_d) << 23);
            rk[j] = atomicAdd(&lcnt[bk[j]], 1);
            bs[j] = (int)(((long long)s * NBUK) / N);
            int lo_s = (bs[j] * N + NBUK - 1) / NBUK;
            pk2[j] = (unsigned short)(s - lo_s);
            rs[j] = atomicAdd(&lcnt2[bs[j]], 1);
        } else {
            bk[j] = -1;
        }
    }
    __syncthreads();
    if (tid < NBUK) {
        int c = lcnt[tid];
        lbase[tid] = (c > 0) ? atomicAdd(&cnt[tid], c) : 0;
        int c2 = lcnt2[tid];
        lbase2[tid] = (c2 > 0) ? atomicAdd(&cnt2[tid], c2) : 0;
    }
    __syncthreads();
    #pragma unroll
    for (int j = 0; j < PART_EPT; ++j) {
        if (bk[j] >= 0) {
            int r = lbase[bk[j]] + rk[j];
            if (r < cap)                       // overflow clamp (>=24 sigma headroom)
                staging[(size_t)bk[j] * cap + r] = pk[j];
            int r2 = lbase2[bs[j]] + rs[j];
            if (r2 < cap)
                staging2[(size_t)bs[j] * cap + r2] = pk2[j];
        }
    }
}

// FUSED per-bucket: dst-hist + src-hist + bucket-base scan + within-bucket scan
// + row_ptr/inv_in/inv_out writes + CSR scatter (LDS-atomic pos). One kernel
// replaces hist_in, hist_out, bucket_off, scan_*, scatter.
__global__ __launch_bounds__(512) void build_kernel(
        const int* __restrict__ cnt, const int* __restrict__ cnt2,
        const unsigned* __restrict__ staging, const unsigned short* __restrict__ staging2,
        int* __restrict__ row_ptr, int* __restrict__ csr_src,
        float* __restrict__ inv_in, float* __restrict__ inv_out,
        int cap, int N) {
    __shared__ int h[512];
    __shared__ int h2[512];
    __shared__ int csum[NBUK];
    __shared__ int posl[512];
    int b = blockIdx.x;
    int t = threadIdx.x;
    int lo = (b * N + NBUK - 1) / NBUK;
    int hi = ((b + 1) * N + NBUK - 1) / NBUK;
    if (hi > N) hi = N;
    int w = hi - lo;
    h[t] = 0; h2[t] = 0;
    if (t < NBUK) {
        int c = cnt[t];
        csum[t] = (c > cap) ? cap : c;
    }
    __syncthreads();
    size_t base = (size_t)b * cap;
    int cnt_b  = cnt[b];  if (cnt_b  > cap) cnt_b  = cap;
    int cnt2_b = cnt2[b]; if (cnt2_b > cap) cnt2_b = cap;
    for (int i = t; i < cnt_b; i += 512)
        atomicAdd(&h[staging[base + i] >> 23], 1);
    for (int i = t; i < cnt2_b; i += 512)
        atomicAdd(&h2[staging2[base + i]], 1);
    __syncthreads();
    // out-degree -> inv_out
    if (t < w) {
        int v2 = h2[t];
        inv_out[lo + t] = 1.0f / sqrtf((float)(v2 > 1 ? v2 : 1));
    }
    // bucket-base: inclusive scan of csum (256), same result in every block
    for (int offset = 1; offset < NBUK; offset <<= 1) {
        int tmp = (t >= offset && t < NBUK) ? csum[t - offset] : 0;
        __syncthreads();
        if (t < NBUK) csum[t] += tmp;
        __syncthreads();
    }
    int gbase = (b > 0) ? csum[b - 1] : 0;
    // in-degree: save, inclusive scan h in place (Hillis-Steele, 512)
    int v = h[t];
    __syncthreads();
    for (int offset = 1; offset < 512; offset <<= 1) {
        int tmp = (t >= offset) ? h[t - offset] : 0;
        __syncthreads();
        h[t] += tmp;
        __syncthreads();
    }
    if (t < w) {
        int incl = gbase + h[t];
        row_ptr[lo + t + 1] = incl;
        posl[t] = incl - v;          // global CSR slot base for local node t
        inv_in[lo + t] = 1.0f / sqrtf((float)(v > 1 ? v : 1));
    }
    if (b == 0 && t == 0) row_ptr[0] = 0;
    __syncthreads();
    // scatter this bucket's edges with LDS-atomic slot allocation
    for (int i = t; i < cnt_b; i += 512) {
        unsigned p = staging[base + i];
        int dl = (int)(p >> 23);
        int slot = atomicAdd(&posl[dl], 1);
        csr_src[slot] = (int)(p & 0x7FFFFFu);
    }
}

// ---------- needed-set flags (exact pruning; idempotent byte stores) ----------
__global__ __launch_bounds__(128) void flag2_kernel(
        const int* __restrict__ plist, const int* __restrict__ row_ptr,
        const int* __restrict__ csr_src, unsigned char* __restrict__ flags2, int M) {
    int gtid = blockIdx.x * blockDim.x + threadIdx.x;
    int i = gtid >> 6;
    int lane = threadIdx.x & 63;
    if (i >= M) return;
    int n = plist[i];
    int start = row_ptr[n], end = row_ptr[n + 1];
    for (int e = start + lane; e < end; e += 64) flags2[csr_src[e]] = 1;
}

__global__ __launch_bounds__(128) void flag1_kernel(
        const unsigned char* __restrict__ flags2, const int* __restrict__ row_ptr,
        const int* __restrict__ csr_src, unsigned char* __restrict__ flags1, int N) {
    int gtid = blockIdx.x * blockDim.x + threadIdx.x;
    int n = gtid >> 6;
    int lane = threadIdx.x & 63;
    if (n >= N || !flags2[n]) return;
    int start = row_ptr[n], end = row_ptr[n + 1];
    for (int e = start + lane; e < end; e += 64) flags1[csr_src[e]] = 1;
}

// ---------- embedding gather, pre-scaled + bf16 pack ----------
__global__ void embed_kernel(const int* __restrict__ z, const float* __restrict__ z_table,
                             const float* __restrict__ inv_out,
                             uint2* __restrict__ xs, int N) {
    int t = blockIdx.x * blockDim.x + threadIdx.x;
    int n = t >> 5;          // 32 uint2 per row (H=128 bf16)
    int c = t & 31;
    if (n < N) {
        int zz = z[n];
        float w = inv_out[n];
        float4 v = reinterpret_cast<const float4*>(z_table)[(size_t)zz * 32 + c];
        uint2 p;
        p.x = pack_bf16x2(v.x * w, v.y * w);
        p.y = pack_bf16x2(v.z * w, v.w * w);
        xs[(size_t)n * 32 + c] = p;
    }
}

// ---------- generic bf16->bf16 conv body (8-way, flag-masked) ----------
__device__ inline void conv_bf16_body(
        const unsigned* __restrict__ xs, unsigned* __restrict__ out_bf,
        const int* __restrict__ row_ptr, const int* __restrict__ csr_src,
        const float* __restrict__ inv_out, const float* __restrict__ inv_in,
        const float* __restrict__ bias, int n, int lane) {
    int start = row_ptr[n];
    int end   = row_ptr[n + 1];

    float ax0 = 0.f, ay0 = 0.f, ax1 = 0.f, ay1 = 0.f;
    float ax2 = 0.f, ay2 = 0.f, ax3 = 0.f, ay3 = 0.f;
    float ax4 = 0.f, ay4 = 0.f, ax5 = 0.f, ay5 = 0.f;
    float ax6 = 0.f, ay6 = 0.f, ax7 = 0.f, ay7 = 0.f;
    int e = start;
    for (; e + 8 <= end; e += 8) {
        int s0 = csr_src[e + 0], s1 = csr_src[e + 1];
        int s2 = csr_src[e + 2], s3 = csr_src[e + 3];
        int s4 = csr_src[e + 4], s5 = csr_src[e + 5];
        int s6 = csr_src[e + 6], s7 = csr_src[e + 7];
        unsigned v0 = xs[(size_t)s0 * 64 + lane];
        unsigned v1 = xs[(size_t)s1 * 64 + lane];
        unsigned v2 = xs[(size_t)s2 * 64 + lane];
        unsigned v3 = xs[(size_t)s3 * 64 + lane];
        unsigned v4 = xs[(size_t)s4 * 64 + lane];
        unsigned v5 = xs[(size_t)s5 * 64 + lane];
        unsigned v6 = xs[(size_t)s6 * 64 + lane];
        unsigned v7 = xs[(size_t)s7 * 64 + lane];
        ax0 += bf16_lo(v0); ay0 += bf16_hi(v0);
        ax1 += bf16_lo(v1); ay1 += bf16_hi(v1);
        ax2 += bf16_lo(v2); ay2 += bf16_hi(v2);
        ax3 += bf16_lo(v3); ay3 += bf16_hi(v3);
        ax4 += bf16_lo(v4); ay4 += bf16_hi(v4);
        ax5 += bf16_lo(v5); ay5 += bf16_hi(v5);
        ax6 += bf16_lo(v6); ay6 += bf16_hi(v6);
        ax7 += bf16_lo(v7); ay7 += bf16_hi(v7);
    }
    if (e + 4 <= end) {
        int s0 = csr_src[e + 0], s1 = csr_src[e + 1];
        int s2 = csr_src[e + 2], s3 = csr_src[e + 3];
        unsigned v0 = xs[(size_t)s0 * 64 + lane];
        unsigned v1 = xs[(size_t)s1 * 64 + lane];
        unsigned v2 = xs[(size_t)s2 * 64 + lane];
        unsigned v3 = xs[(size_t)s3 * 64 + lane];
        ax0 += bf16_lo(v0); ay0 += bf16_hi(v0);
        ax1 += bf16_lo(v1); ay1 += bf16_hi(v1);
        ax2 += bf16_lo(v2); ay2 += bf16_hi(v2);
        ax3 += bf16_lo(v3); ay3 += bf16_hi(v3);
        e += 4;
    }
    for (; e < end; ++e) {
        unsigned v = xs[(size_t)csr_src[e] * 64 + lane];
        ax0 += bf16_lo(v); ay0 += bf16_hi(v);
    }
    float accx = ((ax0 + ax1) + (ax2 + ax3)) + ((ax4 + ax5) + (ax6 + ax7));
    float accy = ((ay0 + ay1) + (ay2 + ay3)) + ((ay4 + ay5) + (ay6 + ay7));

    float win = inv_in[n];
    float2 b = reinterpret_cast<const float2*>(bias)[lane];
    float wout = inv_out[n];
    float ox = fmaxf(accx * win + b.x, 0.0f) * wout;
    float oy = fmaxf(accy * win + b.y, 0.0f) * wout;
    out_bf[(size_t)n * 64 + lane] = pack_bf16x2(ox, oy);
}

__global__ __launch_bounds__(128) void conv1_kernel(
        const unsigned* __restrict__ xs, const unsigned char* __restrict__ flags1,
        unsigned* __restrict__ out_bf,
        const int* __restrict__ row_ptr, const int* __restrict__ csr_src,
        const float* __restrict__ inv_out, const float* __restrict__ inv_in,
        const float* __restrict__ bias, int N) {
    int gtid = blockIdx.x * blockDim.x + threadIdx.x;
    int n = gtid >> 6;
    int lane = threadIdx.x & 63;
    if (n >= N || !flags1[n]) return;
    conv_bf16_body(xs, out_bf, row_ptr, csr_src, inv_out, inv_in, bias, n, lane);
}

__global__ __launch_bounds__(128) void conv2_kernel(
        const unsigned* __restrict__ xs, const unsigned char* __restrict__ flags2,
        unsigned* __restrict__ out_bf,
        const int* __restrict__ row_ptr, const int* __restrict__ csr_src,
        const float* __restrict__ inv_out, const float* __restrict__ inv_in,
        const float* __restrict__ bias, int N) {
    int gtid = blockIdx.x * blockDim.x + threadIdx.x;
    int n = gtid >> 6;
    int lane = threadIdx.x & 63;
    if (n >= N || !flags2[n]) return;
    conv_bf16_body(xs, out_bf, row_ptr, csr_src, inv_out, inv_in, bias, n, lane);
}

// ---------- FUSED conv3 (both pair nodes) + center pooling + MLP, one block/pair ----------
__global__ __launch_bounds__(128) void conv3mlp_kernel(
        const unsigned* __restrict__ xs, const int* __restrict__ pairs,
        const int* __restrict__ row_ptr, const int* __restrict__ csr_src,
        const float* __restrict__ inv_in, const float* __restrict__ bias2,
        const float* __restrict__ W1, const float* __restrict__ b1,
        const float* __restrict__ W2, const float* __restrict__ b2,
        float* __restrict__ out, int B) {
    __shared__ float2 xr[2][64];     // conv3 outputs for the two pair nodes
    __shared__ float xp[HDIM];
    __shared__ float red[HDIM];
    int p = blockIdx.x;
    int t = threadIdx.x;
    int wv = t >> 6;                 // 0: pairs[p], 1: pairs[B+p]
    int lane = t & 63;
    int n = pairs[p + wv * B];

    int start = row_ptr[n];
    int end   = row_ptr[n + 1];
    float ax0 = 0.f, ay0 = 0.f, ax1 = 0.f, ay1 = 0.f;
    float ax2 = 0.f, ay2 = 0.f, ax3 = 0.f, ay3 = 0.f;
    int e = start;
    for (; e + 4 <= end; e += 4) {
        int s0 = csr_src[e + 0], s1 = csr_src[e + 1];
        int s2 = csr_src[e + 2], s3 = csr_src[e + 3];
        unsigned v0 = xs[(size_t)s0 * 64 + lane];
        unsigned v1 = xs[(size_t)s1 * 64 + lane];
        unsigned v2 = xs[(size_t)s2 * 64 + lane];
        unsigned v3 = xs[(size_t)s3 * 64 + lane];
        ax0 += bf16_lo(v0); ay0 += bf16_hi(v0);
        ax1 += bf16_lo(v1); ay1 += bf16_hi(v1);
        ax2 += bf16_lo(v2); ay2 += bf16_hi(v2);
        ax3 += bf16_lo(v3); ay3 += bf16_hi(v3);
    }
    for (; e < end; ++e) {
        unsigned v = xs[(size_t)csr_src[e] * 64 + lane];
        ax0 += bf16_lo(v); ay0 += bf16_hi(v);
    }
    float accx = (ax0 + ax1) + (ax2 + ax3);
    float accy = (ay0 + ay1) + (ay2 + ay3);

    float win = inv_in[n];
    float2 bb = reinterpret_cast<const float2*>(bias2)[lane];
    xr[wv][lane] = make_float2(accx * win + bb.x, accy * win + bb.y);
    __syncthreads();

    const float* xa = (const float*)xr[0];
    const float* xbv = (const float*)xr[1];
    xp[t] = xa[t] * xbv[t];
    __syncthreads();

    float h = b1[t];
    #pragma unroll 8
    for (int k = 0; k < HDIM; ++k) h += xp[k] * W1[k * HDIM + t];
    h = fmaxf(h, 0.0f);
    red[t] = h * W2[t];
    __syncthreads();
    for (int s = 64; s > 0; s >>= 1) {
        if (t < s) red[t] += red[t + s];
        __syncthreads();
    }
    if (t == 0) out[p] = red[0] + b2[0];
}

extern "C" void kernel_launch(void* const* d_in, const int* in_sizes, int n_in,
                              void* d_out, int out_size, void* d_ws, size_t ws_size,
                              hipStream_t stream) {
    const int*   z       = (const int*)d_in[0];
    const int*   src     = (const int*)d_in[1];
    const int*   dst     = (const int*)d_in[2];
    const int*   pairs   = (const int*)d_in[3];
    const float* z_table = (const float*)d_in[4];
    const float* bias[3] = {(const float*)d_in[5], (const float*)d_in[6], (const float*)d_in[7]};
    const float* W1      = (const float*)d_in[8];
    const float* b1      = (const float*)d_in[9];
    const float* W2      = (const float*)d_in[10];
    const float* b2      = (const float*)d_in[11];

    const int N = in_sizes[0];
    const int E = in_sizes[1];
    const int B = in_sizes[3] / 2;
    const int M = 2 * B;
    const int nblk = (N + SCAN_CHUNK - 1) / SCAN_CHUNK;
    const int window = (N + NBUK - 1) / NBUK;

    char* ws = (char*)d_ws;
    size_t off = 0;
    auto carve = [&](size_t bytes) -> void* {
        void* p = ws + off;
        off = (off + bytes + 255) & ~(size_t)255;
        return p;
    };
    int*      deg_out = (int*)carve((size_t)N * 4);   // fallback only
    int*      deg_in  = (int*)carve((size_t)N * 4);   // fallback only
    float*    inv_out = (float*)carve((size_t)N * 4);
    float*    inv_in  = (float*)carve((size_t)N * 4);
    int*      row_ptr = (int*)carve((size_t)(N + 1) * 4);
    int*      pos     = (int*)carve((size_t)N * 4);      // fallback only
    int*      blk_sum = (int*)carve((size_t)nblk * 4);   // fallback only
    int*      blk_off = (int*)carve((size_t)nblk * 4);   // fallback only
    int*      csr_src = (int*)carve((size_t)E * 4);
    unsigned* xe      = (unsigned*)carve((size_t)N * 64 * 4);   // embed out, bf16x2
    unsigned* xb      = (unsigned*)carve((size_t)N * 64 * 4);   // conv1 out, bf16x2
    unsigned* mbuf    = (unsigned*)carve((size_t)N * 64 * 4);   // conv2 out, bf16x2

    // zero region: flags1 | flags2 | cnt | cnt2 (single memset covers all)
    unsigned char* zbase  = (unsigned char*)carve((size_t)N * 2 + (size_t)NBUK * 8 + 512);
    unsigned char* flags1 = zbase;
    unsigned char* flags2 = zbase + N;
    int* cnt  = (int*)(zbase + ((size_t)N * 2 + 255 & ~(size_t)255));
    int* cnt2 = cnt + NBUK;
    size_t zsize = ((size_t)N * 2 + 255 & ~(size_t)255) + (size_t)NBUK * 8;

    // radix-partition staging (packed)
    const int mean = (E + NBUK - 1) / NBUK;
    const int cap  = (int)((((size_t)mean * 2) + 255) / 256) * 256;   // 2x headroom
    unsigned*       staging  = (unsigned*)carve((size_t)NBUK * (size_t)cap * 4);
    unsigned short* staging2 = (unsigned short*)carve((size_t)NBUK * (size_t)cap * 2);
    const bool pack_ok  = (N < (1 << 23)) && (window <= 512);
    const bool use_part = pack_ok && (off <= ws_size);

    if (use_part) {
        hipMemsetAsync(zbase, 0, zsize, stream);
        const int edges_per_block = 1024 * PART_EPT;
        const int pblocks = (E + edges_per_block - 1) / edges_per_block;
        partition_kernel<<<pblocks, 1024, 0, stream>>>(
            src, dst, cnt, cnt2, staging, staging2, E, N, cap);
        build_kernel<<<NBUK, 512, 0, stream>>>(
            cnt, cnt2, staging, staging2, row_ptr, csr_src, inv_in, inv_out, cap, N);
    } else {
        hipMemsetAsync(zbase, 0, zsize, stream);
        hipMemsetAsync(deg_out, 0, (size_t)N * 4, stream);
        hipMemsetAsync(deg_in,  0, (size_t)N * 4, stream);
        deg_kernel<<<(E + 255) / 256, 256, 0, stream>>>(src, dst, deg_out, deg_in, E);
        inv_kernel<<<(N + 255) / 256, 256, 0, stream>>>(deg_out, deg_in, inv_out, inv_in, N);
        scan_blk_sum<<<nblk, 1024, 0, stream>>>(deg_in, blk_sum, N);
        scan_blk_off<<<1, 128, 0, stream>>>(blk_sum, blk_off, nblk);
        scan_apply<<<nblk, 1024, 0, stream>>>(deg_in, blk_off, row_ptr, pos, inv_in, N);
        fill_kernel<<<(E + 255) / 256, 256, 0, stream>>>(src, dst, pos, csr_src, E);
    }

    // needed-set flags + embed
    flag2_kernel<<<((long long)M * 64 + 127) / 128, 128, 0, stream>>>(
        pairs, row_ptr, csr_src, flags2, M);
    flag1_kernel<<<((long long)N * 64 + 127) / 128, 128, 0, stream>>>(
        flags2, row_ptr, csr_src, flags1, N);
    embed_kernel<<<((size_t)N * 32 + 255) / 256, 256, 0, stream>>>(
        z, z_table, inv_out, (uint2*)xe, N);

    long long threads = (long long)N * 64;
    conv1_kernel<<<(threads + 127) / 128, 128, 0, stream>>>(
        xe, flags1, xb, row_ptr, csr_src, inv_out, inv_in, bias[0], N);
    conv2_kernel<<<(threads + 127) / 128, 128, 0, stream>>>(
        xb, flags2, mbuf, row_ptr, csr_src, inv_out, inv_in, bias[1], N);
    conv3mlp_kernel<<<B, 128, 0, stream>>>(
        mbuf, pairs, row_ptr, csr_src, inv_in, bias[2],
        W1, b1, W2, b2, (float*)d_out, B);
}

// Round 17
// 168.707 us; speedup vs baseline: 5.1790x; 1.0453x over previous
//
#include <hip/hip_runtime.h>

#define HDIM 128
#define SCAN_CHUNK 1024
#define NBUK 256          // range buckets for radix partition
#define PART_EPT 2        // edges per thread in partition kernel

// ---------- bf16x2 pack/unpack (RNE) ----------
__device__ inline unsigned pack_bf16x2(float a, float b) {
    unsigned ua = __float_as_uint(a);
    unsigned ub = __float_as_uint(b);
    ua = (ua + 0x7FFFu + ((ua >> 16) & 1u)) >> 16;
    ub = (ub + 0x7FFFu + ((ub >> 16) & 1u)) >> 16;
    return ua | (ub << 16);
}
__device__ inline float bf16_lo(unsigned v) { return __uint_as_float(v << 16); }
__device__ inline float bf16_hi(unsigned v) { return __uint_as_float(v & 0xFFFF0000u); }

// ================= fallback path (used only if ws too small) =================
__global__ void deg_kernel(const int* __restrict__ src, const int* __restrict__ dst,
                           int* __restrict__ deg_out, int* __restrict__ deg_in, int E) {
    int e = blockIdx.x * blockDim.x + threadIdx.x;
    if (e < E) {
        atomicAdd(&deg_out[src[e]], 1);
        atomicAdd(&deg_in[dst[e]], 1);
    }
}

__global__ void inv_kernel(const int* __restrict__ deg_out, const int* __restrict__ deg_in,
                           float* __restrict__ inv_out, float* __restrict__ inv_in, int N) {
    int n = blockIdx.x * blockDim.x + threadIdx.x;
    if (n < N) {
        float dO = (float)(deg_out[n] > 1 ? deg_out[n] : 1);
        float dI = (float)(deg_in[n]  > 1 ? deg_in[n]  : 1);
        inv_out[n] = 1.0f / sqrtf(dO);
        inv_in[n]  = 1.0f / sqrtf(dI);
    }
}

__global__ __launch_bounds__(1024) void scan_blk_sum(const int* __restrict__ deg,
                                                     int* __restrict__ blk_sum, int n) {
    __shared__ int red[1024];
    int tid = threadIdx.x;
    int i = blockIdx.x * SCAN_CHUNK + tid;
    red[tid] = (i < n) ? deg[i] : 0;
    __syncthreads();
    for (int s = 512; s > 0; s >>= 1) {
        if (tid < s) red[tid] += red[tid + s];
        __syncthreads();
    }
    if (tid == 0) blk_sum[blockIdx.x] = red[0];
}

__global__ __launch_bounds__(128) void scan_blk_off(const int* __restrict__ blk_sum,
                                                    int* __restrict__ blk_off, int nblk) {
    __shared__ int buf[128];
    int tid = threadIdx.x;
    int v = (tid < nblk) ? blk_sum[tid] : 0;
    buf[tid] = v;
    __syncthreads();
    for (int offset = 1; offset < 128; offset <<= 1) {
        int t = (tid >= offset) ? buf[tid - offset] : 0;
        __syncthreads();
        buf[tid] += t;
        __syncthreads();
    }
    if (tid < nblk) blk_off[tid] = buf[tid] - v;   // exclusive
}

__global__ __launch_bounds__(1024) void scan_apply(const int* __restrict__ deg,
                                                   const int* __restrict__ blk_off,
                                                   int* __restrict__ row_ptr,
                                                   int* __restrict__ pos,
                                                   float* __restrict__ inv_in, int n) {
    __shared__ int buf[1024];
    int tid = threadIdx.x;
    int i = blockIdx.x * SCAN_CHUNK + tid;
    int v = (i < n) ? deg[i] : 0;
    buf[tid] = v;
    __syncthreads();
    for (int offset = 1; offset < 1024; offset <<= 1) {
        int t = (tid >= offset) ? buf[tid - offset] : 0;
        __syncthreads();
        buf[tid] += t;
        __syncthreads();
    }
    int base = blk_off[blockIdx.x];
    if (i < n) {
        int incl = base + buf[tid];
        row_ptr[i + 1] = incl;
        pos[i] = incl - v;
        inv_in[i] = 1.0f / sqrtf((float)(v > 1 ? v : 1));
    }
    if (i == 0) row_ptr[0] = 0;
}

__global__ void fill_kernel(const int* __restrict__ src, const int* __restrict__ dst,
                            int* __restrict__ pos, int* __restrict__ csr_src, int E) {
    int e = blockIdx.x * blockDim.x + threadIdx.x;
    if (e < E) {
        int d = dst[e];
        int idx = atomicAdd(&pos[d], 1);
        csr_src[idx] = src[e];
    }
}

__global__ __launch_bounds__(128) void flag2_kernel(
        const int* __restrict__ plist, const int* __restrict__ row_ptr,
        const int* __restrict__ csr_src, unsigned char* __restrict__ flags2, int M) {
    int gtid = blockIdx.x * blockDim.x + threadIdx.x;
    int i = gtid >> 6;
    int lane = threadIdx.x & 63;
    if (i >= M) return;
    int n = plist[i];
    int start = row_ptr[n], end = row_ptr[n + 1];
    for (int e = start + lane; e < end; e += 64) flags2[csr_src[e]] = 1;
}

// ================= fast path =================
// radix partition, PACKED staging; allocators are zero-initialized counters.
// staging[.]  = src | (dst - lo(bk)) << 23    (dst-bucketed; local dst < 512)
// staging2[.] = (ushort)(src - lo(bs))        (src-bucketed; for out-degree)
// block 0 additionally builds is_pair[] from the pair list.
__global__ __launch_bounds__(1024) void partition_kernel(
        const int* __restrict__ src, const int* __restrict__ dst,
        const int* __restrict__ plist, unsigned char* __restrict__ is_pair,
        int* __restrict__ cnt, int* __restrict__ cnt2,
        unsigned* __restrict__ staging, unsigned short* __restrict__ staging2,
        int E, int N, int cap, int M) {
    __shared__ int lcnt[NBUK];
    __shared__ int lbase[NBUK];
    __shared__ int lcnt2[NBUK];
    __shared__ int lbase2[NBUK];
    int tid = threadIdx.x;
    if (blockIdx.x == 0) {
        for (int i = tid; i < M; i += 1024) is_pair[plist[i]] = 1;
    }
    if (tid < NBUK) { lcnt[tid] = 0; lcnt2[tid] = 0; }
    __syncthreads();
    int base_e = blockIdx.x * (1024 * PART_EPT);
    unsigned pk[PART_EPT]; unsigned short pk2[PART_EPT];
    int bk[PART_EPT], rk[PART_EPT], bs[PART_EPT], rs[PART_EPT];
    #pragma unroll
    for (int j = 0; j < PART_EPT; ++j) {
        int e = base_e + j * 1024 + tid;    // coalesced
        if (e < E) {
            int s = src[e];
            int d = dst[e];
            bk[j] = (int)(((long long)d * NBUK) / N);
            int lo_d = (bk[j] * N + NBUK - 1) / NBUK;
            pk[j] = (unsigned)s | ((unsigned)(d - lo_d) << 23);
            rk[j] = atomicAdd(&lcnt[bk[j]], 1);
            bs[j] = (int)(((long long)s * NBUK) / N);
            int lo_s = (bs[j] * N + NBUK - 1) / NBUK;
            pk2[j] = (unsigned short)(s - lo_s);
            rs[j] = atomicAdd(&lcnt2[bs[j]], 1);
        } else {
            bk[j] = -1;
        }
    }
    __syncthreads();
    if (tid < NBUK) {
        int c = lcnt[tid];
        lbase[tid] = (c > 0) ? atomicAdd(&cnt[tid], c) : 0;
        int c2 = lcnt2[tid];
        lbase2[tid] = (c2 > 0) ? atomicAdd(&cnt2[tid], c2) : 0;
    }
    __syncthreads();
    #pragma unroll
    for (int j = 0; j < PART_EPT; ++j) {
        if (bk[j] >= 0) {
            int r = lbase[bk[j]] + rk[j];
            if (r < cap)                       // overflow clamp (>=24 sigma headroom)
                staging[(size_t)bk[j] * cap + r] = pk[j];
            int r2 = lbase2[bs[j]] + rs[j];
            if (r2 < cap)
                staging2[(size_t)bs[j] * cap + r2] = pk2[j];
        }
    }
}

// FUSED per-bucket: dst-hist + src-hist + bucket-base scan + within-bucket scan
// + row_ptr/inv_in/inv_out writes + CSR scatter (LDS-atomic pos) + flags2 marks.
__global__ __launch_bounds__(512) void build_kernel(
        const int* __restrict__ cnt, const int* __restrict__ cnt2,
        const unsigned* __restrict__ staging, const unsigned short* __restrict__ staging2,
        const unsigned char* __restrict__ is_pair,
        int* __restrict__ row_ptr, int* __restrict__ csr_src,
        float* __restrict__ inv_in, float* __restrict__ inv_out,
        unsigned char* __restrict__ flags2,
        int cap, int N) {
    __shared__ int h[512];
    __shared__ int h2[512];
    __shared__ int csum[NBUK];
    __shared__ int posl[512];
    __shared__ unsigned char ip[512];
    int b = blockIdx.x;
    int t = threadIdx.x;
    int lo = (b * N + NBUK - 1) / NBUK;
    int hi = ((b + 1) * N + NBUK - 1) / NBUK;
    if (hi > N) hi = N;
    int w = hi - lo;
    h[t] = 0; h2[t] = 0;
    ip[t] = (t < w) ? is_pair[lo + t] : 0;
    if (t < NBUK) {
        int c = cnt[t];
        csum[t] = (c > cap) ? cap : c;
    }
    __syncthreads();
    size_t base = (size_t)b * cap;
    int cnt_b  = cnt[b];  if (cnt_b  > cap) cnt_b  = cap;
    int cnt2_b = cnt2[b]; if (cnt2_b > cap) cnt2_b = cap;
    for (int i = t; i < cnt_b; i += 512)
        atomicAdd(&h[staging[base + i] >> 23], 1);
    for (int i = t; i < cnt2_b; i += 512)
        atomicAdd(&h2[staging2[base + i]], 1);
    __syncthreads();
    // out-degree -> inv_out
    if (t < w) {
        int v2 = h2[t];
        inv_out[lo + t] = 1.0f / sqrtf((float)(v2 > 1 ? v2 : 1));
    }
    // bucket-base: inclusive scan of csum (256), same result in every block
    for (int offset = 1; offset < NBUK; offset <<= 1) {
        int tmp = (t >= offset && t < NBUK) ? csum[t - offset] : 0;
        __syncthreads();
        if (t < NBUK) csum[t] += tmp;
        __syncthreads();
    }
    int gbase = (b > 0) ? csum[b - 1] : 0;
    // in-degree: save, inclusive scan h in place (Hillis-Steele, 512)
    int v = h[t];
    __syncthreads();
    for (int offset = 1; offset < 512; offset <<= 1) {
        int tmp = (t >= offset) ? h[t - offset] : 0;
        __syncthreads();
        h[t] += tmp;
        __syncthreads();
    }
    if (t < w) {
        int incl = gbase + h[t];
        row_ptr[lo + t + 1] = incl;
        posl[t] = incl - v;          // global CSR slot base for local node t
        inv_in[lo + t] = 1.0f / sqrtf((float)(v > 1 ? v : 1));
    }
    if (b == 0 && t == 0) row_ptr[0] = 0;
    __syncthreads();
    // scatter this bucket's edges; mark flags2[src] for edges into pair nodes
    for (int i = t; i < cnt_b; i += 512) {
        unsigned p = staging[base + i];
        int dl = (int)(p >> 23);
        int s  = (int)(p & 0x7FFFFFu);
        int slot = atomicAdd(&posl[dl], 1);
        csr_src[slot] = s;
        if (ip[dl]) flags2[s] = 1;
    }
}

// ---------- FUSED flag1 + embed (independent, both depend only on build) ----------
// blocks [0, fblocks): flag1 — mark in-neighbors of flags2 nodes.
// blocks [fblocks, ..): embed — xe[n] = pack_bf16(z_table[z[n]] * inv_out[n]).
__global__ __launch_bounds__(256) void flag1_embed_kernel(
        const unsigned char* __restrict__ flags2, const int* __restrict__ row_ptr,
        const int* __restrict__ csr_src, unsigned char* __restrict__ flags1,
        const int* __restrict__ z, const float* __restrict__ z_table,
        const float* __restrict__ inv_out, uint2* __restrict__ xs,
        int N, int fblocks) {
    if ((int)blockIdx.x < fblocks) {
        int gtid = blockIdx.x * 256 + threadIdx.x;
        int n = gtid >> 6;
        int lane = threadIdx.x & 63;
        if (n >= N || !flags2[n]) return;
        int start = row_ptr[n], end = row_ptr[n + 1];
        for (int e = start + lane; e < end; e += 64) flags1[csr_src[e]] = 1;
    } else {
        int t = (blockIdx.x - fblocks) * 256 + threadIdx.x;
        int n = t >> 5;          // 32 uint2 per row
        int c = t & 31;
        if (n < N) {
            int zz = z[n];
            float w = inv_out[n];
            float4 v = reinterpret_cast<const float4*>(z_table)[(size_t)zz * 32 + c];
            uint2 p;
            p.x = pack_bf16x2(v.x * w, v.y * w);
            p.y = pack_bf16x2(v.z * w, v.w * w);
            xs[(size_t)n * 32 + c] = p;
        }
    }
}

// standalone embed for the fallback path
__global__ void embed_kernel(const int* __restrict__ z, const float* __restrict__ z_table,
                             const float* __restrict__ inv_out,
                             uint2* __restrict__ xs, int N) {
    int t = blockIdx.x * blockDim.x + threadIdx.x;
    int n = t >> 5;
    int c = t & 31;
    if (n < N) {
        int zz = z[n];
        float w = inv_out[n];
        float4 v = reinterpret_cast<const float4*>(z_table)[(size_t)zz * 32 + c];
        uint2 p;
        p.x = pack_bf16x2(v.x * w, v.y * w);
        p.y = pack_bf16x2(v.z * w, v.w * w);
        xs[(size_t)n * 32 + c] = p;
    }
}

// ---------- generic bf16->bf16 conv body (8-way, flag-masked) ----------
__device__ inline void conv_bf16_body(
        const unsigned* __restrict__ xs, unsigned* __restrict__ out_bf,
        const int* __restrict__ row_ptr, const int* __restrict__ csr_src,
        const float* __restrict__ inv_out, const float* __restrict__ inv_in,
        const float* __restrict__ bias, int n, int lane) {
    int start = row_ptr[n];
    int end   = row_ptr[n + 1];

    float ax0 = 0.f, ay0 = 0.f, ax1 = 0.f, ay1 = 0.f;
    float ax2 = 0.f, ay2 = 0.f, ax3 = 0.f, ay3 = 0.f;
    float ax4 = 0.f, ay4 = 0.f, ax5 = 0.f, ay5 = 0.f;
    float ax6 = 0.f, ay6 = 0.f, ax7 = 0.f, ay7 = 0.f;
    int e = start;
    for (; e + 8 <= end; e += 8) {
        int s0 = csr_src[e + 0], s1 = csr_src[e + 1];
        int s2 = csr_src[e + 2], s3 = csr_src[e + 3];
        int s4 = csr_src[e + 4], s5 = csr_src[e + 5];
        int s6 = csr_src[e + 6], s7 = csr_src[e + 7];
        unsigned v0 = xs[(size_t)s0 * 64 + lane];
        unsigned v1 = xs[(size_t)s1 * 64 + lane];
        unsigned v2 = xs[(size_t)s2 * 64 + lane];
        unsigned v3 = xs[(size_t)s3 * 64 + lane];
        unsigned v4 = xs[(size_t)s4 * 64 + lane];
        unsigned v5 = xs[(size_t)s5 * 64 + lane];
        unsigned v6 = xs[(size_t)s6 * 64 + lane];
        unsigned v7 = xs[(size_t)s7 * 64 + lane];
        ax0 += bf16_lo(v0); ay0 += bf16_hi(v0);
        ax1 += bf16_lo(v1); ay1 += bf16_hi(v1);
        ax2 += bf16_lo(v2); ay2 += bf16_hi(v2);
        ax3 += bf16_lo(v3); ay3 += bf16_hi(v3);
        ax4 += bf16_lo(v4); ay4 += bf16_hi(v4);
        ax5 += bf16_lo(v5); ay5 += bf16_hi(v5);
        ax6 += bf16_lo(v6); ay6 += bf16_hi(v6);
        ax7 += bf16_lo(v7); ay7 += bf16_hi(v7);
    }
    if (e + 4 <= end) {
        int s0 = csr_src[e + 0], s1 = csr_src[e + 1];
        int s2 = csr_src[e + 2], s3 = csr_src[e + 3];
        unsigned v0 = xs[(size_t)s0 * 64 + lane];
        unsigned v1 = xs[(size_t)s1 * 64 + lane];
        unsigned v2 = xs[(size_t)s2 * 64 + lane];
        unsigned v3 = xs[(size_t)s3 * 64 + lane];
        ax0 += bf16_lo(v0); ay0 += bf16_hi(v0);
        ax1 += bf16_lo(v1); ay1 += bf16_hi(v1);
        ax2 += bf16_lo(v2); ay2 += bf16_hi(v2);
        ax3 += bf16_lo(v3); ay3 += bf16_hi(v3);
        e += 4;
    }
    for (; e < end; ++e) {
        unsigned v = xs[(size_t)csr_src[e] * 64 + lane];
        ax0 += bf16_lo(v); ay0 += bf16_hi(v);
    }
    float accx = ((ax0 + ax1) + (ax2 + ax3)) + ((ax4 + ax5) + (ax6 + ax7));
    float accy = ((ay0 + ay1) + (ay2 + ay3)) + ((ay4 + ay5) + (ay6 + ay7));

    float win = inv_in[n];
    float2 b = reinterpret_cast<const float2*>(bias)[lane];
    float wout = inv_out[n];
    float ox = fmaxf(accx * win + b.x, 0.0f) * wout;
    float oy = fmaxf(accy * win + b.y, 0.0f) * wout;
    out_bf[(size_t)n * 64 + lane] = pack_bf16x2(ox, oy);
}

__global__ __launch_bounds__(128) void conv1_kernel(
        const unsigned* __restrict__ xs, const unsigned char* __restrict__ flags1,
        unsigned* __restrict__ out_bf,
        const int* __restrict__ row_ptr, const int* __restrict__ csr_src,
        const float* __restrict__ inv_out, const float* __restrict__ inv_in,
        const float* __restrict__ bias, int N) {
    int gtid = blockIdx.x * blockDim.x + threadIdx.x;
    int n = gtid >> 6;
    int lane = threadIdx.x & 63;
    if (n >= N || !flags1[n]) return;
    conv_bf16_body(xs, out_bf, row_ptr, csr_src, inv_out, inv_in, bias, n, lane);
}

__global__ __launch_bounds__(128) void conv2_kernel(
        const unsigned* __restrict__ xs, const unsigned char* __restrict__ flags2,
        unsigned* __restrict__ out_bf,
        const int* __restrict__ row_ptr, const int* __restrict__ csr_src,
        const float* __restrict__ inv_out, const float* __restrict__ inv_in,
        const float* __restrict__ bias, int N) {
    int gtid = blockIdx.x * blockDim.x + threadIdx.x;
    int n = gtid >> 6;
    int lane = threadIdx.x & 63;
    if (n >= N || !flags2[n]) return;
    conv_bf16_body(xs, out_bf, row_ptr, csr_src, inv_out, inv_in, bias, n, lane);
}

// ---------- FUSED conv3 (both pair nodes) + center pooling + MLP, one block/pair ----------
__global__ __launch_bounds__(128) void conv3mlp_kernel(
        const unsigned* __restrict__ xs, const int* __restrict__ pairs,
        const int* __restrict__ row_ptr, const int* __restrict__ csr_src,
        const float* __restrict__ inv_in, const float* __restrict__ bias2,
        const float* __restrict__ W1, const float* __restrict__ b1,
        const float* __restrict__ W2, const float* __restrict__ b2,
        float* __restrict__ out, int B) {
    __shared__ float2 xr[2][64];
    __shared__ float xp[HDIM];
    __shared__ float red[HDIM];
    int p = blockIdx.x;
    int t = threadIdx.x;
    int wv = t >> 6;
    int lane = t & 63;
    int n = pairs[p + wv * B];

    int start = row_ptr[n];
    int end   = row_ptr[n + 1];
    float ax0 = 0.f, ay0 = 0.f, ax1 = 0.f, ay1 = 0.f;
    float ax2 = 0.f, ay2 = 0.f, ax3 = 0.f, ay3 = 0.f;
    int e = start;
    for (; e + 4 <= end; e += 4) {
        int s0 = csr_src[e + 0], s1 = csr_src[e + 1];
        int s2 = csr_src[e + 2], s3 = csr_src[e + 3];
        unsigned v0 = xs[(size_t)s0 * 64 + lane];
        unsigned v1 = xs[(size_t)s1 * 64 + lane];
        unsigned v2 = xs[(size_t)s2 * 64 + lane];
        unsigned v3 = xs[(size_t)s3 * 64 + lane];
        ax0 += bf16_lo(v0); ay0 += bf16_hi(v0);
        ax1 += bf16_lo(v1); ay1 += bf16_hi(v1);
        ax2 += bf16_lo(v2); ay2 += bf16_hi(v2);
        ax3 += bf16_lo(v3); ay3 += bf16_hi(v3);
    }
    for (; e < end; ++e) {
        unsigned v = xs[(size_t)csr_src[e] * 64 + lane];
        ax0 += bf16_lo(v); ay0 += bf16_hi(v);
    }
    float accx = (ax0 + ax1) + (ax2 + ax3);
    float accy = (ay0 + ay1) + (ay2 + ay3);

    float win = inv_in[n];
    float2 bb = reinterpret_cast<const float2*>(bias2)[lane];
    xr[wv][lane] = make_float2(accx * win + bb.x, accy * win + bb.y);
    __syncthreads();

    const float* xa = (const float*)xr[0];
    const float* xbv = (const float*)xr[1];
    xp[t] = xa[t] * xbv[t];
    __syncthreads();

    float h = b1[t];
    #pragma unroll 8
    for (int k = 0; k < HDIM; ++k) h += xp[k] * W1[k * HDIM + t];
    h = fmaxf(h, 0.0f);
    red[t] = h * W2[t];
    __syncthreads();
    for (int s = 64; s > 0; s >>= 1) {
        if (t < s) red[t] += red[t + s];
        __syncthreads();
    }
    if (t == 0) out[p] = red[0] + b2[0];
}

extern "C" void kernel_launch(void* const* d_in, const int* in_sizes, int n_in,
                              void* d_out, int out_size, void* d_ws, size_t ws_size,
                              hipStream_t stream) {
    const int*   z       = (const int*)d_in[0];
    const int*   src     = (const int*)d_in[1];
    const int*   dst     = (const int*)d_in[2];
    const int*   pairs   = (const int*)d_in[3];
    const float* z_table = (const float*)d_in[4];
    const float* bias[3] = {(const float*)d_in[5], (const float*)d_in[6], (const float*)d_in[7]};
    const float* W1      = (const float*)d_in[8];
    const float* b1      = (const float*)d_in[9];
    const float* W2      = (const float*)d_in[10];
    const float* b2      = (const float*)d_in[11];

    const int N = in_sizes[0];
    const int E = in_sizes[1];
    const int B = in_sizes[3] / 2;
    const int M = 2 * B;
    const int nblk = (N + SCAN_CHUNK - 1) / SCAN_CHUNK;
    const int window = (N + NBUK - 1) / NBUK;

    char* ws = (char*)d_ws;
    size_t off = 0;
    auto carve = [&](size_t bytes) -> void* {
        void* p = ws + off;
        off = (off + bytes + 255) & ~(size_t)255;
        return p;
    };
    int*      deg_out = (int*)carve((size_t)N * 4);   // fallback only
    int*      deg_in  = (int*)carve((size_t)N * 4);   // fallback only
    float*    inv_out = (float*)carve((size_t)N * 4);
    float*    inv_in  = (float*)carve((size_t)N * 4);
    int*      row_ptr = (int*)carve((size_t)(N + 1) * 4);
    int*      pos     = (int*)carve((size_t)N * 4);      // fallback only
    int*      blk_sum = (int*)carve((size_t)nblk * 4);   // fallback only
    int*      blk_off = (int*)carve((size_t)nblk * 4);   // fallback only
    int*      csr_src = (int*)carve((size_t)E * 4);
    unsigned* xe      = (unsigned*)carve((size_t)N * 64 * 4);   // embed out, bf16x2
    unsigned* xb      = (unsigned*)carve((size_t)N * 64 * 4);   // conv1 out, bf16x2
    unsigned* mbuf    = (unsigned*)carve((size_t)N * 64 * 4);   // conv2 out, bf16x2

    // zero region: flags1 | flags2 | is_pair | cnt | cnt2 (single memset)
    size_t zflags = (size_t)N * 3;
    size_t zpad   = (zflags + 255) & ~(size_t)255;
    unsigned char* zbase  = (unsigned char*)carve(zpad + (size_t)NBUK * 8);
    unsigned char* flags1  = zbase;
    unsigned char* flags2  = zbase + N;
    unsigned char* is_pair = zbase + (size_t)N * 2;
    int* cnt  = (int*)(zbase + zpad);
    int* cnt2 = cnt + NBUK;
    size_t zsize = zpad + (size_t)NBUK * 8;

    // radix-partition staging (packed)
    const int mean = (E + NBUK - 1) / NBUK;
    const int cap  = (int)((((size_t)mean * 2) + 255) / 256) * 256;   // 2x headroom
    unsigned*       staging  = (unsigned*)carve((size_t)NBUK * (size_t)cap * 4);
    unsigned short* staging2 = (unsigned short*)carve((size_t)NBUK * (size_t)cap * 2);
    const bool pack_ok  = (N < (1 << 23)) && (window <= 512);
    const bool use_part = pack_ok && (off <= ws_size);

    hipMemsetAsync(zbase, 0, zsize, stream);

    if (use_part) {
        const int edges_per_block = 1024 * PART_EPT;
        const int pblocks = (E + edges_per_block - 1) / edges_per_block;
        partition_kernel<<<pblocks, 1024, 0, stream>>>(
            src, dst, pairs, is_pair, cnt, cnt2, staging, staging2, E, N, cap, M);
        build_kernel<<<NBUK, 512, 0, stream>>>(
            cnt, cnt2, staging, staging2, is_pair,
            row_ptr, csr_src, inv_in, inv_out, flags2, cap, N);
    } else {
        hipMemsetAsync(deg_out, 0, (size_t)N * 4, stream);
        hipMemsetAsync(deg_in,  0, (size_t)N * 4, stream);
        deg_kernel<<<(E + 255) / 256, 256, 0, stream>>>(src, dst, deg_out, deg_in, E);
        inv_kernel<<<(N + 255) / 256, 256, 0, stream>>>(deg_out, deg_in, inv_out, inv_in, N);
        scan_blk_sum<<<nblk, 1024, 0, stream>>>(deg_in, blk_sum, N);
        scan_blk_off<<<1, 128, 0, stream>>>(blk_sum, blk_off, nblk);
        scan_apply<<<nblk, 1024, 0, stream>>>(deg_in, blk_off, row_ptr, pos, inv_in, N);
        fill_kernel<<<(E + 255) / 256, 256, 0, stream>>>(src, dst, pos, csr_src, E);
        flag2_kernel<<<((long long)M * 64 + 127) / 128, 128, 0, stream>>>(
            pairs, row_ptr, csr_src, flags2, M);
    }

    // fused flag1 + embed (both depend only on CSR/flags2/inv_out)
    const int fblocks = (int)(((long long)N * 64 + 255) / 256);
    const int eblocks = (int)(((long long)N * 32 + 255) / 256);
    flag1_embed_kernel<<<fblocks + eblocks, 256, 0, stream>>>(
        flags2, row_ptr, csr_src, flags1, z, z_table, inv_out, (uint2*)xe, N, fblocks);

    long long threads = (long long)N * 64;
    conv1_kernel<<<(threads + 127) / 128, 128, 0, stream>>>(
        xe, flags1, xb, row_ptr, csr_src, inv_out, inv_in, bias[0], N);
    conv2_kernel<<<(threads + 127) / 128, 128, 0, stream>>>(
        xb, flags2, mbuf, row_ptr, csr_src, inv_out, inv_in, bias[1], N);
    conv3mlp_kernel<<<B, 128, 0, stream>>>(
        mbuf, pairs, row_ptr, csr_src, inv_in, bias[2],
        W1, b1, W2, b2, (float*)d_out, B);
}